// Round 17
// baseline (643.325 us; speedup 1.0000x reference)
//
#include <hip/hip_runtime.h>
#include <math.h>
#include <stdint.h>

typedef __attribute__((ext_vector_type(8))) short    bf16x8;
typedef __attribute__((ext_vector_type(4))) float    f32x4;
typedef __attribute__((ext_vector_type(8))) uint16_t u16x8;
typedef __attribute__((ext_vector_type(4))) uint16_t u16x4;

#define LSTR 40   // LDS row stride (bf16): 80B rows -> 2-way banks (free)
#define NBLK 160  // persistent LSTM blocks

__device__ __forceinline__ uint16_t f2bf(float f) {
    union { float f; uint32_t u; } v; v.f = f;
    uint32_t r = v.u + 0x7FFFu + ((v.u >> 16) & 1u);
    return (uint16_t)(r >> 16);
}

__device__ __forceinline__ float sigm(float x) { return 1.f / (1.f + expf(-x)); }

// packed RNE f32x2 -> bf16x2
__device__ __forceinline__ uint32_t cvtpk(float lo, float hi) {
    uint32_t r;
    asm volatile("v_cvt_pk_bf16_f32 %0, %1, %2" : "=v"(r) : "v"(lo), "v"(hi));
    return r;
}

// ---------------------------------------------------------------------------
// prep (fused): blocks [0,8192) cvt_flat (coalesced), [8192,12288) nhwc,
// [12288,12576) wpack, [12576,15136) lstm_pack.
// ---------------------------------------------------------------------------
__global__ __launch_bounds__(256) void prep_all_kernel(
    const float* __restrict__ f_t, const float* __restrict__ f_t_1,
    const float* __restrict__ w1, const float* __restrict__ w2,
    const float* __restrict__ whh_m, const float* __restrict__ whh_a,
    const float* __restrict__ m_wih, const float* __restrict__ m_whh,
    const float* __restrict__ a_wih, const float* __restrict__ a_whh,
    const float* __restrict__ m_bih, const float* __restrict__ m_bhh,
    const float* __restrict__ a_bih, const float* __restrict__ a_bhh,
    uint16_t* __restrict__ ftflat16, uint16_t* __restrict__ in1_nhwc,
    uint16_t* __restrict__ p1, uint16_t* __restrict__ p2,
    uint16_t* __restrict__ pw1, uint16_t* __restrict__ pw2m,
    uint16_t* __restrict__ pw2a,
    float* __restrict__ b2m_s, float* __restrict__ b2a_s)
{
    __shared__ float lds[32][258];
    const int bid = blockIdx.x;
    const int tid = threadIdx.x;

    if (bid < 8192) {
        int i = (bid * 256 + tid) * 8;
        float4 a = *(const float4*)(f_t + i);
        float4 b = *(const float4*)(f_t + i + 4);
        u16x8 o;
        o[0] = f2bf(a.x); o[1] = f2bf(a.y); o[2] = f2bf(a.z); o[3] = f2bf(a.w);
        o[4] = f2bf(b.x); o[5] = f2bf(b.y); o[6] = f2bf(b.z); o[7] = f2bf(b.w);
        *(u16x8*)(ftflat16 + i) = o;
    } else if (bid < 12288) {
        const int v   = bid - 8192;
        const int bt  = v >> 4;
        const int c0  = ((v & 15) >> 2) * 32;
        const int px0 = (v & 3) * 256;
        const int lc  = tid & 31;
        const int lpx = (tid >> 5) * 32;
        const int c   = c0 + lc;
        const float* src = (c < 64)
            ? (f_t   + ((size_t)bt * 64 + c) * 1024)
            : (f_t_1 + ((size_t)bt * 64 + (c - 64)) * 1024);
#pragma unroll
        for (int j = 0; j < 32; j += 4) {
            float4 vv = *(const float4*)(src + px0 + lpx + j);
            lds[lc][lpx + j + 0] = vv.x;
            lds[lc][lpx + j + 1] = vv.y;
            lds[lc][lpx + j + 2] = vv.z;
            lds[lc][lpx + j + 3] = vv.w;
        }
        __syncthreads();
        uint16_t* op = in1_nhwc + ((size_t)bt * 1024 + px0 + tid) * 128 + c0;
#pragma unroll
        for (int u0 = 0; u0 < 32; u0 += 8) {
            u16x8 o;
#pragma unroll
            for (int u = 0; u < 8; ++u) o[u] = f2bf(lds[u0 + u][tid]);
            *(u16x8*)(op + u0) = o;
        }
    } else if (bid < 12576) {
        int i = (bid - 12288) * 256 + tid;
        if (i < 64 * 1152) {
            int oc = i / 1152, k = i - oc * 1152;
            int s = k >> 7, c = k & 127;
            int ky = s / 3, kx = s - ky * 3;
            p1[i] = f2bf(w1[((oc * 128 + c) * 3 + ky) * 3 + kx]);
        }
        if (i < 64 * 576) {
            int oc = i / 576, k = i - oc * 576;
            int s = k >> 6, c = k & 63;
            int ky = s / 3, kx = s - ky * 3;
            p2[i] = f2bf(w2[((oc * 64 + c) * 3 + ky) * 3 + kx]);
        }
    } else {
        int id = (bid - 12576) * 256 + tid;
        if (id < 2048) {
            b2m_s[id] = m_bih[id] + m_bhh[id];
            b2a_s[id] = a_bih[id] + a_bhh[id];
        }
        if (id < 262144) {                       // pw1
            int kc = id & 63, g = (id >> 6) & 3, j = (id >> 8) & 511, pp = id >> 17;
            const float* src = (pp ? whh_a : whh_m) + ((size_t)(g * 512 + j)) * 512 + kc * 8;
            uint16_t* dst = pw1 + ((((size_t)pp * 32 + (j >> 4)) * 64 + (j & 15) * 4 + g) * 512) + kc * 8;
            float4 a = *(const float4*)src; float4 b = *(const float4*)(src + 4);
            u16x8 o;
            o[0]=f2bf(a.x); o[1]=f2bf(a.y); o[2]=f2bf(a.z); o[3]=f2bf(a.w);
            o[4]=f2bf(b.x); o[5]=f2bf(b.y); o[6]=f2bf(b.z); o[7]=f2bf(b.w);
            *(u16x8*)dst = o;
        } else if (id < 393216) {                // pw2m (sum)
            int id2 = id - 262144;
            int kc = id2 & 63, g = (id2 >> 6) & 3, j = id2 >> 8;
            size_t off = ((size_t)(g * 512 + j)) * 512 + kc * 8;
            const float* s1 = m_wih + off; const float* s2 = m_whh + off;
            uint16_t* dst = pw2m + (((size_t)(j >> 4)) * 64 + (j & 15) * 4 + g) * 512 + kc * 8;
            u16x8 o;
#pragma unroll
            for (int u = 0; u < 8; ++u) o[u] = f2bf(s1[u] + s2[u]);
            *(u16x8*)dst = o;
        } else if (id < 655360) {                // pw2a
            int id3 = id - 393216;
            int kc = id3 & 63, g = (id3 >> 6) & 3, j = (id3 >> 8) & 511, mat = id3 >> 17;
            const float* src = (mat ? a_whh : a_wih) + ((size_t)(g * 512 + j)) * 512 + kc * 8;
            uint16_t* dst = pw2a + ((((size_t)(j >> 3)) * 2 + mat) * 32 + (j & 7) * 4 + g) * 512 + kc * 8;
            float4 a = *(const float4*)src; float4 b = *(const float4*)(src + 4);
            u16x8 o;
            o[0]=f2bf(a.x); o[1]=f2bf(a.y); o[2]=f2bf(a.z); o[3]=f2bf(a.w);
            o[4]=f2bf(b.x); o[5]=f2bf(b.y); o[6]=f2bf(b.z); o[7]=f2bf(b.w);
            *(u16x8*)dst = o;
        }
    }
}

// ---------------------------------------------------------------------------
// conv3x3 + bias + relu, implicit-GEMM MFMA v3: halo staged ONCE (one
// barrier total); weights read DIRECTLY from global (L2-resident 147/74 KB)
// -> zero in-loop barriers, compiler pipelines W-loads across iterations.
// ---------------------------------------------------------------------------
template<int IC, bool SWAP>
__global__ __launch_bounds__(256) void conv_mfma2_kernel(
    const uint16_t* __restrict__ in_nhwc,
    const uint16_t* __restrict__ wpack,
    const float* __restrict__ bias,
    uint16_t* __restrict__ out)
{
    constexpr int ICP = IC + 8;
    constexpr int KT  = 9 * IC;
    constexpr int CPS = IC / 32;
    constexpr int C8  = IC / 8;
    constexpr int MF  = SWAP ? 4 : 2;
    constexpr int NF  = SWAP ? 2 : 4;

    __shared__ __align__(16) uint16_t Ah[6 * 34 * ICP];

    const int bt  = blockIdx.y;
    const int px0 = blockIdx.x * 128;
    const int y0  = blockIdx.x * 4;
    const int tid = threadIdx.x;
    const int w   = tid >> 6, l = tid & 63;
    const int lrow = l & 15, kg = (l >> 4) * 8;

    for (int idx = tid; idx < 204 * C8; idx += 256) {
        int cpos = idx / C8;
        int c8   = (idx - cpos * C8) * 8;
        int hy = cpos / 34, hx = cpos - hy * 34;
        int gy = y0 - 1 + hy, gx = hx - 1;
        u16x8 v = {};
        if (gy >= 0 && gy < 32 && gx >= 0 && gx < 32)
            v = *(const u16x8*)(in_nhwc + (((size_t)bt * 1024) + gy * 32 + gx) * IC + c8);
        *(u16x8*)(Ah + (hy * 34 + hx) * ICP + c8) = v;
    }
    __syncthreads();                     // the only barrier

    f32x4 acc[MF][NF] = {};

    int abase[MF > NF ? MF : 2];
#pragma unroll
    for (int i = 0; i < (SWAP ? 2 : MF); ++i) {
        int m  = w * 32 + i * 16 + lrow;
        int py = m >> 5, px = m & 31;
        abase[i] = (py * 34 + px) * ICP;
    }
    // W fragment base for this lane: row (j*16 + lrow), k-chunk kg
    const uint16_t* wl = wpack + (size_t)lrow * KT + kg;

    for (int q = 0; q < 9 * CPS; ++q) {
        const int s  = q / CPS, cc = (q - s * CPS) * 32;
        const int ky = s / 3,  kx = s - ky * 3;
        const int aoff = (ky * 34 + kx) * ICP + cc + kg;

        bf16x8 wf[4];
#pragma unroll
        for (int j = 0; j < 4; ++j)
            wf[j] = *(const bf16x8*)(wl + (size_t)j * 16 * KT + q * 32);

        if (!SWAP) {
            bf16x8 af[2];
#pragma unroll
            for (int i = 0; i < 2; ++i)
                af[i] = *(const bf16x8*)(Ah + abase[i] + aoff);
#pragma unroll
            for (int i = 0; i < MF; ++i)
#pragma unroll
                for (int j = 0; j < NF; ++j)
                    acc[i][j] = __builtin_amdgcn_mfma_f32_16x16x32_bf16(
                        af[i], wf[j], acc[i][j], 0, 0, 0);
        } else {
            bf16x8 pf[2];
#pragma unroll
            for (int j = 0; j < 2; ++j)
                pf[j] = *(const bf16x8*)(Ah + abase[j] + aoff);
#pragma unroll
            for (int i = 0; i < MF; ++i)
#pragma unroll
                for (int j = 0; j < NF; ++j)
                    acc[i][j] = __builtin_amdgcn_mfma_f32_16x16x32_bf16(
                        wf[i], pf[j], acc[i][j], 0, 0, 0);
        }
    }

    const int col = l & 15, rg = (l >> 4) * 4;
    if (!SWAP) {
#pragma unroll
        for (int i = 0; i < 2; ++i)
#pragma unroll
            for (int j = 0; j < 4; ++j) {
                const int ocb = j * 16 + col;
                const float bv = bias[ocb];
#pragma unroll
                for (int r = 0; r < 4; ++r) {
                    const int px = px0 + w * 32 + i * 16 + rg + r;
                    float v = acc[i][j][r] + bv; v = v > 0.f ? v : 0.f;
                    out[((size_t)bt * 1024 + px) * 64 + ocb] = f2bf(v);
                }
            }
    } else {
#pragma unroll
        for (int i = 0; i < 4; ++i)
#pragma unroll
            for (int j = 0; j < 2; ++j)
#pragma unroll
                for (int r = 0; r < 4; ++r) {
                    const int oc = i * 16 + rg + r;
                    const int px = px0 + w * 32 + j * 16 + col;
                    float v = acc[i][j][r] + bias[oc]; v = v > 0.f ? v : 0.f;
                    out[((size_t)bt * 64 + oc) * 1024 + px] = f2bf(v);
                }
    }
}

// ---------------------------------------------------------------------------
// fc1 MFMA (R7 geometry + coalesced slot staging): BM=256, BN=128, BK=32,
// split-K=32, grid 512; 32 MFMAs per barrier pair.
// ---------------------------------------------------------------------------
__global__ __launch_bounds__(256) void fc1_mfma_kernel(
    const uint16_t* __restrict__ Am, const uint16_t* __restrict__ Af,
    const float* __restrict__ Wf, float* __restrict__ part)
{
    __shared__ __align__(16) uint16_t Aa[256 * LSTR];
    __shared__ __align__(16) uint16_t Bb[128 * LSTR];

    const int id  = blockIdx.x;
    const int vid = (id & 7) * 64 + (id >> 3);   // 512 % 8 == 0 -> bijective
    const int bx  = vid & 1;
    const int by  = (vid >> 1) & 7;
    const int ks  = vid >> 4;

    const int row0 = bx * 256;
    const int col0 = by * 128;
    const size_t kbase = (size_t)ks * 2048;
    const uint16_t* Abase = bx ? Af : Am;

    const int tid = threadIdx.x;
    const int w = tid >> 6, l = tid & 63;
    const int lrow = l & 15, kg = (l >> 4) * 8;

    const int arow = tid >> 2, achk = (tid & 3) * 8;
    const int brow = tid >> 3, bchk = (tid & 7) * 4;

    f32x4 acc[4][8] = {};

    for (int kk = 0; kk < 2048; kk += 32) {
        u16x8 ra[4];
        float4 rb[4];
#pragma unroll
        for (int i = 0; i < 4; ++i)
            ra[i] = *(const u16x8*)(Abase + (size_t)(i * 64 + arow) * 65536 + kbase + kk + achk);
#pragma unroll
        for (int i = 0; i < 4; ++i)
            rb[i] = *(const float4*)(Wf + (size_t)(col0 + i * 32 + brow) * 65536 + kbase + kk + bchk);

        union { u16x4 v; uint32_t u[2]; } cb[4];
#pragma unroll
        for (int i = 0; i < 4; ++i) {
            cb[i].u[0] = cvtpk(rb[i].x, rb[i].y);
            cb[i].u[1] = cvtpk(rb[i].z, rb[i].w);
        }

        __syncthreads();
#pragma unroll
        for (int i = 0; i < 4; ++i)
            *(u16x8*)(Aa + (i * 64 + arow) * LSTR + achk) = ra[i];
#pragma unroll
        for (int i = 0; i < 4; ++i)
            *(u16x4*)(Bb + (i * 32 + brow) * LSTR + bchk) = cb[i].v;
        __syncthreads();

        bf16x8 afr[4], bfr[8];
#pragma unroll
        for (int i = 0; i < 4; ++i)
            afr[i] = *(const bf16x8*)(Aa + (w * 64 + i * 16 + lrow) * LSTR + kg);
#pragma unroll
        for (int j = 0; j < 8; ++j)
            bfr[j] = *(const bf16x8*)(Bb + (j * 16 + lrow) * LSTR + kg);
#pragma unroll
        for (int i = 0; i < 4; ++i)
#pragma unroll
            for (int j = 0; j < 8; ++j)
                acc[i][j] = __builtin_amdgcn_mfma_f32_16x16x32_bf16(
                    afr[i], bfr[j], acc[i][j], 0, 0, 0);
    }

    const int col = l & 15, rg = (l >> 4) * 4;
#pragma unroll
    for (int i = 0; i < 4; ++i)
#pragma unroll
        for (int r = 0; r < 4; ++r) {
            const int grow = row0 + w * 64 + i * 16 + rg + r;
            float* op = part + ((size_t)ks * 512 + grow) * 1024 + col0 + col;
#pragma unroll
            for (int j = 0; j < 8; ++j) op[j * 16] = acc[i][j][r];
        }
}

__global__ __launch_bounds__(256) void fc1_reduce_kernel(
    const float* __restrict__ part, const float* __restrict__ bias,
    uint16_t* __restrict__ h16)
{
    int idx = blockIdx.x * 256 + threadIdx.x;
    int j = idx & 1023;
    float s = bias[j];
#pragma unroll
    for (int ks = 0; ks < 32; ++ks) s += part[(size_t)ks * 524288 + idx];
    h16[idx] = f2bf(s > 0.f ? s : 0.f);
}

// ---------------------------------------------------------------------------
// fc2 MFMA + attention epilogue.  A = hbuf bf16; outputs inm/ina bf16.
// ---------------------------------------------------------------------------
__global__ __launch_bounds__(256) void fc2_att_mfma_kernel(
    const uint16_t* __restrict__ h16, const float* __restrict__ wf,
    const float* __restrict__ bias,
    const float* __restrict__ att1, const float* __restrict__ att2,
    float* __restrict__ alpha_out, uint16_t* __restrict__ inm, uint16_t* __restrict__ ina)
{
    __shared__ __align__(16) uint16_t Aa[128 * LSTR];
    __shared__ __align__(16) uint16_t Bb[128 * LSTR];

    const int row0 = blockIdx.x * 128;
    const int col0 = blockIdx.y * 128;

    const int t = threadIdx.x;
    const int w = t >> 6, l = t & 63;
    const int wr = (w >> 1) * 64, wc = (w & 1) * 64;

    const int srow  = t >> 1;
    const int shalf = (t & 1) * 16;
    const uint16_t* ap = h16 + (size_t)(row0 + srow) * 1024 + shalf;
    const float*    bp = wf  + (size_t)(col0 + srow) * 1024 + shalf;
    uint16_t* awr = Aa + srow * LSTR + shalf;
    uint16_t* bwr = Bb + srow * LSTR + shalf;

    f32x4 acc[4][4] = {};

    for (int kk = 0; kk < 1024; kk += 32) {
        u16x8 a0 = *(const u16x8*)(ap + kk);
        u16x8 a1 = *(const u16x8*)(ap + kk + 8);
        float4 f0 = *(const float4*)(bp + kk);
        float4 f1 = *(const float4*)(bp + kk + 4);
        float4 f2 = *(const float4*)(bp + kk + 8);
        float4 f3 = *(const float4*)(bp + kk + 12);
        union { u16x8 v; uint32_t u[4]; } b0, b1;
        b0.u[0] = cvtpk(f0.x, f0.y); b0.u[1] = cvtpk(f0.z, f0.w);
        b0.u[2] = cvtpk(f1.x, f1.y); b0.u[3] = cvtpk(f1.z, f1.w);
        b1.u[0] = cvtpk(f2.x, f2.y); b1.u[1] = cvtpk(f2.z, f2.w);
        b1.u[2] = cvtpk(f3.x, f3.y); b1.u[3] = cvtpk(f3.z, f3.w);

        __syncthreads();
        *(u16x8*)awr       = a0;
        *(u16x8*)(awr + 8) = a1;
        *(u16x8*)bwr       = b0.v;
        *(u16x8*)(bwr + 8) = b1.v;
        __syncthreads();

        const int row = l & 15, kg = (l >> 4) * 8;
        bf16x8 afr[4], bfr[4];
#pragma unroll
        for (int i = 0; i < 4; ++i)
            afr[i] = *(const bf16x8*)(Aa + (wr + i * 16 + row) * LSTR + kg);
#pragma unroll
        for (int j = 0; j < 4; ++j)
            bfr[j] = *(const bf16x8*)(Bb + (wc + j * 16 + row) * LSTR + kg);
#pragma unroll
        for (int i = 0; i < 4; ++i)
#pragma unroll
            for (int j = 0; j < 4; ++j)
                acc[i][j] = __builtin_amdgcn_mfma_f32_16x16x32_bf16(
                    afr[i], bfr[j], acc[i][j], 0, 0, 0);
    }

    const int col = l & 15, rg = (l >> 4) * 4;
#pragma unroll
    for (int i = 0; i < 4; ++i)
#pragma unroll
        for (int r = 0; r < 4; ++r) {
            const int row = row0 + wr + i * 16 + rg + r;
            const int bt  = row & 255;
            const int b = bt >> 4, tt = bt & 15;
            const size_t ibase = ((size_t)tt * 16 + b) * 1024;
#pragma unroll
            for (int j = 0; j < 4; ++j) {
                const int jj = col0 + wc + j * 16 + col;
                float v = acc[i][j][r] + bias[jj];
                if (row < 256) {
                    float al = sigm(att1[b * 512 + jj] * v);
                    alpha_out[(size_t)bt * 512 + jj] = al;
                    inm[ibase + jj]       = f2bf(al * v);
                    inm[ibase + 512 + jj] = f2bf(v);
                } else {
                    float be = sigm(att2[b * 512 + jj] * v);
                    ina[ibase + jj]       = f2bf(be * v);
                    ina[ibase + 512 + jj] = f2bf(v);
                }
            }
        }
}

// ---------------------------------------------------------------------------
// gx MFMA: gates x-projection, M=256, N=2048, K=1024, grid (2,16,2 paths).
// ---------------------------------------------------------------------------
__global__ __launch_bounds__(256) void gx_mfma_kernel(
    const uint16_t* __restrict__ inm, const uint16_t* __restrict__ ina,
    const float* __restrict__ wih_m, const float* __restrict__ bih_m, const float* __restrict__ bhh_m,
    const float* __restrict__ wih_a, const float* __restrict__ bih_a, const float* __restrict__ bhh_a,
    float* __restrict__ gxm, float* __restrict__ gxa)
{
    __shared__ __align__(16) uint16_t Aa[128 * LSTR];
    __shared__ __align__(16) uint16_t Bb[128 * LSTR];

    const int row0 = blockIdx.x * 128;
    const int col0 = blockIdx.y * 128;
    const int path = blockIdx.z;

    const uint16_t* A = path ? ina : inm;
    const float* W  = path ? wih_a : wih_m;
    const float* bi = path ? bih_a : bih_m;
    const float* bh = path ? bhh_a : bhh_m;
    float* out = path ? gxa : gxm;

    const int t = threadIdx.x;
    const int w = t >> 6, l = t & 63;
    const int wr = (w >> 1) * 64, wc = (w & 1) * 64;

    const int srow  = t >> 1;
    const int shalf = (t & 1) * 16;
    const uint16_t* ap = A + (size_t)(row0 + srow) * 1024 + shalf;
    const float*    bp = W + (size_t)(col0 + srow) * 1024 + shalf;
    uint16_t* awr = Aa + srow * LSTR + shalf;
    uint16_t* bwr = Bb + srow * LSTR + shalf;

    f32x4 acc[4][4] = {};

    for (int kk = 0; kk < 1024; kk += 32) {
        u16x8 a0 = *(const u16x8*)(ap + kk);
        u16x8 a1 = *(const u16x8*)(ap + kk + 8);
        float4 f0 = *(const float4*)(bp + kk);
        float4 f1 = *(const float4*)(bp + kk + 4);
        float4 f2 = *(const float4*)(bp + kk + 8);
        float4 f3 = *(const float4*)(bp + kk + 12);
        union { u16x8 v; uint32_t u[4]; } b0, b1;
        b0.u[0] = cvtpk(f0.x, f0.y); b0.u[1] = cvtpk(f0.z, f0.w);
        b0.u[2] = cvtpk(f1.x, f1.y); b0.u[3] = cvtpk(f1.z, f1.w);
        b1.u[0] = cvtpk(f2.x, f2.y); b1.u[1] = cvtpk(f2.z, f2.w);
        b1.u[2] = cvtpk(f3.x, f3.y); b1.u[3] = cvtpk(f3.z, f3.w);

        __syncthreads();
        *(u16x8*)awr       = a0;
        *(u16x8*)(awr + 8) = a1;
        *(u16x8*)bwr       = b0.v;
        *(u16x8*)(bwr + 8) = b1.v;
        __syncthreads();

        const int row = l & 15, kg = (l >> 4) * 8;
        bf16x8 afr[4], bfr[4];
#pragma unroll
        for (int i = 0; i < 4; ++i)
            afr[i] = *(const bf16x8*)(Aa + (wr + i * 16 + row) * LSTR + kg);
#pragma unroll
        for (int j = 0; j < 4; ++j)
            bfr[j] = *(const bf16x8*)(Bb + (wc + j * 16 + row) * LSTR + kg);
#pragma unroll
        for (int i = 0; i < 4; ++i)
#pragma unroll
            for (int j = 0; j < 4; ++j)
                acc[i][j] = __builtin_amdgcn_mfma_f32_16x16x32_bf16(
                    afr[i], bfr[j], acc[i][j], 0, 0, 0);
    }

    const int col = l & 15, rg = (l >> 4) * 4;
#pragma unroll
    for (int i = 0; i < 4; ++i)
#pragma unroll
        for (int r = 0; r < 4; ++r) {
            const int grow = row0 + wr + i * 16 + rg + r;
#pragma unroll
            for (int j = 0; j < 4; ++j) {
                const int jj = col0 + wc + j * 16 + col;
                out[(size_t)grow * 2048 + jj] = acc[i][j][r] + bi[jj] + bh[jj];
            }
        }
}

// ---------------------------------------------------------------------------
// Persistent LSTM scan v5b: fence-free point-to-point sync (IC-coherent).
// ---------------------------------------------------------------------------
__device__ __forceinline__ void wait_cnt(int* cnt, int target) {
    if (threadIdx.x == 0) {
        while (__hip_atomic_load(cnt, __ATOMIC_RELAXED, __HIP_MEMORY_SCOPE_AGENT) < target)
            __builtin_amdgcn_s_sleep(1);
    }
    __syncthreads();
}

__device__ __forceinline__ void post_cnt(int* cnt) {
    __syncthreads();   // drains vmcnt(0): all waves' sc1 stores reached the IC
    if (threadIdx.x == 0)
        __hip_atomic_fetch_add(cnt, 1, __ATOMIC_RELAXED, __HIP_MEMORY_SCOPE_AGENT);
}

__device__ __forceinline__ void stage_state(uint16_t* dst, const uint32_t* src, int tid) {
#pragma unroll
    for (int i = 0; i < 4; ++i) {
        const int idx = i * 1024 + tid * 4;
        uint4 v = *(const uint4*)(src + idx);
        const int flat = idx * 2;
        union { uint4 q; u16x8 h; } cv; cv.q = v;
        *(u16x8*)(dst + (flat >> 9) * 520 + (flat & 511)) = cv.h;
    }
}

__global__ __launch_bounds__(256, 1) void lstm_scan5_kernel(
    const float* __restrict__ gxm, const float* __restrict__ gxa,
    const uint16_t* __restrict__ pw1, const uint16_t* __restrict__ pw2m,
    const uint16_t* __restrict__ pw2a,
    const float* __restrict__ b2m_s, const float* __restrict__ b2a_s,
    uint32_t* __restrict__ s1p, uint32_t* __restrict__ s2ap,
    int* __restrict__ s1cnt, int* __restrict__ s2acnt,
    float* __restrict__ out)
{
    __shared__ __align__(16) uint16_t wlds[64 * 520];
    __shared__ __align__(16) uint16_t xs[16 * 520];
    __shared__ __align__(16) uint16_t hs[16 * 520];
    __shared__ float gbuf[2][16][68];

    const int bk  = blockIdx.x;
    const int tid = threadIdx.x;
    const int w   = tid >> 6, l = tid & 63;
    const int lrow = l & 15, kg = (l >> 4) * 8;

    const int role = (bk < 64) ? 0 : (bk < 96) ? 1 : 2;   // S1, S2M, S2A
    const int path = (role == 0) ? (bk >> 5) : (role == 1 ? 0 : 1);
    const int tile = (role == 0) ? (bk & 31) : (role == 1 ? bk - 64 : bk - 96);
    const int j0   = tile * ((role == 2) ? 8 : 16);

    const uint16_t* wsrc =
        (role == 0) ? pw1 + ((size_t)path * 32 + tile) * 64 * 512 :
        (role == 1) ? pw2m + (size_t)tile * 64 * 512
                    : pw2a + (size_t)tile * 64 * 512;
    for (int idx = tid; idx < 64 * 64; idx += 256) {
        int row = idx >> 6, c = idx & 63;
        *(u16x8*)(wlds + row * 520 + c * 8) = *(const u16x8*)(wsrc + row * 512 + c * 8);
    }

    float cv = 0.f;
    const float* gx1 = path ? gxa : gxm;

    if (role == 0) {
        const int b = tid >> 4, j = tid & 15, jg = j0 + j;
        const size_t obase = path ? 0 : 262144;
        for (int t = 0; t < 16; ++t) {
            const float* gxr = gx1 + ((size_t)(t * 16 + b)) * 2048;
            float g0 = gxr[jg], g1 = gxr[512 + jg], g2 = gxr[1024 + jg], g3 = gxr[1536 + jg];
            if (t > 0) wait_cnt(&s1cnt[path * 16 + t - 1], 32);
            stage_state(xs, s1p + ((size_t)t * 2 + path) * 4096, tid);
            __syncthreads();
            f32x4 acc = {};
#pragma unroll
            for (int kk = 0; kk < 512; kk += 32) {
                bf16x8 a  = *(const bf16x8*)(xs + lrow * 520 + kk + kg);
                bf16x8 bw = *(const bf16x8*)(wlds + (w * 16 + lrow) * 520 + kk + kg);
                acc = __builtin_amdgcn_mfma_f32_16x16x32_bf16(a, bw, acc, 0, 0, 0);
            }
#pragma unroll
            for (int r = 0; r < 4; ++r)
                gbuf[0][(l >> 4) * 4 + r][w * 16 + lrow] = acc[r];
            __syncthreads();

            float G0 = gbuf[0][b][j * 4 + 0] + g0;
            float G1 = gbuf[0][b][j * 4 + 1] + g1;
            float G2 = gbuf[0][b][j * 4 + 2] + g2;
            float G3 = gbuf[0][b][j * 4 + 3] + g3;
            cv = sigm(G1) * cv + sigm(G0) * tanhf(G2);
            float h = sigm(G3) * tanhf(cv);
            out[obase + ((size_t)b * 16 + t) * 1024 + jg] = h;
            float hn = __shfl_xor(h, 1);
            if ((j & 1) == 0) {
                uint32_t pk = (uint32_t)f2bf(h) | ((uint32_t)f2bf(hn) << 16);
                __hip_atomic_store(s1p + ((size_t)(t + 1) * 2 + path) * 4096 + b * 256 + (jg >> 1),
                                   pk, __ATOMIC_RELAXED, __HIP_MEMORY_SCOPE_AGENT);
            }
            post_cnt(&s1cnt[path * 16 + t]);
        }
    } else if (role == 1) {
        const int b = tid >> 4, j = tid & 15, jg = j0 + j;
        const float B0 = b2m_s[jg], B1 = b2m_s[512 + jg], B2 = b2m_s[1024 + jg], B3 = b2m_s[1536 + jg];
        for (int t = 0; t < 16; ++t) {
            wait_cnt(&s1cnt[t], 32);
            stage_state(xs, s1p + ((size_t)(t + 1) * 2 + 0) * 4096, tid);
            __syncthreads();
            f32x4 acc = {};
#pragma unroll
            for (int kk = 0; kk < 512; kk += 32) {
                bf16x8 a  = *(const bf16x8*)(xs + lrow * 520 + kk + kg);
                bf16x8 bw = *(const bf16x8*)(wlds + (w * 16 + lrow) * 520 + kk + kg);
                acc = __builtin_amdgcn_mfma_f32_16x16x32_bf16(a, bw, acc, 0, 0, 0);
            }
#pragma unroll
            for (int r = 0; r < 4; ++r)
                gbuf[0][(l >> 4) * 4 + r][w * 16 + lrow] = acc[r];
            __syncthreads();

            float G0 = gbuf[0][b][j * 4 + 0] + B0;
            float G1 = gbuf[0][b][j * 4 + 1] + B1;
            float G2 = gbuf[0][b][j * 4 + 2] + B2;
            float G3 = gbuf[0][b][j * 4 + 3] + B3;
            cv = sigm(G1) * cv + sigm(G0) * tanhf(G2);
            float h = sigm(G3) * tanhf(cv);
            out[262144 + ((size_t)b * 16 + t) * 1024 + 512 + jg] = h;
        }
    } else {
        const int b = tid >> 3, j = tid & 7, jg = j0 + j;
        float B0 = 0, B1 = 0, B2 = 0, B3 = 0;
        if (tid < 128) {
            B0 = b2a_s[jg]; B1 = b2a_s[512 + jg]; B2 = b2a_s[1024 + jg]; B3 = b2a_s[1536 + jg];
        }
        for (int t = 0; t < 16; ++t) {
            wait_cnt(&s1cnt[16 + t], 32);
            if (t > 0) wait_cnt(&s2acnt[t - 1], 64);
            stage_state(xs, s1p + ((size_t)(t + 1) * 2 + 1) * 4096, tid);
            stage_state(hs, s2ap + (size_t)t * 4096, tid);
            __syncthreads();
            const uint16_t* src = (w < 2) ? xs : hs;
            const int wt = (w < 2) ? w : w - 2;
            const int wb = (w < 2) ? 0 : 32 * 520;
            f32x4 acc = {};
#pragma unroll
            for (int kk = 0; kk < 512; kk += 32) {
                bf16x8 a  = *(const bf16x8*)(src + lrow * 520 + kk + kg);
                bf16x8 bw = *(const bf16x8*)(wlds + wb + (wt * 16 + lrow) * 520 + kk + kg);
                acc = __builtin_amdgcn_mfma_f32_16x16x32_bf16(a, bw, acc, 0, 0, 0);
            }
#pragma unroll
            for (int r = 0; r < 4; ++r)
                gbuf[w >> 1][(l >> 4) * 4 + r][wt * 16 + lrow] = acc[r];
            __syncthreads();

            if (tid < 128) {
                float G0 = gbuf[0][b][j * 4 + 0] + gbuf[1][b][j * 4 + 0] + B0;
                float G1 = gbuf[0][b][j * 4 + 1] + gbuf[1][b][j * 4 + 1] + B1;
                float G2 = gbuf[0][b][j * 4 + 2] + gbuf[1][b][j * 4 + 2] + B2;
                float G3 = gbuf[0][b][j * 4 + 3] + gbuf[1][b][j * 4 + 3] + B3;
                cv = sigm(G1) * cv + sigm(G0) * tanhf(G2);
                float h = sigm(G3) * tanhf(cv);
                out[((size_t)b * 16 + t) * 1024 + 512 + jg] = h;
                float hn = __shfl_xor(h, 1);
                if ((j & 1) == 0) {
                    uint32_t pk = (uint32_t)f2bf(h) | ((uint32_t)f2bf(hn) << 16);
                    __hip_atomic_store(s2ap + (size_t)(t + 1) * 4096 + b * 256 + (jg >> 1),
                                       pk, __ATOMIC_RELAXED, __HIP_MEMORY_SCOPE_AGENT);
                }
            }
            post_cnt(&s2acnt[t]);
        }
    }
}

// ---------------------------------------------------------------------------
extern "C" void kernel_launch(void* const* d_in, const int* in_sizes, int n_in,
                              void* d_out, int out_size, void* d_ws, size_t ws_size,
                              hipStream_t stream)
{
    (void)in_sizes; (void)n_in; (void)out_size; (void)ws_size;
    const float* f_t     = (const float*)d_in[0];
    const float* f_t_1   = (const float*)d_in[1];
    const float* att1    = (const float*)d_in[2];
    const float* att2    = (const float*)d_in[3];
    const float* conv1_w = (const float*)d_in[4];
    const float* conv1_b = (const float*)d_in[5];
    const float* conv2_w = (const float*)d_in[6];
    const float* conv2_b = (const float*)d_in[7];
    const float* l1a_wih = (const float*)d_in[8];
    const float* l1a_whh = (const float*)d_in[9];
    const float* l1a_bih = (const float*)d_in[10];
    const float* l1a_bhh = (const float*)d_in[11];
    const float* l2a_wih = (const float*)d_in[12];
    const float* l2a_whh = (const float*)d_in[13];
    const float* l2a_bih = (const float*)d_in[14];
    const float* l2a_bhh = (const float*)d_in[15];
    const float* l1m_wih = (const float*)d_in[16];
    const float* l1m_whh = (const float*)d_in[17];
    const float* l1m_bih = (const float*)d_in[18];
    const float* l1m_bhh = (const float*)d_in[19];
    const float* l2m_wih = (const float*)d_in[20];
    const float* l2m_whh = (const float*)d_in[21];
    const float* l2m_bih = (const float*)d_in[22];
    const float* l2m_bhh = (const float*)d_in[23];
    const float* fc1_w   = (const float*)d_in[24];
    const float* fc1_b   = (const float*)d_in[25];
    const float* fc2_w   = (const float*)d_in[26];
    const float* fc2_b   = (const float*)d_in[27];

    char* p = (char*)d_ws;
    // part (64MB, fc1 split-K=32 partials) aliases in1_nhwc (dead after conv1)
    float*    part     = (float*)p;
    uint16_t* in1_nhwc = (uint16_t*)p;             // [256][1024][128] bf16
    p += (size_t)64 << 20;
    uint16_t* c1out    = (uint16_t*)p; p += (size_t)32 << 20;  // [256][1024][64] NHWC
    uint16_t* mbuf16   = (uint16_t*)p; p += (size_t)32 << 20;  // [256][64][1024] NCHW
    uint16_t* ftflat16 = (uint16_t*)p; p += (size_t)32 << 20;  // [256][65536]
    uint16_t* wpack1   = (uint16_t*)p; p += 256 * 1024;
    uint16_t* wpack2   = (uint16_t*)p; p += 128 * 1024;
    uint16_t* hbuf16 = (uint16_t*)p; p += (size_t)2 << 20;
    uint16_t* inm  = (uint16_t*)p; p += (size_t)1 << 20;
    uint16_t* ina  = (uint16_t*)p; p += (size_t)1 << 20;
    float* gxm  = (float*)p; p += (size_t)2 << 20;
    float* gxa  = (float*)p; p += (size_t)2 << 20;
    uint16_t* pw1  = (uint16_t*)p; p += (size_t)2097152 * 2;
    uint16_t* pw2m = (uint16_t*)p; p += (size_t)1048576 * 2;
    uint16_t* pw2a = (uint16_t*)p; p += (size_t)2097152 * 2;
    float* b2m_s = (float*)p; p += 2048 * 4;
    float* b2a_s = (float*)p; p += 2048 * 4;
    uint32_t* s1p  = (uint32_t*)p; p += (size_t)17 * 2 * 4096 * 4;
    uint32_t* s2ap = (uint32_t*)p; p += (size_t)17 * 4096 * 4;
    int* s1cnt  = (int*)p; p += 32 * 4;
    int* s2acnt = (int*)p; p += 16 * 4;

    float* outp = (float*)d_out;
    float* alpha_out = outp + 524288;

    hipMemsetAsync(s1p, 0, 2 * 4096 * 4, stream);
    hipMemsetAsync(s2ap, 0, 4096 * 4, stream);
    hipMemsetAsync(s1cnt, 0, 48 * 4, stream);

    prep_all_kernel<<<15136, 256, 0, stream>>>(
        f_t, f_t_1, conv1_w, conv2_w,
        l1m_whh, l1a_whh, l2m_wih, l2m_whh, l2a_wih, l2a_whh,
        l2m_bih, l2m_bhh, l2a_bih, l2a_bhh,
        ftflat16, in1_nhwc, wpack1, wpack2,
        pw1, pw2m, pw2a, b2m_s, b2a_s);

    conv_mfma2_kernel<128, false><<<dim3(8, 256), 256, 0, stream>>>(
        in1_nhwc, wpack1, conv1_b, c1out);
    conv_mfma2_kernel<64, true><<<dim3(8, 256), 256, 0, stream>>>(
        c1out, wpack2, conv2_b, mbuf16);

    fc1_mfma_kernel<<<512, 256, 0, stream>>>(mbuf16, ftflat16, fc1_w, part);
    fc1_reduce_kernel<<<2048, 256, 0, stream>>>(part, fc1_b, hbuf16);

    fc2_att_mfma_kernel<<<dim3(4, 4), 256, 0, stream>>>(hbuf16, fc2_w, fc2_b, att1, att2,
                                                        alpha_out, inm, ina);

    gx_mfma_kernel<<<dim3(2, 16, 2), 256, 0, stream>>>(inm, ina,
                                                       l1m_wih, l1m_bih, l1m_bhh,
                                                       l1a_wih, l1a_bih, l1a_bhh,
                                                       gxm, gxa);

    lstm_scan5_kernel<<<NBLK, 256, 0, stream>>>(
        gxm, gxa, pw1, pw2m, pw2a, b2m_s, b2a_s,
        s1p, s2ap, s1cnt, s2acnt, outp);
}

// Round 18
// 519.843 us; speedup vs baseline: 1.2375x; 1.2375x over previous
//
#include <hip/hip_runtime.h>
#include <math.h>
#include <stdint.h>

typedef __attribute__((ext_vector_type(8))) short    bf16x8;
typedef __attribute__((ext_vector_type(4))) float    f32x4;
typedef __attribute__((ext_vector_type(8))) uint16_t u16x8;
typedef __attribute__((ext_vector_type(4))) uint16_t u16x4;

#define LSTR 40   // LDS row stride (bf16): 80B rows -> 2-way banks (free)
#define NBLK 160  // persistent LSTM blocks

__device__ __forceinline__ uint16_t f2bf(float f) {
    union { float f; uint32_t u; } v; v.f = f;
    uint32_t r = v.u + 0x7FFFu + ((v.u >> 16) & 1u);
    return (uint16_t)(r >> 16);
}

__device__ __forceinline__ float sigm(float x) { return 1.f / (1.f + expf(-x)); }

// packed RNE f32x2 -> bf16x2
__device__ __forceinline__ uint32_t cvtpk(float lo, float hi) {
    uint32_t r;
    asm volatile("v_cvt_pk_bf16_f32 %0, %1, %2" : "=v"(r) : "v"(lo), "v"(hi));
    return r;
}

// ---------------------------------------------------------------------------
// prep (fused): blocks [0,8192) cvt_flat (coalesced), [8192,12288) nhwc,
// [12288,12576) wpack, [12576,15136) lstm_pack.
// ---------------------------------------------------------------------------
__global__ __launch_bounds__(256) void prep_all_kernel(
    const float* __restrict__ f_t, const float* __restrict__ f_t_1,
    const float* __restrict__ w1, const float* __restrict__ w2,
    const float* __restrict__ whh_m, const float* __restrict__ whh_a,
    const float* __restrict__ m_wih, const float* __restrict__ m_whh,
    const float* __restrict__ a_wih, const float* __restrict__ a_whh,
    const float* __restrict__ m_bih, const float* __restrict__ m_bhh,
    const float* __restrict__ a_bih, const float* __restrict__ a_bhh,
    uint16_t* __restrict__ ftflat16, uint16_t* __restrict__ in1_nhwc,
    uint16_t* __restrict__ p1, uint16_t* __restrict__ p2,
    uint16_t* __restrict__ pw1, uint16_t* __restrict__ pw2m,
    uint16_t* __restrict__ pw2a,
    float* __restrict__ b2m_s, float* __restrict__ b2a_s)
{
    __shared__ float lds[32][258];
    const int bid = blockIdx.x;
    const int tid = threadIdx.x;

    if (bid < 8192) {
        int i = (bid * 256 + tid) * 8;
        float4 a = *(const float4*)(f_t + i);
        float4 b = *(const float4*)(f_t + i + 4);
        u16x8 o;
        o[0] = f2bf(a.x); o[1] = f2bf(a.y); o[2] = f2bf(a.z); o[3] = f2bf(a.w);
        o[4] = f2bf(b.x); o[5] = f2bf(b.y); o[6] = f2bf(b.z); o[7] = f2bf(b.w);
        *(u16x8*)(ftflat16 + i) = o;
    } else if (bid < 12288) {
        const int v   = bid - 8192;
        const int bt  = v >> 4;
        const int c0  = ((v & 15) >> 2) * 32;
        const int px0 = (v & 3) * 256;
        const int lc  = tid & 31;
        const int lpx = (tid >> 5) * 32;
        const int c   = c0 + lc;
        const float* src = (c < 64)
            ? (f_t   + ((size_t)bt * 64 + c) * 1024)
            : (f_t_1 + ((size_t)bt * 64 + (c - 64)) * 1024);
#pragma unroll
        for (int j = 0; j < 32; j += 4) {
            float4 vv = *(const float4*)(src + px0 + lpx + j);
            lds[lc][lpx + j + 0] = vv.x;
            lds[lc][lpx + j + 1] = vv.y;
            lds[lc][lpx + j + 2] = vv.z;
            lds[lc][lpx + j + 3] = vv.w;
        }
        __syncthreads();
        uint16_t* op = in1_nhwc + ((size_t)bt * 1024 + px0 + tid) * 128 + c0;
#pragma unroll
        for (int u0 = 0; u0 < 32; u0 += 8) {
            u16x8 o;
#pragma unroll
            for (int u = 0; u < 8; ++u) o[u] = f2bf(lds[u0 + u][tid]);
            *(u16x8*)(op + u0) = o;
        }
    } else if (bid < 12576) {
        int i = (bid - 12288) * 256 + tid;
        if (i < 64 * 1152) {
            int oc = i / 1152, k = i - oc * 1152;
            int s = k >> 7, c = k & 127;
            int ky = s / 3, kx = s - ky * 3;
            p1[i] = f2bf(w1[((oc * 128 + c) * 3 + ky) * 3 + kx]);
        }
        if (i < 64 * 576) {
            int oc = i / 576, k = i - oc * 576;
            int s = k >> 6, c = k & 63;
            int ky = s / 3, kx = s - ky * 3;
            p2[i] = f2bf(w2[((oc * 64 + c) * 3 + ky) * 3 + kx]);
        }
    } else {
        int id = (bid - 12576) * 256 + tid;
        if (id < 2048) {
            b2m_s[id] = m_bih[id] + m_bhh[id];
            b2a_s[id] = a_bih[id] + a_bhh[id];
        }
        if (id < 262144) {                       // pw1
            int kc = id & 63, g = (id >> 6) & 3, j = (id >> 8) & 511, pp = id >> 17;
            const float* src = (pp ? whh_a : whh_m) + ((size_t)(g * 512 + j)) * 512 + kc * 8;
            uint16_t* dst = pw1 + ((((size_t)pp * 32 + (j >> 4)) * 64 + (j & 15) * 4 + g) * 512) + kc * 8;
            float4 a = *(const float4*)src; float4 b = *(const float4*)(src + 4);
            u16x8 o;
            o[0]=f2bf(a.x); o[1]=f2bf(a.y); o[2]=f2bf(a.z); o[3]=f2bf(a.w);
            o[4]=f2bf(b.x); o[5]=f2bf(b.y); o[6]=f2bf(b.z); o[7]=f2bf(b.w);
            *(u16x8*)dst = o;
        } else if (id < 393216) {                // pw2m (sum)
            int id2 = id - 262144;
            int kc = id2 & 63, g = (id2 >> 6) & 3, j = id2 >> 8;
            size_t off = ((size_t)(g * 512 + j)) * 512 + kc * 8;
            const float* s1 = m_wih + off; const float* s2 = m_whh + off;
            uint16_t* dst = pw2m + (((size_t)(j >> 4)) * 64 + (j & 15) * 4 + g) * 512 + kc * 8;
            u16x8 o;
#pragma unroll
            for (int u = 0; u < 8; ++u) o[u] = f2bf(s1[u] + s2[u]);
            *(u16x8*)dst = o;
        } else if (id < 655360) {                // pw2a
            int id3 = id - 393216;
            int kc = id3 & 63, g = (id3 >> 6) & 3, j = (id3 >> 8) & 511, mat = id3 >> 17;
            const float* src = (mat ? a_whh : a_wih) + ((size_t)(g * 512 + j)) * 512 + kc * 8;
            uint16_t* dst = pw2a + ((((size_t)(j >> 3)) * 2 + mat) * 32 + (j & 7) * 4 + g) * 512 + kc * 8;
            float4 a = *(const float4*)src; float4 b = *(const float4*)(src + 4);
            u16x8 o;
            o[0]=f2bf(a.x); o[1]=f2bf(a.y); o[2]=f2bf(a.z); o[3]=f2bf(a.w);
            o[4]=f2bf(b.x); o[5]=f2bf(b.y); o[6]=f2bf(b.z); o[7]=f2bf(b.w);
            *(u16x8*)dst = o;
        }
    }
}

// ---------------------------------------------------------------------------
// conv3x3 + bias + relu, implicit-GEMM MFMA, halo staged ONCE per block
// (R16-exact: Bw staged in LDS per tap — coalesced W reads, proven best).
// ---------------------------------------------------------------------------
template<int IC, bool SWAP>
__global__ __launch_bounds__(256) void conv_mfma2_kernel(
    const uint16_t* __restrict__ in_nhwc,
    const uint16_t* __restrict__ wpack,
    const float* __restrict__ bias,
    uint16_t* __restrict__ out)
{
    constexpr int ICP = IC + 8;
    constexpr int KT  = 9 * IC;
    constexpr int CPS = IC / 32;
    constexpr int C8  = IC / 8;
    constexpr int MF  = SWAP ? 4 : 2;
    constexpr int NF  = SWAP ? 2 : 4;

    __shared__ __align__(16) uint16_t Ah[6 * 34 * ICP];
    __shared__ __align__(16) uint16_t Bw[64 * LSTR];

    const int bt  = blockIdx.y;
    const int px0 = blockIdx.x * 128;
    const int y0  = blockIdx.x * 4;
    const int tid = threadIdx.x;
    const int w   = tid >> 6, l = tid & 63;
    const int lrow = l & 15, kg = (l >> 4) * 8;

    for (int idx = tid; idx < 204 * C8; idx += 256) {
        int cpos = idx / C8;
        int c8   = (idx - cpos * C8) * 8;
        int hy = cpos / 34, hx = cpos - hy * 34;
        int gy = y0 - 1 + hy, gx = hx - 1;
        u16x8 v = {};
        if (gy >= 0 && gy < 32 && gx >= 0 && gx < 32)
            v = *(const u16x8*)(in_nhwc + (((size_t)bt * 1024) + gy * 32 + gx) * IC + c8);
        *(u16x8*)(Ah + (hy * 34 + hx) * ICP + c8) = v;
    }

    const int oc_s = tid >> 2, kslot = tid & 3;

    f32x4 acc[MF][NF] = {};

    int abase[MF > NF ? MF : 2];
#pragma unroll
    for (int i = 0; i < (SWAP ? 2 : MF); ++i) {
        int m  = w * 32 + i * 16 + lrow;
        int py = m >> 5, px = m & 31;
        abase[i] = (py * 34 + px) * ICP;
    }

    for (int q = 0; q < 9 * CPS; ++q) {
        const int s  = q / CPS, cc = (q - s * CPS) * 32;
        const int ky = s / 3,  kx = s - ky * 3;
        const int aoff = (ky * 34 + kx) * ICP + cc + kg;

        u16x8 b0 = *(const u16x8*)(wpack + (size_t)oc_s * KT + q * 32 + kslot * 8);
        __syncthreads();
        *(u16x8*)(Bw + oc_s * LSTR + kslot * 8) = b0;
        __syncthreads();

        if (!SWAP) {
            bf16x8 af[2], bf[4];
#pragma unroll
            for (int i = 0; i < 2; ++i)
                af[i] = *(const bf16x8*)(Ah + abase[i] + aoff);
#pragma unroll
            for (int j = 0; j < 4; ++j)
                bf[j] = *(const bf16x8*)(Bw + (j * 16 + lrow) * LSTR + kg);
#pragma unroll
            for (int i = 0; i < MF; ++i)
#pragma unroll
                for (int j = 0; j < NF; ++j)
                    acc[i][j] = __builtin_amdgcn_mfma_f32_16x16x32_bf16(
                        af[i], bf[j], acc[i][j], 0, 0, 0);
        } else {
            bf16x8 af[4], bf[2];
#pragma unroll
            for (int i = 0; i < 4; ++i)
                af[i] = *(const bf16x8*)(Bw + (i * 16 + lrow) * LSTR + kg);
#pragma unroll
            for (int j = 0; j < 2; ++j)
                bf[j] = *(const bf16x8*)(Ah + abase[j] + aoff);
#pragma unroll
            for (int i = 0; i < MF; ++i)
#pragma unroll
                for (int j = 0; j < NF; ++j)
                    acc[i][j] = __builtin_amdgcn_mfma_f32_16x16x32_bf16(
                        af[i], bf[j], acc[i][j], 0, 0, 0);
        }
    }

    const int col = l & 15, rg = (l >> 4) * 4;
    if (!SWAP) {
#pragma unroll
        for (int i = 0; i < 2; ++i)
#pragma unroll
            for (int j = 0; j < 4; ++j) {
                const int ocb = j * 16 + col;
                const float bv = bias[ocb];
#pragma unroll
                for (int r = 0; r < 4; ++r) {
                    const int px = px0 + w * 32 + i * 16 + rg + r;
                    float v = acc[i][j][r] + bv; v = v > 0.f ? v : 0.f;
                    out[((size_t)bt * 1024 + px) * 64 + ocb] = f2bf(v);
                }
            }
    } else {
#pragma unroll
        for (int i = 0; i < 4; ++i)
#pragma unroll
            for (int j = 0; j < 2; ++j)
#pragma unroll
                for (int r = 0; r < 4; ++r) {
                    const int oc = i * 16 + rg + r;
                    const int px = px0 + w * 32 + j * 16 + col;
                    float v = acc[i][j][r] + bias[oc]; v = v > 0.f ? v : 0.f;
                    out[((size_t)bt * 64 + oc) * 1024 + px] = f2bf(v);
                }
    }
}

// ---------------------------------------------------------------------------
// fc1 MFMA (R7 geometry + coalesced slot staging): BM=256, BN=128, BK=32,
// split-K=32, grid 512; 32 MFMAs per barrier pair.
// ---------------------------------------------------------------------------
__global__ __launch_bounds__(256) void fc1_mfma_kernel(
    const uint16_t* __restrict__ Am, const uint16_t* __restrict__ Af,
    const float* __restrict__ Wf, float* __restrict__ part)
{
    __shared__ __align__(16) uint16_t Aa[256 * LSTR];
    __shared__ __align__(16) uint16_t Bb[128 * LSTR];

    const int id  = blockIdx.x;
    const int vid = (id & 7) * 64 + (id >> 3);   // 512 % 8 == 0 -> bijective
    const int bx  = vid & 1;
    const int by  = (vid >> 1) & 7;
    const int ks  = vid >> 4;

    const int row0 = bx * 256;
    const int col0 = by * 128;
    const size_t kbase = (size_t)ks * 2048;
    const uint16_t* Abase = bx ? Af : Am;

    const int tid = threadIdx.x;
    const int w = tid >> 6, l = tid & 63;
    const int lrow = l & 15, kg = (l >> 4) * 8;

    const int arow = tid >> 2, achk = (tid & 3) * 8;
    const int brow = tid >> 3, bchk = (tid & 7) * 4;

    f32x4 acc[4][8] = {};

    for (int kk = 0; kk < 2048; kk += 32) {
        u16x8 ra[4];
        float4 rb[4];
#pragma unroll
        for (int i = 0; i < 4; ++i)
            ra[i] = *(const u16x8*)(Abase + (size_t)(i * 64 + arow) * 65536 + kbase + kk + achk);
#pragma unroll
        for (int i = 0; i < 4; ++i)
            rb[i] = *(const float4*)(Wf + (size_t)(col0 + i * 32 + brow) * 65536 + kbase + kk + bchk);

        union { u16x4 v; uint32_t u[2]; } cb[4];
#pragma unroll
        for (int i = 0; i < 4; ++i) {
            cb[i].u[0] = cvtpk(rb[i].x, rb[i].y);
            cb[i].u[1] = cvtpk(rb[i].z, rb[i].w);
        }

        __syncthreads();
#pragma unroll
        for (int i = 0; i < 4; ++i)
            *(u16x8*)(Aa + (i * 64 + arow) * LSTR + achk) = ra[i];
#pragma unroll
        for (int i = 0; i < 4; ++i)
            *(u16x4*)(Bb + (i * 32 + brow) * LSTR + bchk) = cb[i].v;
        __syncthreads();

        bf16x8 afr[4], bfr[8];
#pragma unroll
        for (int i = 0; i < 4; ++i)
            afr[i] = *(const bf16x8*)(Aa + (w * 64 + i * 16 + lrow) * LSTR + kg);
#pragma unroll
        for (int j = 0; j < 8; ++j)
            bfr[j] = *(const bf16x8*)(Bb + (j * 16 + lrow) * LSTR + kg);
#pragma unroll
        for (int i = 0; i < 4; ++i)
#pragma unroll
            for (int j = 0; j < 8; ++j)
                acc[i][j] = __builtin_amdgcn_mfma_f32_16x16x32_bf16(
                    afr[i], bfr[j], acc[i][j], 0, 0, 0);
    }

    const int col = l & 15, rg = (l >> 4) * 4;
#pragma unroll
    for (int i = 0; i < 4; ++i)
#pragma unroll
        for (int r = 0; r < 4; ++r) {
            const int grow = row0 + w * 64 + i * 16 + rg + r;
            float* op = part + ((size_t)ks * 512 + grow) * 1024 + col0 + col;
#pragma unroll
            for (int j = 0; j < 8; ++j) op[j * 16] = acc[i][j][r];
        }
}

__global__ __launch_bounds__(256) void fc1_reduce_kernel(
    const float* __restrict__ part, const float* __restrict__ bias,
    uint16_t* __restrict__ h16)
{
    int idx = blockIdx.x * 256 + threadIdx.x;
    int j = idx & 1023;
    float s = bias[j];
#pragma unroll
    for (int ks = 0; ks < 32; ++ks) s += part[(size_t)ks * 524288 + idx];
    h16[idx] = f2bf(s > 0.f ? s : 0.f);
}

// ---------------------------------------------------------------------------
// fc2 MFMA + attention epilogue.  A = hbuf bf16; outputs inm/ina bf16.
// ---------------------------------------------------------------------------
__global__ __launch_bounds__(256) void fc2_att_mfma_kernel(
    const uint16_t* __restrict__ h16, const float* __restrict__ wf,
    const float* __restrict__ bias,
    const float* __restrict__ att1, const float* __restrict__ att2,
    float* __restrict__ alpha_out, uint16_t* __restrict__ inm, uint16_t* __restrict__ ina)
{
    __shared__ __align__(16) uint16_t Aa[128 * LSTR];
    __shared__ __align__(16) uint16_t Bb[128 * LSTR];

    const int row0 = blockIdx.x * 128;
    const int col0 = blockIdx.y * 128;

    const int t = threadIdx.x;
    const int w = t >> 6, l = t & 63;
    const int wr = (w >> 1) * 64, wc = (w & 1) * 64;

    const int srow  = t >> 1;
    const int shalf = (t & 1) * 16;
    const uint16_t* ap = h16 + (size_t)(row0 + srow) * 1024 + shalf;
    const float*    bp = wf  + (size_t)(col0 + srow) * 1024 + shalf;
    uint16_t* awr = Aa + srow * LSTR + shalf;
    uint16_t* bwr = Bb + srow * LSTR + shalf;

    f32x4 acc[4][4] = {};

    for (int kk = 0; kk < 1024; kk += 32) {
        u16x8 a0 = *(const u16x8*)(ap + kk);
        u16x8 a1 = *(const u16x8*)(ap + kk + 8);
        float4 f0 = *(const float4*)(bp + kk);
        float4 f1 = *(const float4*)(bp + kk + 4);
        float4 f2 = *(const float4*)(bp + kk + 8);
        float4 f3 = *(const float4*)(bp + kk + 12);
        union { u16x8 v; uint32_t u[4]; } b0, b1;
        b0.u[0] = cvtpk(f0.x, f0.y); b0.u[1] = cvtpk(f0.z, f0.w);
        b0.u[2] = cvtpk(f1.x, f1.y); b0.u[3] = cvtpk(f1.z, f1.w);
        b1.u[0] = cvtpk(f2.x, f2.y); b1.u[1] = cvtpk(f2.z, f2.w);
        b1.u[2] = cvtpk(f3.x, f3.y); b1.u[3] = cvtpk(f3.z, f3.w);

        __syncthreads();
        *(u16x8*)awr       = a0;
        *(u16x8*)(awr + 8) = a1;
        *(u16x8*)bwr       = b0.v;
        *(u16x8*)(bwr + 8) = b1.v;
        __syncthreads();

        const int row = l & 15, kg = (l >> 4) * 8;
        bf16x8 afr[4], bfr[4];
#pragma unroll
        for (int i = 0; i < 4; ++i)
            afr[i] = *(const bf16x8*)(Aa + (wr + i * 16 + row) * LSTR + kg);
#pragma unroll
        for (int j = 0; j < 4; ++j)
            bfr[j] = *(const bf16x8*)(Bb + (wc + j * 16 + row) * LSTR + kg);
#pragma unroll
        for (int i = 0; i < 4; ++i)
#pragma unroll
            for (int j = 0; j < 4; ++j)
                acc[i][j] = __builtin_amdgcn_mfma_f32_16x16x32_bf16(
                    afr[i], bfr[j], acc[i][j], 0, 0, 0);
    }

    const int col = l & 15, rg = (l >> 4) * 4;
#pragma unroll
    for (int i = 0; i < 4; ++i)
#pragma unroll
        for (int r = 0; r < 4; ++r) {
            const int row = row0 + wr + i * 16 + rg + r;
            const int bt  = row & 255;
            const int b = bt >> 4, tt = bt & 15;
            const size_t ibase = ((size_t)tt * 16 + b) * 1024;
#pragma unroll
            for (int j = 0; j < 4; ++j) {
                const int jj = col0 + wc + j * 16 + col;
                float v = acc[i][j][r] + bias[jj];
                if (row < 256) {
                    float al = sigm(att1[b * 512 + jj] * v);
                    alpha_out[(size_t)bt * 512 + jj] = al;
                    inm[ibase + jj]       = f2bf(al * v);
                    inm[ibase + 512 + jj] = f2bf(v);
                } else {
                    float be = sigm(att2[b * 512 + jj] * v);
                    ina[ibase + jj]       = f2bf(be * v);
                    ina[ibase + 512 + jj] = f2bf(v);
                }
            }
        }
}

// ---------------------------------------------------------------------------
// gx MFMA: gates x-projection, M=256, N=2048, K=1024, grid (2,16,2 paths).
// ---------------------------------------------------------------------------
__global__ __launch_bounds__(256) void gx_mfma_kernel(
    const uint16_t* __restrict__ inm, const uint16_t* __restrict__ ina,
    const float* __restrict__ wih_m, const float* __restrict__ bih_m, const float* __restrict__ bhh_m,
    const float* __restrict__ wih_a, const float* __restrict__ bih_a, const float* __restrict__ bhh_a,
    float* __restrict__ gxm, float* __restrict__ gxa)
{
    __shared__ __align__(16) uint16_t Aa[128 * LSTR];
    __shared__ __align__(16) uint16_t Bb[128 * LSTR];

    const int row0 = blockIdx.x * 128;
    const int col0 = blockIdx.y * 128;
    const int path = blockIdx.z;

    const uint16_t* A = path ? ina : inm;
    const float* W  = path ? wih_a : wih_m;
    const float* bi = path ? bih_a : bih_m;
    const float* bh = path ? bhh_a : bhh_m;
    float* out = path ? gxa : gxm;

    const int t = threadIdx.x;
    const int w = t >> 6, l = t & 63;
    const int wr = (w >> 1) * 64, wc = (w & 1) * 64;

    const int srow  = t >> 1;
    const int shalf = (t & 1) * 16;
    const uint16_t* ap = A + (size_t)(row0 + srow) * 1024 + shalf;
    const float*    bp = W + (size_t)(col0 + srow) * 1024 + shalf;
    uint16_t* awr = Aa + srow * LSTR + shalf;
    uint16_t* bwr = Bb + srow * LSTR + shalf;

    f32x4 acc[4][4] = {};

    for (int kk = 0; kk < 1024; kk += 32) {
        u16x8 a0 = *(const u16x8*)(ap + kk);
        u16x8 a1 = *(const u16x8*)(ap + kk + 8);
        float4 f0 = *(const float4*)(bp + kk);
        float4 f1 = *(const float4*)(bp + kk + 4);
        float4 f2 = *(const float4*)(bp + kk + 8);
        float4 f3 = *(const float4*)(bp + kk + 12);
        union { u16x8 v; uint32_t u[4]; } b0, b1;
        b0.u[0] = cvtpk(f0.x, f0.y); b0.u[1] = cvtpk(f0.z, f0.w);
        b0.u[2] = cvtpk(f1.x, f1.y); b0.u[3] = cvtpk(f1.z, f1.w);
        b1.u[0] = cvtpk(f2.x, f2.y); b1.u[1] = cvtpk(f2.z, f2.w);
        b1.u[2] = cvtpk(f3.x, f3.y); b1.u[3] = cvtpk(f3.z, f3.w);

        __syncthreads();
        *(u16x8*)awr       = a0;
        *(u16x8*)(awr + 8) = a1;
        *(u16x8*)bwr       = b0.v;
        *(u16x8*)(bwr + 8) = b1.v;
        __syncthreads();

        const int row = l & 15, kg = (l >> 4) * 8;
        bf16x8 afr[4], bfr[4];
#pragma unroll
        for (int i = 0; i < 4; ++i)
            afr[i] = *(const bf16x8*)(Aa + (wr + i * 16 + row) * LSTR + kg);
#pragma unroll
        for (int j = 0; j < 4; ++j)
            bfr[j] = *(const bf16x8*)(Bb + (wc + j * 16 + row) * LSTR + kg);
#pragma unroll
        for (int i = 0; i < 4; ++i)
#pragma unroll
            for (int j = 0; j < 4; ++j)
                acc[i][j] = __builtin_amdgcn_mfma_f32_16x16x32_bf16(
                    afr[i], bfr[j], acc[i][j], 0, 0, 0);
    }

    const int col = l & 15, rg = (l >> 4) * 4;
#pragma unroll
    for (int i = 0; i < 4; ++i)
#pragma unroll
        for (int r = 0; r < 4; ++r) {
            const int grow = row0 + wr + i * 16 + rg + r;
#pragma unroll
            for (int j = 0; j < 4; ++j) {
                const int jj = col0 + wc + j * 16 + col;
                out[(size_t)grow * 2048 + jj] = acc[i][j][r] + bi[jj] + bh[jj];
            }
        }
}

// ---------------------------------------------------------------------------
// Persistent LSTM scan v5b: fence-free point-to-point sync (IC-coherent).
// ---------------------------------------------------------------------------
__device__ __forceinline__ void wait_cnt(int* cnt, int target) {
    if (threadIdx.x == 0) {
        while (__hip_atomic_load(cnt, __ATOMIC_RELAXED, __HIP_MEMORY_SCOPE_AGENT) < target)
            __builtin_amdgcn_s_sleep(1);
    }
    __syncthreads();
}

__device__ __forceinline__ void post_cnt(int* cnt) {
    __syncthreads();   // drains vmcnt(0): all waves' sc1 stores reached the IC
    if (threadIdx.x == 0)
        __hip_atomic_fetch_add(cnt, 1, __ATOMIC_RELAXED, __HIP_MEMORY_SCOPE_AGENT);
}

__device__ __forceinline__ void stage_state(uint16_t* dst, const uint32_t* src, int tid) {
#pragma unroll
    for (int i = 0; i < 4; ++i) {
        const int idx = i * 1024 + tid * 4;
        uint4 v = *(const uint4*)(src + idx);
        const int flat = idx * 2;
        union { uint4 q; u16x8 h; } cv; cv.q = v;
        *(u16x8*)(dst + (flat >> 9) * 520 + (flat & 511)) = cv.h;
    }
}

__global__ __launch_bounds__(256, 1) void lstm_scan5_kernel(
    const float* __restrict__ gxm, const float* __restrict__ gxa,
    const uint16_t* __restrict__ pw1, const uint16_t* __restrict__ pw2m,
    const uint16_t* __restrict__ pw2a,
    const float* __restrict__ b2m_s, const float* __restrict__ b2a_s,
    uint32_t* __restrict__ s1p, uint32_t* __restrict__ s2ap,
    int* __restrict__ s1cnt, int* __restrict__ s2acnt,
    float* __restrict__ out)
{
    __shared__ __align__(16) uint16_t wlds[64 * 520];
    __shared__ __align__(16) uint16_t xs[16 * 520];
    __shared__ __align__(16) uint16_t hs[16 * 520];
    __shared__ float gbuf[2][16][68];

    const int bk  = blockIdx.x;
    const int tid = threadIdx.x;
    const int w   = tid >> 6, l = tid & 63;
    const int lrow = l & 15, kg = (l >> 4) * 8;

    const int role = (bk < 64) ? 0 : (bk < 96) ? 1 : 2;   // S1, S2M, S2A
    const int path = (role == 0) ? (bk >> 5) : (role == 1 ? 0 : 1);
    const int tile = (role == 0) ? (bk & 31) : (role == 1 ? bk - 64 : bk - 96);
    const int j0   = tile * ((role == 2) ? 8 : 16);

    const uint16_t* wsrc =
        (role == 0) ? pw1 + ((size_t)path * 32 + tile) * 64 * 512 :
        (role == 1) ? pw2m + (size_t)tile * 64 * 512
                    : pw2a + (size_t)tile * 64 * 512;
    for (int idx = tid; idx < 64 * 64; idx += 256) {
        int row = idx >> 6, c = idx & 63;
        *(u16x8*)(wlds + row * 520 + c * 8) = *(const u16x8*)(wsrc + row * 512 + c * 8);
    }

    float cv = 0.f;
    const float* gx1 = path ? gxa : gxm;

    if (role == 0) {
        const int b = tid >> 4, j = tid & 15, jg = j0 + j;
        const size_t obase = path ? 0 : 262144;
        for (int t = 0; t < 16; ++t) {
            const float* gxr = gx1 + ((size_t)(t * 16 + b)) * 2048;
            float g0 = gxr[jg], g1 = gxr[512 + jg], g2 = gxr[1024 + jg], g3 = gxr[1536 + jg];
            if (t > 0) wait_cnt(&s1cnt[path * 16 + t - 1], 32);
            stage_state(xs, s1p + ((size_t)t * 2 + path) * 4096, tid);
            __syncthreads();
            f32x4 acc = {};
#pragma unroll
            for (int kk = 0; kk < 512; kk += 32) {
                bf16x8 a  = *(const bf16x8*)(xs + lrow * 520 + kk + kg);
                bf16x8 bw = *(const bf16x8*)(wlds + (w * 16 + lrow) * 520 + kk + kg);
                acc = __builtin_amdgcn_mfma_f32_16x16x32_bf16(a, bw, acc, 0, 0, 0);
            }
#pragma unroll
            for (int r = 0; r < 4; ++r)
                gbuf[0][(l >> 4) * 4 + r][w * 16 + lrow] = acc[r];
            __syncthreads();

            float G0 = gbuf[0][b][j * 4 + 0] + g0;
            float G1 = gbuf[0][b][j * 4 + 1] + g1;
            float G2 = gbuf[0][b][j * 4 + 2] + g2;
            float G3 = gbuf[0][b][j * 4 + 3] + g3;
            cv = sigm(G1) * cv + sigm(G0) * tanhf(G2);
            float h = sigm(G3) * tanhf(cv);
            out[obase + ((size_t)b * 16 + t) * 1024 + jg] = h;
            float hn = __shfl_xor(h, 1);
            if ((j & 1) == 0) {
                uint32_t pk = (uint32_t)f2bf(h) | ((uint32_t)f2bf(hn) << 16);
                __hip_atomic_store(s1p + ((size_t)(t + 1) * 2 + path) * 4096 + b * 256 + (jg >> 1),
                                   pk, __ATOMIC_RELAXED, __HIP_MEMORY_SCOPE_AGENT);
            }
            post_cnt(&s1cnt[path * 16 + t]);
        }
    } else if (role == 1) {
        const int b = tid >> 4, j = tid & 15, jg = j0 + j;
        const float B0 = b2m_s[jg], B1 = b2m_s[512 + jg], B2 = b2m_s[1024 + jg], B3 = b2m_s[1536 + jg];
        for (int t = 0; t < 16; ++t) {
            wait_cnt(&s1cnt[t], 32);
            stage_state(xs, s1p + ((size_t)(t + 1) * 2 + 0) * 4096, tid);
            __syncthreads();
            f32x4 acc = {};
#pragma unroll
            for (int kk = 0; kk < 512; kk += 32) {
                bf16x8 a  = *(const bf16x8*)(xs + lrow * 520 + kk + kg);
                bf16x8 bw = *(const bf16x8*)(wlds + (w * 16 + lrow) * 520 + kk + kg);
                acc = __builtin_amdgcn_mfma_f32_16x16x32_bf16(a, bw, acc, 0, 0, 0);
            }
#pragma unroll
            for (int r = 0; r < 4; ++r)
                gbuf[0][(l >> 4) * 4 + r][w * 16 + lrow] = acc[r];
            __syncthreads();

            float G0 = gbuf[0][b][j * 4 + 0] + B0;
            float G1 = gbuf[0][b][j * 4 + 1] + B1;
            float G2 = gbuf[0][b][j * 4 + 2] + B2;
            float G3 = gbuf[0][b][j * 4 + 3] + B3;
            cv = sigm(G1) * cv + sigm(G0) * tanhf(G2);
            float h = sigm(G3) * tanhf(cv);
            out[262144 + ((size_t)b * 16 + t) * 1024 + 512 + jg] = h;
        }
    } else {
        const int b = tid >> 3, j = tid & 7, jg = j0 + j;
        float B0 = 0, B1 = 0, B2 = 0, B3 = 0;
        if (tid < 128) {
            B0 = b2a_s[jg]; B1 = b2a_s[512 + jg]; B2 = b2a_s[1024 + jg]; B3 = b2a_s[1536 + jg];
        }
        for (int t = 0; t < 16; ++t) {
            wait_cnt(&s1cnt[16 + t], 32);
            if (t > 0) wait_cnt(&s2acnt[t - 1], 64);
            stage_state(xs, s1p + ((size_t)(t + 1) * 2 + 1) * 4096, tid);
            stage_state(hs, s2ap + (size_t)t * 4096, tid);
            __syncthreads();
            const uint16_t* src = (w < 2) ? xs : hs;
            const int wt = (w < 2) ? w : w - 2;
            const int wb = (w < 2) ? 0 : 32 * 520;
            f32x4 acc = {};
#pragma unroll
            for (int kk = 0; kk < 512; kk += 32) {
                bf16x8 a  = *(const bf16x8*)(src + lrow * 520 + kk + kg);
                bf16x8 bw = *(const bf16x8*)(wlds + wb + (wt * 16 + lrow) * 520 + kk + kg);
                acc = __builtin_amdgcn_mfma_f32_16x16x32_bf16(a, bw, acc, 0, 0, 0);
            }
#pragma unroll
            for (int r = 0; r < 4; ++r)
                gbuf[w >> 1][(l >> 4) * 4 + r][wt * 16 + lrow] = acc[r];
            __syncthreads();

            if (tid < 128) {
                float G0 = gbuf[0][b][j * 4 + 0] + gbuf[1][b][j * 4 + 0] + B0;
                float G1 = gbuf[0][b][j * 4 + 1] + gbuf[1][b][j * 4 + 1] + B1;
                float G2 = gbuf[0][b][j * 4 + 2] + gbuf[1][b][j * 4 + 2] + B2;
                float G3 = gbuf[0][b][j * 4 + 3] + gbuf[1][b][j * 4 + 3] + B3;
                cv = sigm(G1) * cv + sigm(G0) * tanhf(G2);
                float h = sigm(G3) * tanhf(cv);
                out[((size_t)b * 16 + t) * 1024 + 512 + jg] = h;
                float hn = __shfl_xor(h, 1);
                if ((j & 1) == 0) {
                    uint32_t pk = (uint32_t)f2bf(h) | ((uint32_t)f2bf(hn) << 16);
                    __hip_atomic_store(s2ap + (size_t)(t + 1) * 4096 + b * 256 + (jg >> 1),
                                       pk, __ATOMIC_RELAXED, __HIP_MEMORY_SCOPE_AGENT);
                }
            }
            post_cnt(&s2acnt[t]);
        }
    }
}

// ---------------------------------------------------------------------------
extern "C" void kernel_launch(void* const* d_in, const int* in_sizes, int n_in,
                              void* d_out, int out_size, void* d_ws, size_t ws_size,
                              hipStream_t stream)
{
    (void)in_sizes; (void)n_in; (void)out_size; (void)ws_size;
    const float* f_t     = (const float*)d_in[0];
    const float* f_t_1   = (const float*)d_in[1];
    const float* att1    = (const float*)d_in[2];
    const float* att2    = (const float*)d_in[3];
    const float* conv1_w = (const float*)d_in[4];
    const float* conv1_b = (const float*)d_in[5];
    const float* conv2_w = (const float*)d_in[6];
    const float* conv2_b = (const float*)d_in[7];
    const float* l1a_wih = (const float*)d_in[8];
    const float* l1a_whh = (const float*)d_in[9];
    const float* l1a_bih = (const float*)d_in[10];
    const float* l1a_bhh = (const float*)d_in[11];
    const float* l2a_wih = (const float*)d_in[12];
    const float* l2a_whh = (const float*)d_in[13];
    const float* l2a_bih = (const float*)d_in[14];
    const float* l2a_bhh = (const float*)d_in[15];
    const float* l1m_wih = (const float*)d_in[16];
    const float* l1m_whh = (const float*)d_in[17];
    const float* l1m_bih = (const float*)d_in[18];
    const float* l1m_bhh = (const float*)d_in[19];
    const float* l2m_wih = (const float*)d_in[20];
    const float* l2m_whh = (const float*)d_in[21];
    const float* l2m_bih = (const float*)d_in[22];
    const float* l2m_bhh = (const float*)d_in[23];
    const float* fc1_w   = (const float*)d_in[24];
    const float* fc1_b   = (const float*)d_in[25];
    const float* fc2_w   = (const float*)d_in[26];
    const float* fc2_b   = (const float*)d_in[27];

    char* p = (char*)d_ws;
    // part (64MB, fc1 split-K=32 partials) aliases in1_nhwc (dead after conv1)
    float*    part     = (float*)p;
    uint16_t* in1_nhwc = (uint16_t*)p;             // [256][1024][128] bf16
    p += (size_t)64 << 20;
    uint16_t* c1out    = (uint16_t*)p; p += (size_t)32 << 20;  // [256][1024][64] NHWC
    uint16_t* mbuf16   = (uint16_t*)p; p += (size_t)32 << 20;  // [256][64][1024] NCHW
    uint16_t* ftflat16 = (uint16_t*)p; p += (size_t)32 << 20;  // [256][65536]
    uint16_t* wpack1   = (uint16_t*)p; p += 256 * 1024;
    uint16_t* wpack2   = (uint16_t*)p; p += 128 * 1024;
    uint16_t* hbuf16 = (uint16_t*)p; p += (size_t)2 << 20;
    uint16_t* inm  = (uint16_t*)p; p += (size_t)1 << 20;
    uint16_t* ina  = (uint16_t*)p; p += (size_t)1 << 20;
    float* gxm  = (float*)p; p += (size_t)2 << 20;
    float* gxa  = (float*)p; p += (size_t)2 << 20;
    uint16_t* pw1  = (uint16_t*)p; p += (size_t)2097152 * 2;
    uint16_t* pw2m = (uint16_t*)p; p += (size_t)1048576 * 2;
    uint16_t* pw2a = (uint16_t*)p; p += (size_t)2097152 * 2;
    float* b2m_s = (float*)p; p += 2048 * 4;
    float* b2a_s = (float*)p; p += 2048 * 4;
    uint32_t* s1p  = (uint32_t*)p; p += (size_t)17 * 2 * 4096 * 4;
    uint32_t* s2ap = (uint32_t*)p; p += (size_t)17 * 4096 * 4;
    int* s1cnt  = (int*)p; p += 32 * 4;
    int* s2acnt = (int*)p; p += 16 * 4;

    float* outp = (float*)d_out;
    float* alpha_out = outp + 524288;

    hipMemsetAsync(s1p, 0, 2 * 4096 * 4, stream);
    hipMemsetAsync(s2ap, 0, 4096 * 4, stream);
    hipMemsetAsync(s1cnt, 0, 48 * 4, stream);

    prep_all_kernel<<<15136, 256, 0, stream>>>(
        f_t, f_t_1, conv1_w, conv2_w,
        l1m_whh, l1a_whh, l2m_wih, l2m_whh, l2a_wih, l2a_whh,
        l2m_bih, l2m_bhh, l2a_bih, l2a_bhh,
        ftflat16, in1_nhwc, wpack1, wpack2,
        pw1, pw2m, pw2a, b2m_s, b2a_s);

    conv_mfma2_kernel<128, false><<<dim3(8, 256), 256, 0, stream>>>(
        in1_nhwc, wpack1, conv1_b, c1out);
    conv_mfma2_kernel<64, true><<<dim3(8, 256), 256, 0, stream>>>(
        c1out, wpack2, conv2_b, mbuf16);

    fc1_mfma_kernel<<<512, 256, 0, stream>>>(mbuf16, ftflat16, fc1_w, part);
    fc1_reduce_kernel<<<2048, 256, 0, stream>>>(part, fc1_b, hbuf16);

    fc2_att_mfma_kernel<<<dim3(4, 4), 256, 0, stream>>>(hbuf16, fc2_w, fc2_b, att1, att2,
                                                        alpha_out, inm, ina);

    gx_mfma_kernel<<<dim3(2, 16, 2), 256, 0, stream>>>(inm, ina,
                                                       l1m_wih, l1m_bih, l1m_bhh,
                                                       l1a_wih, l1a_bih, l1a_bhh,
                                                       gxm, gxa);

    lstm_scan5_kernel<<<NBLK, 256, 0, stream>>>(
        gxm, gxa, pw1, pw2m, pw2a, b2m_s, b2a_s,
        s1p, s2ap, s1cnt, s2acnt, outp);
}

// Round 19
// 505.739 us; speedup vs baseline: 1.2720x; 1.0279x over previous
//
#include <hip/hip_runtime.h>
#include <math.h>
#include <stdint.h>

typedef __attribute__((ext_vector_type(8))) short    bf16x8;
typedef __attribute__((ext_vector_type(4))) float    f32x4;
typedef __attribute__((ext_vector_type(8))) uint16_t u16x8;
typedef __attribute__((ext_vector_type(4))) uint16_t u16x4;

#define LSTR 40   // LDS row stride (bf16): 80B rows -> 2-way banks (free)
#define NBLK 160  // persistent LSTM blocks

__device__ __forceinline__ uint16_t f2bf(float f) {
    union { float f; uint32_t u; } v; v.f = f;
    uint32_t r = v.u + 0x7FFFu + ((v.u >> 16) & 1u);
    return (uint16_t)(r >> 16);
}

__device__ __forceinline__ float sigm(float x) { return 1.f / (1.f + expf(-x)); }

// packed RNE f32x2 -> bf16x2
__device__ __forceinline__ uint32_t cvtpk(float lo, float hi) {
    uint32_t r;
    asm volatile("v_cvt_pk_bf16_f32 %0, %1, %2" : "=v"(r) : "v"(lo), "v"(hi));
    return r;
}

// ---------------------------------------------------------------------------
// prep (fused): blocks [0,8192) cvt_flat (coalesced), [8192,12288) nhwc,
// [12288,12576) wpack, [12576,15136) lstm_pack.
// ---------------------------------------------------------------------------
__global__ __launch_bounds__(256) void prep_all_kernel(
    const float* __restrict__ f_t, const float* __restrict__ f_t_1,
    const float* __restrict__ w1, const float* __restrict__ w2,
    const float* __restrict__ whh_m, const float* __restrict__ whh_a,
    const float* __restrict__ m_wih, const float* __restrict__ m_whh,
    const float* __restrict__ a_wih, const float* __restrict__ a_whh,
    const float* __restrict__ m_bih, const float* __restrict__ m_bhh,
    const float* __restrict__ a_bih, const float* __restrict__ a_bhh,
    uint16_t* __restrict__ ftflat16, uint16_t* __restrict__ in1_nhwc,
    uint16_t* __restrict__ p1, uint16_t* __restrict__ p2,
    uint16_t* __restrict__ pw1, uint16_t* __restrict__ pw2m,
    uint16_t* __restrict__ pw2a,
    float* __restrict__ b2m_s, float* __restrict__ b2a_s)
{
    __shared__ float lds[32][258];
    const int bid = blockIdx.x;
    const int tid = threadIdx.x;

    if (bid < 8192) {
        int i = (bid * 256 + tid) * 8;
        float4 a = *(const float4*)(f_t + i);
        float4 b = *(const float4*)(f_t + i + 4);
        u16x8 o;
        o[0] = f2bf(a.x); o[1] = f2bf(a.y); o[2] = f2bf(a.z); o[3] = f2bf(a.w);
        o[4] = f2bf(b.x); o[5] = f2bf(b.y); o[6] = f2bf(b.z); o[7] = f2bf(b.w);
        *(u16x8*)(ftflat16 + i) = o;
    } else if (bid < 12288) {
        const int v   = bid - 8192;
        const int bt  = v >> 4;
        const int c0  = ((v & 15) >> 2) * 32;
        const int px0 = (v & 3) * 256;
        const int lc  = tid & 31;
        const int lpx = (tid >> 5) * 32;
        const int c   = c0 + lc;
        const float* src = (c < 64)
            ? (f_t   + ((size_t)bt * 64 + c) * 1024)
            : (f_t_1 + ((size_t)bt * 64 + (c - 64)) * 1024);
#pragma unroll
        for (int j = 0; j < 32; j += 4) {
            float4 vv = *(const float4*)(src + px0 + lpx + j);
            lds[lc][lpx + j + 0] = vv.x;
            lds[lc][lpx + j + 1] = vv.y;
            lds[lc][lpx + j + 2] = vv.z;
            lds[lc][lpx + j + 3] = vv.w;
        }
        __syncthreads();
        uint16_t* op = in1_nhwc + ((size_t)bt * 1024 + px0 + tid) * 128 + c0;
#pragma unroll
        for (int u0 = 0; u0 < 32; u0 += 8) {
            u16x8 o;
#pragma unroll
            for (int u = 0; u < 8; ++u) o[u] = f2bf(lds[u0 + u][tid]);
            *(u16x8*)(op + u0) = o;
        }
    } else if (bid < 12576) {
        int i = (bid - 12288) * 256 + tid;
        if (i < 64 * 1152) {
            int oc = i / 1152, k = i - oc * 1152;
            int s = k >> 7, c = k & 127;
            int ky = s / 3, kx = s - ky * 3;
            p1[i] = f2bf(w1[((oc * 128 + c) * 3 + ky) * 3 + kx]);
        }
        if (i < 64 * 576) {
            int oc = i / 576, k = i - oc * 576;
            int s = k >> 6, c = k & 63;
            int ky = s / 3, kx = s - ky * 3;
            p2[i] = f2bf(w2[((oc * 64 + c) * 3 + ky) * 3 + kx]);
        }
    } else {
        int id = (bid - 12576) * 256 + tid;
        if (id < 2048) {
            b2m_s[id] = m_bih[id] + m_bhh[id];
            b2a_s[id] = a_bih[id] + a_bhh[id];
        }
        if (id < 262144) {                       // pw1
            int kc = id & 63, g = (id >> 6) & 3, j = (id >> 8) & 511, pp = id >> 17;
            const float* src = (pp ? whh_a : whh_m) + ((size_t)(g * 512 + j)) * 512 + kc * 8;
            uint16_t* dst = pw1 + ((((size_t)pp * 32 + (j >> 4)) * 64 + (j & 15) * 4 + g) * 512) + kc * 8;
            float4 a = *(const float4*)src; float4 b = *(const float4*)(src + 4);
            u16x8 o;
            o[0]=f2bf(a.x); o[1]=f2bf(a.y); o[2]=f2bf(a.z); o[3]=f2bf(a.w);
            o[4]=f2bf(b.x); o[5]=f2bf(b.y); o[6]=f2bf(b.z); o[7]=f2bf(b.w);
            *(u16x8*)dst = o;
        } else if (id < 393216) {                // pw2m (sum)
            int id2 = id - 262144;
            int kc = id2 & 63, g = (id2 >> 6) & 3, j = id2 >> 8;
            size_t off = ((size_t)(g * 512 + j)) * 512 + kc * 8;
            const float* s1 = m_wih + off; const float* s2 = m_whh + off;
            uint16_t* dst = pw2m + (((size_t)(j >> 4)) * 64 + (j & 15) * 4 + g) * 512 + kc * 8;
            u16x8 o;
#pragma unroll
            for (int u = 0; u < 8; ++u) o[u] = f2bf(s1[u] + s2[u]);
            *(u16x8*)dst = o;
        } else if (id < 655360) {                // pw2a
            int id3 = id - 393216;
            int kc = id3 & 63, g = (id3 >> 6) & 3, j = (id3 >> 8) & 511, mat = id3 >> 17;
            const float* src = (mat ? a_whh : a_wih) + ((size_t)(g * 512 + j)) * 512 + kc * 8;
            uint16_t* dst = pw2a + ((((size_t)(j >> 3)) * 2 + mat) * 32 + (j & 7) * 4 + g) * 512 + kc * 8;
            float4 a = *(const float4*)src; float4 b = *(const float4*)(src + 4);
            u16x8 o;
            o[0]=f2bf(a.x); o[1]=f2bf(a.y); o[2]=f2bf(a.z); o[3]=f2bf(a.w);
            o[4]=f2bf(b.x); o[5]=f2bf(b.y); o[6]=f2bf(b.z); o[7]=f2bf(b.w);
            *(u16x8*)dst = o;
        }
    }
}

// ---------------------------------------------------------------------------
// conv3x3 + bias + relu, implicit-GEMM MFMA v4: halo staged ONCE; W staged
// per TAP (full 64 x IC slice in LDS) -> one barrier pair per tap (18 total
// for conv1 vs 72), 32/16 MFMAs between pairs. W loads coalesced.
// ---------------------------------------------------------------------------
template<int IC, bool SWAP>
__global__ __launch_bounds__(256) void conv_mfma2_kernel(
    const uint16_t* __restrict__ in_nhwc,
    const uint16_t* __restrict__ wpack,
    const float* __restrict__ bias,
    uint16_t* __restrict__ out)
{
    constexpr int ICP = IC + 8;           // halo row pad
    constexpr int BWP = IC + 8;           // Bw row pad (272B/144B stride -> 2-way banks)
    constexpr int KT  = 9 * IC;
    constexpr int CPS = IC / 32;
    constexpr int C8  = IC / 8;
    constexpr int NW  = (64 * IC / 8) / 256;   // u16x8 stage iters per thread (4 / 2)
    constexpr int MF  = SWAP ? 4 : 2;
    constexpr int NF  = SWAP ? 2 : 4;

    __shared__ __align__(16) uint16_t Ah[6 * 34 * ICP];
    __shared__ __align__(16) uint16_t Bw[64 * BWP];

    const int bt  = blockIdx.y;
    const int px0 = blockIdx.x * 128;
    const int y0  = blockIdx.x * 4;
    const int tid = threadIdx.x;
    const int w   = tid >> 6, l = tid & 63;
    const int lrow = l & 15, kg = (l >> 4) * 8;

    for (int idx = tid; idx < 204 * C8; idx += 256) {
        int cpos = idx / C8;
        int c8   = (idx - cpos * C8) * 8;
        int hy = cpos / 34, hx = cpos - hy * 34;
        int gy = y0 - 1 + hy, gx = hx - 1;
        u16x8 v = {};
        if (gy >= 0 && gy < 32 && gx >= 0 && gx < 32)
            v = *(const u16x8*)(in_nhwc + (((size_t)bt * 1024) + gy * 32 + gx) * IC + c8);
        *(u16x8*)(Ah + (hy * 34 + hx) * ICP + c8) = v;
    }

    f32x4 acc[MF][NF] = {};

    int abase[MF > NF ? MF : 2];
#pragma unroll
    for (int i = 0; i < (SWAP ? 2 : MF); ++i) {
        int m  = w * 32 + i * 16 + lrow;
        int py = m >> 5, px = m & 31;
        abase[i] = (py * 34 + px) * ICP;
    }

    // staging map for the tap-level W slice: idx -> (row, chunk)
    const int wRow0 = tid / (IC / 8);          // row of first slot
    const int wChk  = (tid % (IC / 8)) * 8;    // elem chunk within row
    const int rowsPerIter = 256 / (IC / 8);    // 16 (IC=128) / 32 (IC=64)

    for (int s = 0; s < 9; ++s) {
        const int ky = s / 3, kx = s - ky * 3;

        // load tap W into regs (coalesced: 16B/lane within contiguous rows)
        u16x8 wreg[NW];
#pragma unroll
        for (int i = 0; i < NW; ++i) {
            const int row = wRow0 + i * rowsPerIter;
            wreg[i] = *(const u16x8*)(wpack + (size_t)row * KT + s * IC + wChk);
        }
        __syncthreads();                  // prior tap's Bw reads (and halo @s==0) done
#pragma unroll
        for (int i = 0; i < NW; ++i) {
            const int row = wRow0 + i * rowsPerIter;
            *(u16x8*)(Bw + row * BWP + wChk) = wreg[i];
        }
        __syncthreads();                  // tap W ready

#pragma unroll
        for (int c = 0; c < CPS; ++c) {
            const int cc = c * 32;
            const int aoff = (ky * 34 + kx) * ICP + cc + kg;

            if (!SWAP) {
                bf16x8 af[2], bf[4];
#pragma unroll
                for (int i = 0; i < 2; ++i)
                    af[i] = *(const bf16x8*)(Ah + abase[i] + aoff);
#pragma unroll
                for (int j = 0; j < 4; ++j)
                    bf[j] = *(const bf16x8*)(Bw + (j * 16 + lrow) * BWP + cc + kg);
#pragma unroll
                for (int i = 0; i < MF; ++i)
#pragma unroll
                    for (int j = 0; j < NF; ++j)
                        acc[i][j] = __builtin_amdgcn_mfma_f32_16x16x32_bf16(
                            af[i], bf[j], acc[i][j], 0, 0, 0);
            } else {
                bf16x8 af[4], bf[2];
#pragma unroll
                for (int i = 0; i < 4; ++i)
                    af[i] = *(const bf16x8*)(Bw + (i * 16 + lrow) * BWP + cc + kg);
#pragma unroll
                for (int j = 0; j < 2; ++j)
                    bf[j] = *(const bf16x8*)(Ah + abase[j] + aoff);
#pragma unroll
                for (int i = 0; i < MF; ++i)
#pragma unroll
                    for (int j = 0; j < NF; ++j)
                        acc[i][j] = __builtin_amdgcn_mfma_f32_16x16x32_bf16(
                            af[i], bf[j], acc[i][j], 0, 0, 0);
            }
        }
    }

    const int col = l & 15, rg = (l >> 4) * 4;
    if (!SWAP) {
#pragma unroll
        for (int i = 0; i < 2; ++i)
#pragma unroll
            for (int j = 0; j < 4; ++j) {
                const int ocb = j * 16 + col;
                const float bv = bias[ocb];
#pragma unroll
                for (int r = 0; r < 4; ++r) {
                    const int px = px0 + w * 32 + i * 16 + rg + r;
                    float v = acc[i][j][r] + bv; v = v > 0.f ? v : 0.f;
                    out[((size_t)bt * 1024 + px) * 64 + ocb] = f2bf(v);
                }
            }
    } else {
#pragma unroll
        for (int i = 0; i < 4; ++i)
#pragma unroll
            for (int j = 0; j < 2; ++j)
#pragma unroll
                for (int r = 0; r < 4; ++r) {
                    const int oc = i * 16 + rg + r;
                    const int px = px0 + w * 32 + j * 16 + col;
                    float v = acc[i][j][r] + bias[oc]; v = v > 0.f ? v : 0.f;
                    out[((size_t)bt * 64 + oc) * 1024 + px] = f2bf(v);
                }
    }
}

// ---------------------------------------------------------------------------
// fc1 MFMA (R7 geometry + coalesced slot staging): BM=256, BN=128, BK=32,
// split-K=32, grid 512; 32 MFMAs per barrier pair.
// ---------------------------------------------------------------------------
__global__ __launch_bounds__(256) void fc1_mfma_kernel(
    const uint16_t* __restrict__ Am, const uint16_t* __restrict__ Af,
    const float* __restrict__ Wf, float* __restrict__ part)
{
    __shared__ __align__(16) uint16_t Aa[256 * LSTR];
    __shared__ __align__(16) uint16_t Bb[128 * LSTR];

    const int id  = blockIdx.x;
    const int vid = (id & 7) * 64 + (id >> 3);   // 512 % 8 == 0 -> bijective
    const int bx  = vid & 1;
    const int by  = (vid >> 1) & 7;
    const int ks  = vid >> 4;

    const int row0 = bx * 256;
    const int col0 = by * 128;
    const size_t kbase = (size_t)ks * 2048;
    const uint16_t* Abase = bx ? Af : Am;

    const int tid = threadIdx.x;
    const int w = tid >> 6, l = tid & 63;
    const int lrow = l & 15, kg = (l >> 4) * 8;

    const int arow = tid >> 2, achk = (tid & 3) * 8;
    const int brow = tid >> 3, bchk = (tid & 7) * 4;

    f32x4 acc[4][8] = {};

    for (int kk = 0; kk < 2048; kk += 32) {
        u16x8 ra[4];
        float4 rb[4];
#pragma unroll
        for (int i = 0; i < 4; ++i)
            ra[i] = *(const u16x8*)(Abase + (size_t)(i * 64 + arow) * 65536 + kbase + kk + achk);
#pragma unroll
        for (int i = 0; i < 4; ++i)
            rb[i] = *(const float4*)(Wf + (size_t)(col0 + i * 32 + brow) * 65536 + kbase + kk + bchk);

        union { u16x4 v; uint32_t u[2]; } cb[4];
#pragma unroll
        for (int i = 0; i < 4; ++i) {
            cb[i].u[0] = cvtpk(rb[i].x, rb[i].y);
            cb[i].u[1] = cvtpk(rb[i].z, rb[i].w);
        }

        __syncthreads();
#pragma unroll
        for (int i = 0; i < 4; ++i)
            *(u16x8*)(Aa + (i * 64 + arow) * LSTR + achk) = ra[i];
#pragma unroll
        for (int i = 0; i < 4; ++i)
            *(u16x4*)(Bb + (i * 32 + brow) * LSTR + bchk) = cb[i].v;
        __syncthreads();

        bf16x8 afr[4], bfr[8];
#pragma unroll
        for (int i = 0; i < 4; ++i)
            afr[i] = *(const bf16x8*)(Aa + (w * 64 + i * 16 + lrow) * LSTR + kg);
#pragma unroll
        for (int j = 0; j < 8; ++j)
            bfr[j] = *(const bf16x8*)(Bb + (j * 16 + lrow) * LSTR + kg);
#pragma unroll
        for (int i = 0; i < 4; ++i)
#pragma unroll
            for (int j = 0; j < 8; ++j)
                acc[i][j] = __builtin_amdgcn_mfma_f32_16x16x32_bf16(
                    afr[i], bfr[j], acc[i][j], 0, 0, 0);
    }

    const int col = l & 15, rg = (l >> 4) * 4;
#pragma unroll
    for (int i = 0; i < 4; ++i)
#pragma unroll
        for (int r = 0; r < 4; ++r) {
            const int grow = row0 + w * 64 + i * 16 + rg + r;
            float* op = part + ((size_t)ks * 512 + grow) * 1024 + col0 + col;
#pragma unroll
            for (int j = 0; j < 8; ++j) op[j * 16] = acc[i][j][r];
        }
}

__global__ __launch_bounds__(256) void fc1_reduce_kernel(
    const float* __restrict__ part, const float* __restrict__ bias,
    uint16_t* __restrict__ h16)
{
    int idx = blockIdx.x * 256 + threadIdx.x;
    int j = idx & 1023;
    float s = bias[j];
#pragma unroll
    for (int ks = 0; ks < 32; ++ks) s += part[(size_t)ks * 524288 + idx];
    h16[idx] = f2bf(s > 0.f ? s : 0.f);
}

// ---------------------------------------------------------------------------
// fc2 MFMA + attention epilogue.  A = hbuf bf16; outputs inm/ina bf16.
// ---------------------------------------------------------------------------
__global__ __launch_bounds__(256) void fc2_att_mfma_kernel(
    const uint16_t* __restrict__ h16, const float* __restrict__ wf,
    const float* __restrict__ bias,
    const float* __restrict__ att1, const float* __restrict__ att2,
    float* __restrict__ alpha_out, uint16_t* __restrict__ inm, uint16_t* __restrict__ ina)
{
    __shared__ __align__(16) uint16_t Aa[128 * LSTR];
    __shared__ __align__(16) uint16_t Bb[128 * LSTR];

    const int row0 = blockIdx.x * 128;
    const int col0 = blockIdx.y * 128;

    const int t = threadIdx.x;
    const int w = t >> 6, l = t & 63;
    const int wr = (w >> 1) * 64, wc = (w & 1) * 64;

    const int srow  = t >> 1;
    const int shalf = (t & 1) * 16;
    const uint16_t* ap = h16 + (size_t)(row0 + srow) * 1024 + shalf;
    const float*    bp = wf  + (size_t)(col0 + srow) * 1024 + shalf;
    uint16_t* awr = Aa + srow * LSTR + shalf;
    uint16_t* bwr = Bb + srow * LSTR + shalf;

    f32x4 acc[4][4] = {};

    for (int kk = 0; kk < 1024; kk += 32) {
        u16x8 a0 = *(const u16x8*)(ap + kk);
        u16x8 a1 = *(const u16x8*)(ap + kk + 8);
        float4 f0 = *(const float4*)(bp + kk);
        float4 f1 = *(const float4*)(bp + kk + 4);
        float4 f2 = *(const float4*)(bp + kk + 8);
        float4 f3 = *(const float4*)(bp + kk + 12);
        union { u16x8 v; uint32_t u[4]; } b0, b1;
        b0.u[0] = cvtpk(f0.x, f0.y); b0.u[1] = cvtpk(f0.z, f0.w);
        b0.u[2] = cvtpk(f1.x, f1.y); b0.u[3] = cvtpk(f1.z, f1.w);
        b1.u[0] = cvtpk(f2.x, f2.y); b1.u[1] = cvtpk(f2.z, f2.w);
        b1.u[2] = cvtpk(f3.x, f3.y); b1.u[3] = cvtpk(f3.z, f3.w);

        __syncthreads();
        *(u16x8*)awr       = a0;
        *(u16x8*)(awr + 8) = a1;
        *(u16x8*)bwr       = b0.v;
        *(u16x8*)(bwr + 8) = b1.v;
        __syncthreads();

        const int row = l & 15, kg = (l >> 4) * 8;
        bf16x8 afr[4], bfr[4];
#pragma unroll
        for (int i = 0; i < 4; ++i)
            afr[i] = *(const bf16x8*)(Aa + (wr + i * 16 + row) * LSTR + kg);
#pragma unroll
        for (int j = 0; j < 4; ++j)
            bfr[j] = *(const bf16x8*)(Bb + (wc + j * 16 + row) * LSTR + kg);
#pragma unroll
        for (int i = 0; i < 4; ++i)
#pragma unroll
            for (int j = 0; j < 4; ++j)
                acc[i][j] = __builtin_amdgcn_mfma_f32_16x16x32_bf16(
                    afr[i], bfr[j], acc[i][j], 0, 0, 0);
    }

    const int col = l & 15, rg = (l >> 4) * 4;
#pragma unroll
    for (int i = 0; i < 4; ++i)
#pragma unroll
        for (int r = 0; r < 4; ++r) {
            const int row = row0 + wr + i * 16 + rg + r;
            const int bt  = row & 255;
            const int b = bt >> 4, tt = bt & 15;
            const size_t ibase = ((size_t)tt * 16 + b) * 1024;
#pragma unroll
            for (int j = 0; j < 4; ++j) {
                const int jj = col0 + wc + j * 16 + col;
                float v = acc[i][j][r] + bias[jj];
                if (row < 256) {
                    float al = sigm(att1[b * 512 + jj] * v);
                    alpha_out[(size_t)bt * 512 + jj] = al;
                    inm[ibase + jj]       = f2bf(al * v);
                    inm[ibase + 512 + jj] = f2bf(v);
                } else {
                    float be = sigm(att2[b * 512 + jj] * v);
                    ina[ibase + jj]       = f2bf(be * v);
                    ina[ibase + 512 + jj] = f2bf(v);
                }
            }
        }
}

// ---------------------------------------------------------------------------
// gx MFMA: gates x-projection, M=256, N=2048, K=1024, grid (2,16,2 paths).
// ---------------------------------------------------------------------------
__global__ __launch_bounds__(256) void gx_mfma_kernel(
    const uint16_t* __restrict__ inm, const uint16_t* __restrict__ ina,
    const float* __restrict__ wih_m, const float* __restrict__ bih_m, const float* __restrict__ bhh_m,
    const float* __restrict__ wih_a, const float* __restrict__ bih_a, const float* __restrict__ bhh_a,
    float* __restrict__ gxm, float* __restrict__ gxa)
{
    __shared__ __align__(16) uint16_t Aa[128 * LSTR];
    __shared__ __align__(16) uint16_t Bb[128 * LSTR];

    const int row0 = blockIdx.x * 128;
    const int col0 = blockIdx.y * 128;
    const int path = blockIdx.z;

    const uint16_t* A = path ? ina : inm;
    const float* W  = path ? wih_a : wih_m;
    const float* bi = path ? bih_a : bih_m;
    const float* bh = path ? bhh_a : bhh_m;
    float* out = path ? gxa : gxm;

    const int t = threadIdx.x;
    const int w = t >> 6, l = t & 63;
    const int wr = (w >> 1) * 64, wc = (w & 1) * 64;

    const int srow  = t >> 1;
    const int shalf = (t & 1) * 16;
    const uint16_t* ap = A + (size_t)(row0 + srow) * 1024 + shalf;
    const float*    bp = W + (size_t)(col0 + srow) * 1024 + shalf;
    uint16_t* awr = Aa + srow * LSTR + shalf;
    uint16_t* bwr = Bb + srow * LSTR + shalf;

    f32x4 acc[4][4] = {};

    for (int kk = 0; kk < 1024; kk += 32) {
        u16x8 a0 = *(const u16x8*)(ap + kk);
        u16x8 a1 = *(const u16x8*)(ap + kk + 8);
        float4 f0 = *(const float4*)(bp + kk);
        float4 f1 = *(const float4*)(bp + kk + 4);
        float4 f2 = *(const float4*)(bp + kk + 8);
        float4 f3 = *(const float4*)(bp + kk + 12);
        union { u16x8 v; uint32_t u[4]; } b0, b1;
        b0.u[0] = cvtpk(f0.x, f0.y); b0.u[1] = cvtpk(f0.z, f0.w);
        b0.u[2] = cvtpk(f1.x, f1.y); b0.u[3] = cvtpk(f1.z, f1.w);
        b1.u[0] = cvtpk(f2.x, f2.y); b1.u[1] = cvtpk(f2.z, f2.w);
        b1.u[2] = cvtpk(f3.x, f3.y); b1.u[3] = cvtpk(f3.z, f3.w);

        __syncthreads();
        *(u16x8*)awr       = a0;
        *(u16x8*)(awr + 8) = a1;
        *(u16x8*)bwr       = b0.v;
        *(u16x8*)(bwr + 8) = b1.v;
        __syncthreads();

        const int row = l & 15, kg = (l >> 4) * 8;
        bf16x8 afr[4], bfr[4];
#pragma unroll
        for (int i = 0; i < 4; ++i)
            afr[i] = *(const bf16x8*)(Aa + (wr + i * 16 + row) * LSTR + kg);
#pragma unroll
        for (int j = 0; j < 4; ++j)
            bfr[j] = *(const bf16x8*)(Bb + (wc + j * 16 + row) * LSTR + kg);
#pragma unroll
        for (int i = 0; i < 4; ++i)
#pragma unroll
            for (int j = 0; j < 4; ++j)
                acc[i][j] = __builtin_amdgcn_mfma_f32_16x16x32_bf16(
                    afr[i], bfr[j], acc[i][j], 0, 0, 0);
    }

    const int col = l & 15, rg = (l >> 4) * 4;
#pragma unroll
    for (int i = 0; i < 4; ++i)
#pragma unroll
        for (int r = 0; r < 4; ++r) {
            const int grow = row0 + wr + i * 16 + rg + r;
#pragma unroll
            for (int j = 0; j < 4; ++j) {
                const int jj = col0 + wc + j * 16 + col;
                out[(size_t)grow * 2048 + jj] = acc[i][j][r] + bi[jj] + bh[jj];
            }
        }
}

// ---------------------------------------------------------------------------
// Persistent LSTM scan v5b: fence-free point-to-point sync (IC-coherent).
// ---------------------------------------------------------------------------
__device__ __forceinline__ void wait_cnt(int* cnt, int target) {
    if (threadIdx.x == 0) {
        while (__hip_atomic_load(cnt, __ATOMIC_RELAXED, __HIP_MEMORY_SCOPE_AGENT) < target)
            __builtin_amdgcn_s_sleep(1);
    }
    __syncthreads();
}

__device__ __forceinline__ void post_cnt(int* cnt) {
    __syncthreads();   // drains vmcnt(0): all waves' sc1 stores reached the IC
    if (threadIdx.x == 0)
        __hip_atomic_fetch_add(cnt, 1, __ATOMIC_RELAXED, __HIP_MEMORY_SCOPE_AGENT);
}

__device__ __forceinline__ void stage_state(uint16_t* dst, const uint32_t* src, int tid) {
#pragma unroll
    for (int i = 0; i < 4; ++i) {
        const int idx = i * 1024 + tid * 4;
        uint4 v = *(const uint4*)(src + idx);
        const int flat = idx * 2;
        union { uint4 q; u16x8 h; } cv; cv.q = v;
        *(u16x8*)(dst + (flat >> 9) * 520 + (flat & 511)) = cv.h;
    }
}

__global__ __launch_bounds__(256, 1) void lstm_scan5_kernel(
    const float* __restrict__ gxm, const float* __restrict__ gxa,
    const uint16_t* __restrict__ pw1, const uint16_t* __restrict__ pw2m,
    const uint16_t* __restrict__ pw2a,
    const float* __restrict__ b2m_s, const float* __restrict__ b2a_s,
    uint32_t* __restrict__ s1p, uint32_t* __restrict__ s2ap,
    int* __restrict__ s1cnt, int* __restrict__ s2acnt,
    float* __restrict__ out)
{
    __shared__ __align__(16) uint16_t wlds[64 * 520];
    __shared__ __align__(16) uint16_t xs[16 * 520];
    __shared__ __align__(16) uint16_t hs[16 * 520];
    __shared__ float gbuf[2][16][68];

    const int bk  = blockIdx.x;
    const int tid = threadIdx.x;
    const int w   = tid >> 6, l = tid & 63;
    const int lrow = l & 15, kg = (l >> 4) * 8;

    const int role = (bk < 64) ? 0 : (bk < 96) ? 1 : 2;   // S1, S2M, S2A
    const int path = (role == 0) ? (bk >> 5) : (role == 1 ? 0 : 1);
    const int tile = (role == 0) ? (bk & 31) : (role == 1 ? bk - 64 : bk - 96);
    const int j0   = tile * ((role == 2) ? 8 : 16);

    const uint16_t* wsrc =
        (role == 0) ? pw1 + ((size_t)path * 32 + tile) * 64 * 512 :
        (role == 1) ? pw2m + (size_t)tile * 64 * 512
                    : pw2a + (size_t)tile * 64 * 512;
    for (int idx = tid; idx < 64 * 64; idx += 256) {
        int row = idx >> 6, c = idx & 63;
        *(u16x8*)(wlds + row * 520 + c * 8) = *(const u16x8*)(wsrc + row * 512 + c * 8);
    }

    float cv = 0.f;
    const float* gx1 = path ? gxa : gxm;

    if (role == 0) {
        const int b = tid >> 4, j = tid & 15, jg = j0 + j;
        const size_t obase = path ? 0 : 262144;
        for (int t = 0; t < 16; ++t) {
            const float* gxr = gx1 + ((size_t)(t * 16 + b)) * 2048;
            float g0 = gxr[jg], g1 = gxr[512 + jg], g2 = gxr[1024 + jg], g3 = gxr[1536 + jg];
            if (t > 0) wait_cnt(&s1cnt[path * 16 + t - 1], 32);
            stage_state(xs, s1p + ((size_t)t * 2 + path) * 4096, tid);
            __syncthreads();
            f32x4 acc = {};
#pragma unroll
            for (int kk = 0; kk < 512; kk += 32) {
                bf16x8 a  = *(const bf16x8*)(xs + lrow * 520 + kk + kg);
                bf16x8 bw = *(const bf16x8*)(wlds + (w * 16 + lrow) * 520 + kk + kg);
                acc = __builtin_amdgcn_mfma_f32_16x16x32_bf16(a, bw, acc, 0, 0, 0);
            }
#pragma unroll
            for (int r = 0; r < 4; ++r)
                gbuf[0][(l >> 4) * 4 + r][w * 16 + lrow] = acc[r];
            __syncthreads();

            float G0 = gbuf[0][b][j * 4 + 0] + g0;
            float G1 = gbuf[0][b][j * 4 + 1] + g1;
            float G2 = gbuf[0][b][j * 4 + 2] + g2;
            float G3 = gbuf[0][b][j * 4 + 3] + g3;
            cv = sigm(G1) * cv + sigm(G0) * tanhf(G2);
            float h = sigm(G3) * tanhf(cv);
            out[obase + ((size_t)b * 16 + t) * 1024 + jg] = h;
            float hn = __shfl_xor(h, 1);
            if ((j & 1) == 0) {
                uint32_t pk = (uint32_t)f2bf(h) | ((uint32_t)f2bf(hn) << 16);
                __hip_atomic_store(s1p + ((size_t)(t + 1) * 2 + path) * 4096 + b * 256 + (jg >> 1),
                                   pk, __ATOMIC_RELAXED, __HIP_MEMORY_SCOPE_AGENT);
            }
            post_cnt(&s1cnt[path * 16 + t]);
        }
    } else if (role == 1) {
        const int b = tid >> 4, j = tid & 15, jg = j0 + j;
        const float B0 = b2m_s[jg], B1 = b2m_s[512 + jg], B2 = b2m_s[1024 + jg], B3 = b2m_s[1536 + jg];
        for (int t = 0; t < 16; ++t) {
            wait_cnt(&s1cnt[t], 32);
            stage_state(xs, s1p + ((size_t)(t + 1) * 2 + 0) * 4096, tid);
            __syncthreads();
            f32x4 acc = {};
#pragma unroll
            for (int kk = 0; kk < 512; kk += 32) {
                bf16x8 a  = *(const bf16x8*)(xs + lrow * 520 + kk + kg);
                bf16x8 bw = *(const bf16x8*)(wlds + (w * 16 + lrow) * 520 + kk + kg);
                acc = __builtin_amdgcn_mfma_f32_16x16x32_bf16(a, bw, acc, 0, 0, 0);
            }
#pragma unroll
            for (int r = 0; r < 4; ++r)
                gbuf[0][(l >> 4) * 4 + r][w * 16 + lrow] = acc[r];
            __syncthreads();

            float G0 = gbuf[0][b][j * 4 + 0] + B0;
            float G1 = gbuf[0][b][j * 4 + 1] + B1;
            float G2 = gbuf[0][b][j * 4 + 2] + B2;
            float G3 = gbuf[0][b][j * 4 + 3] + B3;
            cv = sigm(G1) * cv + sigm(G0) * tanhf(G2);
            float h = sigm(G3) * tanhf(cv);
            out[262144 + ((size_t)b * 16 + t) * 1024 + 512 + jg] = h;
        }
    } else {
        const int b = tid >> 3, j = tid & 7, jg = j0 + j;
        float B0 = 0, B1 = 0, B2 = 0, B3 = 0;
        if (tid < 128) {
            B0 = b2a_s[jg]; B1 = b2a_s[512 + jg]; B2 = b2a_s[1024 + jg]; B3 = b2a_s[1536 + jg];
        }
        for (int t = 0; t < 16; ++t) {
            wait_cnt(&s1cnt[16 + t], 32);
            if (t > 0) wait_cnt(&s2acnt[t - 1], 64);
            stage_state(xs, s1p + ((size_t)(t + 1) * 2 + 1) * 4096, tid);
            stage_state(hs, s2ap + (size_t)t * 4096, tid);
            __syncthreads();
            const uint16_t* src = (w < 2) ? xs : hs;
            const int wt = (w < 2) ? w : w - 2;
            const int wb = (w < 2) ? 0 : 32 * 520;
            f32x4 acc = {};
#pragma unroll
            for (int kk = 0; kk < 512; kk += 32) {
                bf16x8 a  = *(const bf16x8*)(src + lrow * 520 + kk + kg);
                bf16x8 bw = *(const bf16x8*)(wlds + wb + (wt * 16 + lrow) * 520 + kk + kg);
                acc = __builtin_amdgcn_mfma_f32_16x16x32_bf16(a, bw, acc, 0, 0, 0);
            }
#pragma unroll
            for (int r = 0; r < 4; ++r)
                gbuf[w >> 1][(l >> 4) * 4 + r][wt * 16 + lrow] = acc[r];
            __syncthreads();

            if (tid < 128) {
                float G0 = gbuf[0][b][j * 4 + 0] + gbuf[1][b][j * 4 + 0] + B0;
                float G1 = gbuf[0][b][j * 4 + 1] + gbuf[1][b][j * 4 + 1] + B1;
                float G2 = gbuf[0][b][j * 4 + 2] + gbuf[1][b][j * 4 + 2] + B2;
                float G3 = gbuf[0][b][j * 4 + 3] + gbuf[1][b][j * 4 + 3] + B3;
                cv = sigm(G1) * cv + sigm(G0) * tanhf(G2);
                float h = sigm(G3) * tanhf(cv);
                out[((size_t)b * 16 + t) * 1024 + 512 + jg] = h;
                float hn = __shfl_xor(h, 1);
                if ((j & 1) == 0) {
                    uint32_t pk = (uint32_t)f2bf(h) | ((uint32_t)f2bf(hn) << 16);
                    __hip_atomic_store(s2ap + (size_t)(t + 1) * 4096 + b * 256 + (jg >> 1),
                                       pk, __ATOMIC_RELAXED, __HIP_MEMORY_SCOPE_AGENT);
                }
            }
            post_cnt(&s2acnt[t]);
        }
    }
}

// ---------------------------------------------------------------------------
extern "C" void kernel_launch(void* const* d_in, const int* in_sizes, int n_in,
                              void* d_out, int out_size, void* d_ws, size_t ws_size,
                              hipStream_t stream)
{
    (void)in_sizes; (void)n_in; (void)out_size; (void)ws_size;
    const float* f_t     = (const float*)d_in[0];
    const float* f_t_1   = (const float*)d_in[1];
    const float* att1    = (const float*)d_in[2];
    const float* att2    = (const float*)d_in[3];
    const float* conv1_w = (const float*)d_in[4];
    const float* conv1_b = (const float*)d_in[5];
    const float* conv2_w = (const float*)d_in[6];
    const float* conv2_b = (const float*)d_in[7];
    const float* l1a_wih = (const float*)d_in[8];
    const float* l1a_whh = (const float*)d_in[9];
    const float* l1a_bih = (const float*)d_in[10];
    const float* l1a_bhh = (const float*)d_in[11];
    const float* l2a_wih = (const float*)d_in[12];
    const float* l2a_whh = (const float*)d_in[13];
    const float* l2a_bih = (const float*)d_in[14];
    const float* l2a_bhh = (const float*)d_in[15];
    const float* l1m_wih = (const float*)d_in[16];
    const float* l1m_whh = (const float*)d_in[17];
    const float* l1m_bih = (const float*)d_in[18];
    const float* l1m_bhh = (const float*)d_in[19];
    const float* l2m_wih = (const float*)d_in[20];
    const float* l2m_whh = (const float*)d_in[21];
    const float* l2m_bih = (const float*)d_in[22];
    const float* l2m_bhh = (const float*)d_in[23];
    const float* fc1_w   = (const float*)d_in[24];
    const float* fc1_b   = (const float*)d_in[25];
    const float* fc2_w   = (const float*)d_in[26];
    const float* fc2_b   = (const float*)d_in[27];

    char* p = (char*)d_ws;
    // part (64MB, fc1 split-K=32 partials) aliases in1_nhwc (dead after conv1)
    float*    part     = (float*)p;
    uint16_t* in1_nhwc = (uint16_t*)p;             // [256][1024][128] bf16
    p += (size_t)64 << 20;
    uint16_t* c1out    = (uint16_t*)p; p += (size_t)32 << 20;  // [256][1024][64] NHWC
    uint16_t* mbuf16   = (uint16_t*)p; p += (size_t)32 << 20;  // [256][64][1024] NCHW
    uint16_t* ftflat16 = (uint16_t*)p; p += (size_t)32 << 20;  // [256][65536]
    uint16_t* wpack1   = (uint16_t*)p; p += 256 * 1024;
    uint16_t* wpack2   = (uint16_t*)p; p += 128 * 1024;
    uint16_t* hbuf16 = (uint16_t*)p; p += (size_t)2 << 20;
    uint16_t* inm  = (uint16_t*)p; p += (size_t)1 << 20;
    uint16_t* ina  = (uint16_t*)p; p += (size_t)1 << 20;
    float* gxm  = (float*)p; p += (size_t)2 << 20;
    float* gxa  = (float*)p; p += (size_t)2 << 20;
    uint16_t* pw1  = (uint16_t*)p; p += (size_t)2097152 * 2;
    uint16_t* pw2m = (uint16_t*)p; p += (size_t)1048576 * 2;
    uint16_t* pw2a = (uint16_t*)p; p += (size_t)2097152 * 2;
    float* b2m_s = (float*)p; p += 2048 * 4;
    float* b2a_s = (float*)p; p += 2048 * 4;
    uint32_t* s1p  = (uint32_t*)p; p += (size_t)17 * 2 * 4096 * 4;
    uint32_t* s2ap = (uint32_t*)p; p += (size_t)17 * 4096 * 4;
    int* s1cnt  = (int*)p; p += 32 * 4;
    int* s2acnt = (int*)p; p += 16 * 4;

    float* outp = (float*)d_out;
    float* alpha_out = outp + 524288;

    hipMemsetAsync(s1p, 0, 2 * 4096 * 4, stream);
    hipMemsetAsync(s2ap, 0, 4096 * 4, stream);
    hipMemsetAsync(s1cnt, 0, 48 * 4, stream);

    prep_all_kernel<<<15136, 256, 0, stream>>>(
        f_t, f_t_1, conv1_w, conv2_w,
        l1m_whh, l1a_whh, l2m_wih, l2m_whh, l2a_wih, l2a_whh,
        l2m_bih, l2m_bhh, l2a_bih, l2a_bhh,
        ftflat16, in1_nhwc, wpack1, wpack2,
        pw1, pw2m, pw2a, b2m_s, b2a_s);

    conv_mfma2_kernel<128, false><<<dim3(8, 256), 256, 0, stream>>>(
        in1_nhwc, wpack1, conv1_b, c1out);
    conv_mfma2_kernel<64, true><<<dim3(8, 256), 256, 0, stream>>>(
        c1out, wpack2, conv2_b, mbuf16);

    fc1_mfma_kernel<<<512, 256, 0, stream>>>(mbuf16, ftflat16, fc1_w, part);
    fc1_reduce_kernel<<<2048, 256, 0, stream>>>(part, fc1_b, hbuf16);

    fc2_att_mfma_kernel<<<dim3(4, 4), 256, 0, stream>>>(hbuf16, fc2_w, fc2_b, att1, att2,
                                                        alpha_out, inm, ina);

    gx_mfma_kernel<<<dim3(2, 16, 2), 256, 0, stream>>>(inm, ina,
                                                       l1m_wih, l1m_bih, l1m_bhh,
                                                       l1a_wih, l1a_bih, l1a_bhh,
                                                       gxm, gxa);

    lstm_scan5_kernel<<<NBLK, 256, 0, stream>>>(
        gxm, gxa, pw1, pw2m, pw2a, b2m_s, b2a_s,
        s1p, s2ap, s1cnt, s2acnt, outp);
}

// Round 20
// 497.079 us; speedup vs baseline: 1.2942x; 1.0174x over previous
//
#include <hip/hip_runtime.h>
#include <math.h>
#include <stdint.h>

typedef __attribute__((ext_vector_type(8))) short    bf16x8;
typedef __attribute__((ext_vector_type(4))) float    f32x4;
typedef __attribute__((ext_vector_type(8))) uint16_t u16x8;
typedef __attribute__((ext_vector_type(4))) uint16_t u16x4;

#define LSTR 40   // LDS row stride (bf16): 80B rows -> 2-way banks (free)
#define NBLK 160  // persistent LSTM blocks

__device__ __forceinline__ uint16_t f2bf(float f) {
    union { float f; uint32_t u; } v; v.f = f;
    uint32_t r = v.u + 0x7FFFu + ((v.u >> 16) & 1u);
    return (uint16_t)(r >> 16);
}

__device__ __forceinline__ float sigm(float x) { return 1.f / (1.f + expf(-x)); }

// packed RNE f32x2 -> bf16x2
__device__ __forceinline__ uint32_t cvtpk(float lo, float hi) {
    uint32_t r;
    asm volatile("v_cvt_pk_bf16_f32 %0, %1, %2" : "=v"(r) : "v"(lo), "v"(hi));
    return r;
}

// ---------------------------------------------------------------------------
// prep (fused): blocks [0,8192) cvt_flat (coalesced), [8192,12288) nhwc,
// [12288,12576) wpack, [12576,15136) lstm_pack.
// ---------------------------------------------------------------------------
__global__ __launch_bounds__(256) void prep_all_kernel(
    const float* __restrict__ f_t, const float* __restrict__ f_t_1,
    const float* __restrict__ w1, const float* __restrict__ w2,
    const float* __restrict__ whh_m, const float* __restrict__ whh_a,
    const float* __restrict__ m_wih, const float* __restrict__ m_whh,
    const float* __restrict__ a_wih, const float* __restrict__ a_whh,
    const float* __restrict__ m_bih, const float* __restrict__ m_bhh,
    const float* __restrict__ a_bih, const float* __restrict__ a_bhh,
    uint16_t* __restrict__ ftflat16, uint16_t* __restrict__ in1_nhwc,
    uint16_t* __restrict__ p1, uint16_t* __restrict__ p2,
    uint16_t* __restrict__ pw1, uint16_t* __restrict__ pw2m,
    uint16_t* __restrict__ pw2a,
    float* __restrict__ b2m_s, float* __restrict__ b2a_s)
{
    __shared__ float lds[32][258];
    const int bid = blockIdx.x;
    const int tid = threadIdx.x;

    if (bid < 8192) {
        int i = (bid * 256 + tid) * 8;
        float4 a = *(const float4*)(f_t + i);
        float4 b = *(const float4*)(f_t + i + 4);
        u16x8 o;
        o[0] = f2bf(a.x); o[1] = f2bf(a.y); o[2] = f2bf(a.z); o[3] = f2bf(a.w);
        o[4] = f2bf(b.x); o[5] = f2bf(b.y); o[6] = f2bf(b.z); o[7] = f2bf(b.w);
        *(u16x8*)(ftflat16 + i) = o;
    } else if (bid < 12288) {
        const int v   = bid - 8192;
        const int bt  = v >> 4;
        const int c0  = ((v & 15) >> 2) * 32;
        const int px0 = (v & 3) * 256;
        const int lc  = tid & 31;
        const int lpx = (tid >> 5) * 32;
        const int c   = c0 + lc;
        const float* src = (c < 64)
            ? (f_t   + ((size_t)bt * 64 + c) * 1024)
            : (f_t_1 + ((size_t)bt * 64 + (c - 64)) * 1024);
#pragma unroll
        for (int j = 0; j < 32; j += 4) {
            float4 vv = *(const float4*)(src + px0 + lpx + j);
            lds[lc][lpx + j + 0] = vv.x;
            lds[lc][lpx + j + 1] = vv.y;
            lds[lc][lpx + j + 2] = vv.z;
            lds[lc][lpx + j + 3] = vv.w;
        }
        __syncthreads();
        uint16_t* op = in1_nhwc + ((size_t)bt * 1024 + px0 + tid) * 128 + c0;
#pragma unroll
        for (int u0 = 0; u0 < 32; u0 += 8) {
            u16x8 o;
#pragma unroll
            for (int u = 0; u < 8; ++u) o[u] = f2bf(lds[u0 + u][tid]);
            *(u16x8*)(op + u0) = o;
        }
    } else if (bid < 12576) {
        int i = (bid - 12288) * 256 + tid;
        if (i < 64 * 1152) {
            int oc = i / 1152, k = i - oc * 1152;
            int s = k >> 7, c = k & 127;
            int ky = s / 3, kx = s - ky * 3;
            p1[i] = f2bf(w1[((oc * 128 + c) * 3 + ky) * 3 + kx]);
        }
        if (i < 64 * 576) {
            int oc = i / 576, k = i - oc * 576;
            int s = k >> 6, c = k & 63;
            int ky = s / 3, kx = s - ky * 3;
            p2[i] = f2bf(w2[((oc * 64 + c) * 3 + ky) * 3 + kx]);
        }
    } else {
        int id = (bid - 12576) * 256 + tid;
        if (id < 2048) {
            b2m_s[id] = m_bih[id] + m_bhh[id];
            b2a_s[id] = a_bih[id] + a_bhh[id];
        }
        if (id < 262144) {                       // pw1
            int kc = id & 63, g = (id >> 6) & 3, j = (id >> 8) & 511, pp = id >> 17;
            const float* src = (pp ? whh_a : whh_m) + ((size_t)(g * 512 + j)) * 512 + kc * 8;
            uint16_t* dst = pw1 + ((((size_t)pp * 32 + (j >> 4)) * 64 + (j & 15) * 4 + g) * 512) + kc * 8;
            float4 a = *(const float4*)src; float4 b = *(const float4*)(src + 4);
            u16x8 o;
            o[0]=f2bf(a.x); o[1]=f2bf(a.y); o[2]=f2bf(a.z); o[3]=f2bf(a.w);
            o[4]=f2bf(b.x); o[5]=f2bf(b.y); o[6]=f2bf(b.z); o[7]=f2bf(b.w);
            *(u16x8*)dst = o;
        } else if (id < 393216) {                // pw2m (sum)
            int id2 = id - 262144;
            int kc = id2 & 63, g = (id2 >> 6) & 3, j = id2 >> 8;
            size_t off = ((size_t)(g * 512 + j)) * 512 + kc * 8;
            const float* s1 = m_wih + off; const float* s2 = m_whh + off;
            uint16_t* dst = pw2m + (((size_t)(j >> 4)) * 64 + (j & 15) * 4 + g) * 512 + kc * 8;
            u16x8 o;
#pragma unroll
            for (int u = 0; u < 8; ++u) o[u] = f2bf(s1[u] + s2[u]);
            *(u16x8*)dst = o;
        } else if (id < 655360) {                // pw2a
            int id3 = id - 393216;
            int kc = id3 & 63, g = (id3 >> 6) & 3, j = (id3 >> 8) & 511, mat = id3 >> 17;
            const float* src = (mat ? a_whh : a_wih) + ((size_t)(g * 512 + j)) * 512 + kc * 8;
            uint16_t* dst = pw2a + ((((size_t)(j >> 3)) * 2 + mat) * 32 + (j & 7) * 4 + g) * 512 + kc * 8;
            float4 a = *(const float4*)src; float4 b = *(const float4*)(src + 4);
            u16x8 o;
            o[0]=f2bf(a.x); o[1]=f2bf(a.y); o[2]=f2bf(a.z); o[3]=f2bf(a.w);
            o[4]=f2bf(b.x); o[5]=f2bf(b.y); o[6]=f2bf(b.z); o[7]=f2bf(b.w);
            *(u16x8*)dst = o;
        }
    }
}

// ---------------------------------------------------------------------------
// conv3x3 + bias + relu, implicit-GEMM MFMA v5: halo staged ONCE; W staged
// per TAP with NEXT-tap register prefetch issued after the ready-barrier so
// its latency hides under the MFMA loop (fc1's proven schedule).
// ---------------------------------------------------------------------------
template<int IC, bool SWAP>
__global__ __launch_bounds__(256) void conv_mfma2_kernel(
    const uint16_t* __restrict__ in_nhwc,
    const uint16_t* __restrict__ wpack,
    const float* __restrict__ bias,
    uint16_t* __restrict__ out)
{
    constexpr int ICP = IC + 8;           // halo row pad
    constexpr int BWP = IC + 8;           // Bw row pad (2-way banks, free)
    constexpr int KT  = 9 * IC;
    constexpr int CPS = IC / 32;
    constexpr int C8  = IC / 8;
    constexpr int NW  = (64 * IC / 8) / 256;   // u16x8 stage iters per thread (4 / 2)
    constexpr int MF  = SWAP ? 4 : 2;
    constexpr int NF  = SWAP ? 2 : 4;

    __shared__ __align__(16) uint16_t Ah[6 * 34 * ICP];
    __shared__ __align__(16) uint16_t Bw[64 * BWP];

    const int bt  = blockIdx.y;
    const int px0 = blockIdx.x * 128;
    const int y0  = blockIdx.x * 4;
    const int tid = threadIdx.x;
    const int w   = tid >> 6, l = tid & 63;
    const int lrow = l & 15, kg = (l >> 4) * 8;

    for (int idx = tid; idx < 204 * C8; idx += 256) {
        int cpos = idx / C8;
        int c8   = (idx - cpos * C8) * 8;
        int hy = cpos / 34, hx = cpos - hy * 34;
        int gy = y0 - 1 + hy, gx = hx - 1;
        u16x8 v = {};
        if (gy >= 0 && gy < 32 && gx >= 0 && gx < 32)
            v = *(const u16x8*)(in_nhwc + (((size_t)bt * 1024) + gy * 32 + gx) * IC + c8);
        *(u16x8*)(Ah + (hy * 34 + hx) * ICP + c8) = v;
    }

    f32x4 acc[MF][NF] = {};

    int abase[MF > NF ? MF : 2];
#pragma unroll
    for (int i = 0; i < (SWAP ? 2 : MF); ++i) {
        int m  = w * 32 + i * 16 + lrow;
        int py = m >> 5, px = m & 31;
        abase[i] = (py * 34 + px) * ICP;
    }

    // staging map for the tap-level W slice: idx -> (row, chunk)
    const int wRow0 = tid / (IC / 8);
    const int wChk  = (tid % (IC / 8)) * 8;
    const int rowsPerIter = 256 / (IC / 8);

    // prologue: prefetch tap 0's W
    u16x8 wreg[NW];
#pragma unroll
    for (int i = 0; i < NW; ++i) {
        const int row = wRow0 + i * rowsPerIter;
        wreg[i] = *(const u16x8*)(wpack + (size_t)row * KT + 0 * IC + wChk);
    }

    for (int s = 0; s < 9; ++s) {
        const int ky = s / 3, kx = s - ky * 3;

        __syncthreads();                  // prior tap's Bw reads (and halo @s==0) done
#pragma unroll
        for (int i = 0; i < NW; ++i) {
            const int row = wRow0 + i * rowsPerIter;
            *(u16x8*)(Bw + row * BWP + wChk) = wreg[i];
        }
        __syncthreads();                  // tap W ready

        // issue NEXT tap's W loads: latency hides under the MFMA loop below
        if (s + 1 < 9) {
#pragma unroll
            for (int i = 0; i < NW; ++i) {
                const int row = wRow0 + i * rowsPerIter;
                wreg[i] = *(const u16x8*)(wpack + (size_t)row * KT + (s + 1) * IC + wChk);
            }
        }

#pragma unroll
        for (int c = 0; c < CPS; ++c) {
            const int cc = c * 32;
            const int aoff = (ky * 34 + kx) * ICP + cc + kg;

            if (!SWAP) {
                bf16x8 af[2], bf[4];
#pragma unroll
                for (int i = 0; i < 2; ++i)
                    af[i] = *(const bf16x8*)(Ah + abase[i] + aoff);
#pragma unroll
                for (int j = 0; j < 4; ++j)
                    bf[j] = *(const bf16x8*)(Bw + (j * 16 + lrow) * BWP + cc + kg);
#pragma unroll
                for (int i = 0; i < MF; ++i)
#pragma unroll
                    for (int j = 0; j < NF; ++j)
                        acc[i][j] = __builtin_amdgcn_mfma_f32_16x16x32_bf16(
                            af[i], bf[j], acc[i][j], 0, 0, 0);
            } else {
                bf16x8 af[4], bf[2];
#pragma unroll
                for (int i = 0; i < 4; ++i)
                    af[i] = *(const bf16x8*)(Bw + (i * 16 + lrow) * BWP + cc + kg);
#pragma unroll
                for (int j = 0; j < 2; ++j)
                    bf[j] = *(const bf16x8*)(Ah + abase[j] + aoff);
#pragma unroll
                for (int i = 0; i < MF; ++i)
#pragma unroll
                    for (int j = 0; j < NF; ++j)
                        acc[i][j] = __builtin_amdgcn_mfma_f32_16x16x32_bf16(
                            af[i], bf[j], acc[i][j], 0, 0, 0);
            }
        }
    }

    const int col = l & 15, rg = (l >> 4) * 4;
    if (!SWAP) {
#pragma unroll
        for (int i = 0; i < 2; ++i)
#pragma unroll
            for (int j = 0; j < 4; ++j) {
                const int ocb = j * 16 + col;
                const float bv = bias[ocb];
#pragma unroll
                for (int r = 0; r < 4; ++r) {
                    const int px = px0 + w * 32 + i * 16 + rg + r;
                    float v = acc[i][j][r] + bv; v = v > 0.f ? v : 0.f;
                    out[((size_t)bt * 1024 + px) * 64 + ocb] = f2bf(v);
                }
            }
    } else {
#pragma unroll
        for (int i = 0; i < 4; ++i)
#pragma unroll
            for (int j = 0; j < 2; ++j)
#pragma unroll
                for (int r = 0; r < 4; ++r) {
                    const int oc = i * 16 + rg + r;
                    const int px = px0 + w * 32 + j * 16 + col;
                    float v = acc[i][j][r] + bias[oc]; v = v > 0.f ? v : 0.f;
                    out[((size_t)bt * 64 + oc) * 1024 + px] = f2bf(v);
                }
    }
}

// ---------------------------------------------------------------------------
// fc1 MFMA (R7 geometry + coalesced slot staging): BM=256, BN=128, BK=32,
// split-K=32, grid 512; 32 MFMAs per barrier pair.
// ---------------------------------------------------------------------------
__global__ __launch_bounds__(256) void fc1_mfma_kernel(
    const uint16_t* __restrict__ Am, const uint16_t* __restrict__ Af,
    const float* __restrict__ Wf, float* __restrict__ part)
{
    __shared__ __align__(16) uint16_t Aa[256 * LSTR];
    __shared__ __align__(16) uint16_t Bb[128 * LSTR];

    const int id  = blockIdx.x;
    const int vid = (id & 7) * 64 + (id >> 3);   // 512 % 8 == 0 -> bijective
    const int bx  = vid & 1;
    const int by  = (vid >> 1) & 7;
    const int ks  = vid >> 4;

    const int row0 = bx * 256;
    const int col0 = by * 128;
    const size_t kbase = (size_t)ks * 2048;
    const uint16_t* Abase = bx ? Af : Am;

    const int tid = threadIdx.x;
    const int w = tid >> 6, l = tid & 63;
    const int lrow = l & 15, kg = (l >> 4) * 8;

    const int arow = tid >> 2, achk = (tid & 3) * 8;
    const int brow = tid >> 3, bchk = (tid & 7) * 4;

    f32x4 acc[4][8] = {};

    for (int kk = 0; kk < 2048; kk += 32) {
        u16x8 ra[4];
        float4 rb[4];
#pragma unroll
        for (int i = 0; i < 4; ++i)
            ra[i] = *(const u16x8*)(Abase + (size_t)(i * 64 + arow) * 65536 + kbase + kk + achk);
#pragma unroll
        for (int i = 0; i < 4; ++i)
            rb[i] = *(const float4*)(Wf + (size_t)(col0 + i * 32 + brow) * 65536 + kbase + kk + bchk);

        union { u16x4 v; uint32_t u[2]; } cb[4];
#pragma unroll
        for (int i = 0; i < 4; ++i) {
            cb[i].u[0] = cvtpk(rb[i].x, rb[i].y);
            cb[i].u[1] = cvtpk(rb[i].z, rb[i].w);
        }

        __syncthreads();
#pragma unroll
        for (int i = 0; i < 4; ++i)
            *(u16x8*)(Aa + (i * 64 + arow) * LSTR + achk) = ra[i];
#pragma unroll
        for (int i = 0; i < 4; ++i)
            *(u16x4*)(Bb + (i * 32 + brow) * LSTR + bchk) = cb[i].v;
        __syncthreads();

        bf16x8 afr[4], bfr[8];
#pragma unroll
        for (int i = 0; i < 4; ++i)
            afr[i] = *(const bf16x8*)(Aa + (w * 64 + i * 16 + lrow) * LSTR + kg);
#pragma unroll
        for (int j = 0; j < 8; ++j)
            bfr[j] = *(const bf16x8*)(Bb + (j * 16 + lrow) * LSTR + kg);
#pragma unroll
        for (int i = 0; i < 4; ++i)
#pragma unroll
            for (int j = 0; j < 8; ++j)
                acc[i][j] = __builtin_amdgcn_mfma_f32_16x16x32_bf16(
                    afr[i], bfr[j], acc[i][j], 0, 0, 0);
    }

    const int col = l & 15, rg = (l >> 4) * 4;
#pragma unroll
    for (int i = 0; i < 4; ++i)
#pragma unroll
        for (int r = 0; r < 4; ++r) {
            const int grow = row0 + w * 64 + i * 16 + rg + r;
            float* op = part + ((size_t)ks * 512 + grow) * 1024 + col0 + col;
#pragma unroll
            for (int j = 0; j < 8; ++j) op[j * 16] = acc[i][j][r];
        }
}

__global__ __launch_bounds__(256) void fc1_reduce_kernel(
    const float* __restrict__ part, const float* __restrict__ bias,
    uint16_t* __restrict__ h16)
{
    int idx = blockIdx.x * 256 + threadIdx.x;
    int j = idx & 1023;
    float s = bias[j];
#pragma unroll
    for (int ks = 0; ks < 32; ++ks) s += part[(size_t)ks * 524288 + idx];
    h16[idx] = f2bf(s > 0.f ? s : 0.f);
}

// ---------------------------------------------------------------------------
// fc2 MFMA + attention epilogue.  A = hbuf bf16; outputs inm/ina bf16.
// ---------------------------------------------------------------------------
__global__ __launch_bounds__(256) void fc2_att_mfma_kernel(
    const uint16_t* __restrict__ h16, const float* __restrict__ wf,
    const float* __restrict__ bias,
    const float* __restrict__ att1, const float* __restrict__ att2,
    float* __restrict__ alpha_out, uint16_t* __restrict__ inm, uint16_t* __restrict__ ina)
{
    __shared__ __align__(16) uint16_t Aa[128 * LSTR];
    __shared__ __align__(16) uint16_t Bb[128 * LSTR];

    const int row0 = blockIdx.x * 128;
    const int col0 = blockIdx.y * 128;

    const int t = threadIdx.x;
    const int w = t >> 6, l = t & 63;
    const int wr = (w >> 1) * 64, wc = (w & 1) * 64;

    const int srow  = t >> 1;
    const int shalf = (t & 1) * 16;
    const uint16_t* ap = h16 + (size_t)(row0 + srow) * 1024 + shalf;
    const float*    bp = wf  + (size_t)(col0 + srow) * 1024 + shalf;
    uint16_t* awr = Aa + srow * LSTR + shalf;
    uint16_t* bwr = Bb + srow * LSTR + shalf;

    f32x4 acc[4][4] = {};

    for (int kk = 0; kk < 1024; kk += 32) {
        u16x8 a0 = *(const u16x8*)(ap + kk);
        u16x8 a1 = *(const u16x8*)(ap + kk + 8);
        float4 f0 = *(const float4*)(bp + kk);
        float4 f1 = *(const float4*)(bp + kk + 4);
        float4 f2 = *(const float4*)(bp + kk + 8);
        float4 f3 = *(const float4*)(bp + kk + 12);
        union { u16x8 v; uint32_t u[4]; } b0, b1;
        b0.u[0] = cvtpk(f0.x, f0.y); b0.u[1] = cvtpk(f0.z, f0.w);
        b0.u[2] = cvtpk(f1.x, f1.y); b0.u[3] = cvtpk(f1.z, f1.w);
        b1.u[0] = cvtpk(f2.x, f2.y); b1.u[1] = cvtpk(f2.z, f2.w);
        b1.u[2] = cvtpk(f3.x, f3.y); b1.u[3] = cvtpk(f3.z, f3.w);

        __syncthreads();
        *(u16x8*)awr       = a0;
        *(u16x8*)(awr + 8) = a1;
        *(u16x8*)bwr       = b0.v;
        *(u16x8*)(bwr + 8) = b1.v;
        __syncthreads();

        const int row = l & 15, kg = (l >> 4) * 8;
        bf16x8 afr[4], bfr[4];
#pragma unroll
        for (int i = 0; i < 4; ++i)
            afr[i] = *(const bf16x8*)(Aa + (wr + i * 16 + row) * LSTR + kg);
#pragma unroll
        for (int j = 0; j < 4; ++j)
            bfr[j] = *(const bf16x8*)(Bb + (wc + j * 16 + row) * LSTR + kg);
#pragma unroll
        for (int i = 0; i < 4; ++i)
#pragma unroll
            for (int j = 0; j < 4; ++j)
                acc[i][j] = __builtin_amdgcn_mfma_f32_16x16x32_bf16(
                    afr[i], bfr[j], acc[i][j], 0, 0, 0);
    }

    const int col = l & 15, rg = (l >> 4) * 4;
#pragma unroll
    for (int i = 0; i < 4; ++i)
#pragma unroll
        for (int r = 0; r < 4; ++r) {
            const int row = row0 + wr + i * 16 + rg + r;
            const int bt  = row & 255;
            const int b = bt >> 4, tt = bt & 15;
            const size_t ibase = ((size_t)tt * 16 + b) * 1024;
#pragma unroll
            for (int j = 0; j < 4; ++j) {
                const int jj = col0 + wc + j * 16 + col;
                float v = acc[i][j][r] + bias[jj];
                if (row < 256) {
                    float al = sigm(att1[b * 512 + jj] * v);
                    alpha_out[(size_t)bt * 512 + jj] = al;
                    inm[ibase + jj]       = f2bf(al * v);
                    inm[ibase + 512 + jj] = f2bf(v);
                } else {
                    float be = sigm(att2[b * 512 + jj] * v);
                    ina[ibase + jj]       = f2bf(be * v);
                    ina[ibase + 512 + jj] = f2bf(v);
                }
            }
        }
}

// ---------------------------------------------------------------------------
// gx MFMA: gates x-projection, M=256, N=2048, K=1024, grid (2,16,2 paths).
// ---------------------------------------------------------------------------
__global__ __launch_bounds__(256) void gx_mfma_kernel(
    const uint16_t* __restrict__ inm, const uint16_t* __restrict__ ina,
    const float* __restrict__ wih_m, const float* __restrict__ bih_m, const float* __restrict__ bhh_m,
    const float* __restrict__ wih_a, const float* __restrict__ bih_a, const float* __restrict__ bhh_a,
    float* __restrict__ gxm, float* __restrict__ gxa)
{
    __shared__ __align__(16) uint16_t Aa[128 * LSTR];
    __shared__ __align__(16) uint16_t Bb[128 * LSTR];

    const int row0 = blockIdx.x * 128;
    const int col0 = blockIdx.y * 128;
    const int path = blockIdx.z;

    const uint16_t* A = path ? ina : inm;
    const float* W  = path ? wih_a : wih_m;
    const float* bi = path ? bih_a : bih_m;
    const float* bh = path ? bhh_a : bhh_m;
    float* out = path ? gxa : gxm;

    const int t = threadIdx.x;
    const int w = t >> 6, l = t & 63;
    const int wr = (w >> 1) * 64, wc = (w & 1) * 64;

    const int srow  = t >> 1;
    const int shalf = (t & 1) * 16;
    const uint16_t* ap = A + (size_t)(row0 + srow) * 1024 + shalf;
    const float*    bp = W + (size_t)(col0 + srow) * 1024 + shalf;
    uint16_t* awr = Aa + srow * LSTR + shalf;
    uint16_t* bwr = Bb + srow * LSTR + shalf;

    f32x4 acc[4][4] = {};

    for (int kk = 0; kk < 1024; kk += 32) {
        u16x8 a0 = *(const u16x8*)(ap + kk);
        u16x8 a1 = *(const u16x8*)(ap + kk + 8);
        float4 f0 = *(const float4*)(bp + kk);
        float4 f1 = *(const float4*)(bp + kk + 4);
        float4 f2 = *(const float4*)(bp + kk + 8);
        float4 f3 = *(const float4*)(bp + kk + 12);
        union { u16x8 v; uint32_t u[4]; } b0, b1;
        b0.u[0] = cvtpk(f0.x, f0.y); b0.u[1] = cvtpk(f0.z, f0.w);
        b0.u[2] = cvtpk(f1.x, f1.y); b0.u[3] = cvtpk(f1.z, f1.w);
        b1.u[0] = cvtpk(f2.x, f2.y); b1.u[1] = cvtpk(f2.z, f2.w);
        b1.u[2] = cvtpk(f3.x, f3.y); b1.u[3] = cvtpk(f3.z, f3.w);

        __syncthreads();
        *(u16x8*)awr       = a0;
        *(u16x8*)(awr + 8) = a1;
        *(u16x8*)bwr       = b0.v;
        *(u16x8*)(bwr + 8) = b1.v;
        __syncthreads();

        const int row = l & 15, kg = (l >> 4) * 8;
        bf16x8 afr[4], bfr[4];
#pragma unroll
        for (int i = 0; i < 4; ++i)
            afr[i] = *(const bf16x8*)(Aa + (wr + i * 16 + row) * LSTR + kg);
#pragma unroll
        for (int j = 0; j < 4; ++j)
            bfr[j] = *(const bf16x8*)(Bb + (wc + j * 16 + row) * LSTR + kg);
#pragma unroll
        for (int i = 0; i < 4; ++i)
#pragma unroll
            for (int j = 0; j < 4; ++j)
                acc[i][j] = __builtin_amdgcn_mfma_f32_16x16x32_bf16(
                    afr[i], bfr[j], acc[i][j], 0, 0, 0);
    }

    const int col = l & 15, rg = (l >> 4) * 4;
#pragma unroll
    for (int i = 0; i < 4; ++i)
#pragma unroll
        for (int r = 0; r < 4; ++r) {
            const int grow = row0 + wr + i * 16 + rg + r;
#pragma unroll
            for (int j = 0; j < 4; ++j) {
                const int jj = col0 + wc + j * 16 + col;
                out[(size_t)grow * 2048 + jj] = acc[i][j][r] + bi[jj] + bh[jj];
            }
        }
}

// ---------------------------------------------------------------------------
// Persistent LSTM scan v5b: fence-free point-to-point sync (IC-coherent).
// ---------------------------------------------------------------------------
__device__ __forceinline__ void wait_cnt(int* cnt, int target) {
    if (threadIdx.x == 0) {
        while (__hip_atomic_load(cnt, __ATOMIC_RELAXED, __HIP_MEMORY_SCOPE_AGENT) < target)
            __builtin_amdgcn_s_sleep(1);
    }
    __syncthreads();
}

__device__ __forceinline__ void post_cnt(int* cnt) {
    __syncthreads();   // drains vmcnt(0): all waves' sc1 stores reached the IC
    if (threadIdx.x == 0)
        __hip_atomic_fetch_add(cnt, 1, __ATOMIC_RELAXED, __HIP_MEMORY_SCOPE_AGENT);
}

__device__ __forceinline__ void stage_state(uint16_t* dst, const uint32_t* src, int tid) {
#pragma unroll
    for (int i = 0; i < 4; ++i) {
        const int idx = i * 1024 + tid * 4;
        uint4 v = *(const uint4*)(src + idx);
        const int flat = idx * 2;
        union { uint4 q; u16x8 h; } cv; cv.q = v;
        *(u16x8*)(dst + (flat >> 9) * 520 + (flat & 511)) = cv.h;
    }
}

__global__ __launch_bounds__(256, 1) void lstm_scan5_kernel(
    const float* __restrict__ gxm, const float* __restrict__ gxa,
    const uint16_t* __restrict__ pw1, const uint16_t* __restrict__ pw2m,
    const uint16_t* __restrict__ pw2a,
    const float* __restrict__ b2m_s, const float* __restrict__ b2a_s,
    uint32_t* __restrict__ s1p, uint32_t* __restrict__ s2ap,
    int* __restrict__ s1cnt, int* __restrict__ s2acnt,
    float* __restrict__ out)
{
    __shared__ __align__(16) uint16_t wlds[64 * 520];
    __shared__ __align__(16) uint16_t xs[16 * 520];
    __shared__ __align__(16) uint16_t hs[16 * 520];
    __shared__ float gbuf[2][16][68];

    const int bk  = blockIdx.x;
    const int tid = threadIdx.x;
    const int w   = tid >> 6, l = tid & 63;
    const int lrow = l & 15, kg = (l >> 4) * 8;

    const int role = (bk < 64) ? 0 : (bk < 96) ? 1 : 2;   // S1, S2M, S2A
    const int path = (role == 0) ? (bk >> 5) : (role == 1 ? 0 : 1);
    const int tile = (role == 0) ? (bk & 31) : (role == 1 ? bk - 64 : bk - 96);
    const int j0   = tile * ((role == 2) ? 8 : 16);

    const uint16_t* wsrc =
        (role == 0) ? pw1 + ((size_t)path * 32 + tile) * 64 * 512 :
        (role == 1) ? pw2m + (size_t)tile * 64 * 512
                    : pw2a + (size_t)tile * 64 * 512;
    for (int idx = tid; idx < 64 * 64; idx += 256) {
        int row = idx >> 6, c = idx & 63;
        *(u16x8*)(wlds + row * 520 + c * 8) = *(const u16x8*)(wsrc + row * 512 + c * 8);
    }

    float cv = 0.f;
    const float* gx1 = path ? gxa : gxm;

    if (role == 0) {
        const int b = tid >> 4, j = tid & 15, jg = j0 + j;
        const size_t obase = path ? 0 : 262144;
        for (int t = 0; t < 16; ++t) {
            const float* gxr = gx1 + ((size_t)(t * 16 + b)) * 2048;
            float g0 = gxr[jg], g1 = gxr[512 + jg], g2 = gxr[1024 + jg], g3 = gxr[1536 + jg];
            if (t > 0) wait_cnt(&s1cnt[path * 16 + t - 1], 32);
            stage_state(xs, s1p + ((size_t)t * 2 + path) * 4096, tid);
            __syncthreads();
            f32x4 acc = {};
#pragma unroll
            for (int kk = 0; kk < 512; kk += 32) {
                bf16x8 a  = *(const bf16x8*)(xs + lrow * 520 + kk + kg);
                bf16x8 bw = *(const bf16x8*)(wlds + (w * 16 + lrow) * 520 + kk + kg);
                acc = __builtin_amdgcn_mfma_f32_16x16x32_bf16(a, bw, acc, 0, 0, 0);
            }
#pragma unroll
            for (int r = 0; r < 4; ++r)
                gbuf[0][(l >> 4) * 4 + r][w * 16 + lrow] = acc[r];
            __syncthreads();

            float G0 = gbuf[0][b][j * 4 + 0] + g0;
            float G1 = gbuf[0][b][j * 4 + 1] + g1;
            float G2 = gbuf[0][b][j * 4 + 2] + g2;
            float G3 = gbuf[0][b][j * 4 + 3] + g3;
            cv = sigm(G1) * cv + sigm(G0) * tanhf(G2);
            float h = sigm(G3) * tanhf(cv);
            out[obase + ((size_t)b * 16 + t) * 1024 + jg] = h;
            float hn = __shfl_xor(h, 1);
            if ((j & 1) == 0) {
                uint32_t pk = (uint32_t)f2bf(h) | ((uint32_t)f2bf(hn) << 16);
                __hip_atomic_store(s1p + ((size_t)(t + 1) * 2 + path) * 4096 + b * 256 + (jg >> 1),
                                   pk, __ATOMIC_RELAXED, __HIP_MEMORY_SCOPE_AGENT);
            }
            post_cnt(&s1cnt[path * 16 + t]);
        }
    } else if (role == 1) {
        const int b = tid >> 4, j = tid & 15, jg = j0 + j;
        const float B0 = b2m_s[jg], B1 = b2m_s[512 + jg], B2 = b2m_s[1024 + jg], B3 = b2m_s[1536 + jg];
        for (int t = 0; t < 16; ++t) {
            wait_cnt(&s1cnt[t], 32);
            stage_state(xs, s1p + ((size_t)(t + 1) * 2 + 0) * 4096, tid);
            __syncthreads();
            f32x4 acc = {};
#pragma unroll
            for (int kk = 0; kk < 512; kk += 32) {
                bf16x8 a  = *(const bf16x8*)(xs + lrow * 520 + kk + kg);
                bf16x8 bw = *(const bf16x8*)(wlds + (w * 16 + lrow) * 520 + kk + kg);
                acc = __builtin_amdgcn_mfma_f32_16x16x32_bf16(a, bw, acc, 0, 0, 0);
            }
#pragma unroll
            for (int r = 0; r < 4; ++r)
                gbuf[0][(l >> 4) * 4 + r][w * 16 + lrow] = acc[r];
            __syncthreads();

            float G0 = gbuf[0][b][j * 4 + 0] + B0;
            float G1 = gbuf[0][b][j * 4 + 1] + B1;
            float G2 = gbuf[0][b][j * 4 + 2] + B2;
            float G3 = gbuf[0][b][j * 4 + 3] + B3;
            cv = sigm(G1) * cv + sigm(G0) * tanhf(G2);
            float h = sigm(G3) * tanhf(cv);
            out[262144 + ((size_t)b * 16 + t) * 1024 + 512 + jg] = h;
        }
    } else {
        const int b = tid >> 3, j = tid & 7, jg = j0 + j;
        float B0 = 0, B1 = 0, B2 = 0, B3 = 0;
        if (tid < 128) {
            B0 = b2a_s[jg]; B1 = b2a_s[512 + jg]; B2 = b2a_s[1024 + jg]; B3 = b2a_s[1536 + jg];
        }
        for (int t = 0; t < 16; ++t) {
            wait_cnt(&s1cnt[16 + t], 32);
            if (t > 0) wait_cnt(&s2acnt[t - 1], 64);
            stage_state(xs, s1p + ((size_t)(t + 1) * 2 + 1) * 4096, tid);
            stage_state(hs, s2ap + (size_t)t * 4096, tid);
            __syncthreads();
            const uint16_t* src = (w < 2) ? xs : hs;
            const int wt = (w < 2) ? w : w - 2;
            const int wb = (w < 2) ? 0 : 32 * 520;
            f32x4 acc = {};
#pragma unroll
            for (int kk = 0; kk < 512; kk += 32) {
                bf16x8 a  = *(const bf16x8*)(src + lrow * 520 + kk + kg);
                bf16x8 bw = *(const bf16x8*)(wlds + wb + (wt * 16 + lrow) * 520 + kk + kg);
                acc = __builtin_amdgcn_mfma_f32_16x16x32_bf16(a, bw, acc, 0, 0, 0);
            }
#pragma unroll
            for (int r = 0; r < 4; ++r)
                gbuf[w >> 1][(l >> 4) * 4 + r][wt * 16 + lrow] = acc[r];
            __syncthreads();

            if (tid < 128) {
                float G0 = gbuf[0][b][j * 4 + 0] + gbuf[1][b][j * 4 + 0] + B0;
                float G1 = gbuf[0][b][j * 4 + 1] + gbuf[1][b][j * 4 + 1] + B1;
                float G2 = gbuf[0][b][j * 4 + 2] + gbuf[1][b][j * 4 + 2] + B2;
                float G3 = gbuf[0][b][j * 4 + 3] + gbuf[1][b][j * 4 + 3] + B3;
                cv = sigm(G1) * cv + sigm(G0) * tanhf(G2);
                float h = sigm(G3) * tanhf(cv);
                out[((size_t)b * 16 + t) * 1024 + 512 + jg] = h;
                float hn = __shfl_xor(h, 1);
                if ((j & 1) == 0) {
                    uint32_t pk = (uint32_t)f2bf(h) | ((uint32_t)f2bf(hn) << 16);
                    __hip_atomic_store(s2ap + (size_t)(t + 1) * 4096 + b * 256 + (jg >> 1),
                                       pk, __ATOMIC_RELAXED, __HIP_MEMORY_SCOPE_AGENT);
                }
            }
            post_cnt(&s2acnt[t]);
        }
    }
}

// ---------------------------------------------------------------------------
extern "C" void kernel_launch(void* const* d_in, const int* in_sizes, int n_in,
                              void* d_out, int out_size, void* d_ws, size_t ws_size,
                              hipStream_t stream)
{
    (void)in_sizes; (void)n_in; (void)out_size; (void)ws_size;
    const float* f_t     = (const float*)d_in[0];
    const float* f_t_1   = (const float*)d_in[1];
    const float* att1    = (const float*)d_in[2];
    const float* att2    = (const float*)d_in[3];
    const float* conv1_w = (const float*)d_in[4];
    const float* conv1_b = (const float*)d_in[5];
    const float* conv2_w = (const float*)d_in[6];
    const float* conv2_b = (const float*)d_in[7];
    const float* l1a_wih = (const float*)d_in[8];
    const float* l1a_whh = (const float*)d_in[9];
    const float* l1a_bih = (const float*)d_in[10];
    const float* l1a_bhh = (const float*)d_in[11];
    const float* l2a_wih = (const float*)d_in[12];
    const float* l2a_whh = (const float*)d_in[13];
    const float* l2a_bih = (const float*)d_in[14];
    const float* l2a_bhh = (const float*)d_in[15];
    const float* l1m_wih = (const float*)d_in[16];
    const float* l1m_whh = (const float*)d_in[17];
    const float* l1m_bih = (const float*)d_in[18];
    const float* l1m_bhh = (const float*)d_in[19];
    const float* l2m_wih = (const float*)d_in[20];
    const float* l2m_whh = (const float*)d_in[21];
    const float* l2m_bih = (const float*)d_in[22];
    const float* l2m_bhh = (const float*)d_in[23];
    const float* fc1_w   = (const float*)d_in[24];
    const float* fc1_b   = (const float*)d_in[25];
    const float* fc2_w   = (const float*)d_in[26];
    const float* fc2_b   = (const float*)d_in[27];

    char* p = (char*)d_ws;
    // part (64MB, fc1 split-K=32 partials) aliases in1_nhwc (dead after conv1)
    float*    part     = (float*)p;
    uint16_t* in1_nhwc = (uint16_t*)p;             // [256][1024][128] bf16
    p += (size_t)64 << 20;
    uint16_t* c1out    = (uint16_t*)p; p += (size_t)32 << 20;  // [256][1024][64] NHWC
    uint16_t* mbuf16   = (uint16_t*)p; p += (size_t)32 << 20;  // [256][64][1024] NCHW
    uint16_t* ftflat16 = (uint16_t*)p; p += (size_t)32 << 20;  // [256][65536]
    uint16_t* wpack1   = (uint16_t*)p; p += 256 * 1024;
    uint16_t* wpack2   = (uint16_t*)p; p += 128 * 1024;
    uint16_t* hbuf16 = (uint16_t*)p; p += (size_t)2 << 20;
    uint16_t* inm  = (uint16_t*)p; p += (size_t)1 << 20;
    uint16_t* ina  = (uint16_t*)p; p += (size_t)1 << 20;
    float* gxm  = (float*)p; p += (size_t)2 << 20;
    float* gxa  = (float*)p; p += (size_t)2 << 20;
    uint16_t* pw1  = (uint16_t*)p; p += (size_t)2097152 * 2;
    uint16_t* pw2m = (uint16_t*)p; p += (size_t)1048576 * 2;
    uint16_t* pw2a = (uint16_t*)p; p += (size_t)2097152 * 2;
    float* b2m_s = (float*)p; p += 2048 * 4;
    float* b2a_s = (float*)p; p += 2048 * 4;
    uint32_t* s1p  = (uint32_t*)p; p += (size_t)17 * 2 * 4096 * 4;
    uint32_t* s2ap = (uint32_t*)p; p += (size_t)17 * 4096 * 4;
    int* s1cnt  = (int*)p; p += 32 * 4;
    int* s2acnt = (int*)p; p += 16 * 4;

    float* outp = (float*)d_out;
    float* alpha_out = outp + 524288;

    hipMemsetAsync(s1p, 0, 2 * 4096 * 4, stream);
    hipMemsetAsync(s2ap, 0, 4096 * 4, stream);
    hipMemsetAsync(s1cnt, 0, 48 * 4, stream);

    prep_all_kernel<<<15136, 256, 0, stream>>>(
        f_t, f_t_1, conv1_w, conv2_w,
        l1m_whh, l1a_whh, l2m_wih, l2m_whh, l2a_wih, l2a_whh,
        l2m_bih, l2m_bhh, l2a_bih, l2a_bhh,
        ftflat16, in1_nhwc, wpack1, wpack2,
        pw1, pw2m, pw2a, b2m_s, b2a_s);

    conv_mfma2_kernel<128, false><<<dim3(8, 256), 256, 0, stream>>>(
        in1_nhwc, wpack1, conv1_b, c1out);
    conv_mfma2_kernel<64, true><<<dim3(8, 256), 256, 0, stream>>>(
        c1out, wpack2, conv2_b, mbuf16);

    fc1_mfma_kernel<<<512, 256, 0, stream>>>(mbuf16, ftflat16, fc1_w, part);
    fc1_reduce_kernel<<<2048, 256, 0, stream>>>(part, fc1_b, hbuf16);

    fc2_att_mfma_kernel<<<dim3(4, 4), 256, 0, stream>>>(hbuf16, fc2_w, fc2_b, att1, att2,
                                                        alpha_out, inm, ina);

    gx_mfma_kernel<<<dim3(2, 16, 2), 256, 0, stream>>>(inm, ina,
                                                       l1m_wih, l1m_bih, l1m_bhh,
                                                       l1a_wih, l1a_bih, l1a_bhh,
                                                       gxm, gxa);

    lstm_scan5_kernel<<<NBLK, 256, 0, stream>>>(
        gxm, gxa, pw1, pw2m, pw2a, b2m_s, b2a_s,
        s1p, s2ap, s1cnt, s2acnt, outp);
}

// Round 21
// 481.949 us; speedup vs baseline: 1.3348x; 1.0314x over previous
//
#include <hip/hip_runtime.h>
#include <math.h>
#include <stdint.h>

typedef __attribute__((ext_vector_type(8))) short    bf16x8;
typedef __attribute__((ext_vector_type(4))) float    f32x4;
typedef __attribute__((ext_vector_type(8))) uint16_t u16x8;
typedef __attribute__((ext_vector_type(4))) uint16_t u16x4;

#define LSTR 40   // LDS row stride (bf16): 80B rows -> 2-way banks (free)
#define NBLK 160  // persistent LSTM blocks

__device__ __forceinline__ uint16_t f2bf(float f) {
    union { float f; uint32_t u; } v; v.f = f;
    uint32_t r = v.u + 0x7FFFu + ((v.u >> 16) & 1u);
    return (uint16_t)(r >> 16);
}

__device__ __forceinline__ float sigm(float x) { return 1.f / (1.f + expf(-x)); }

// packed RNE f32x2 -> bf16x2
__device__ __forceinline__ uint32_t cvtpk(float lo, float hi) {
    uint32_t r;
    asm volatile("v_cvt_pk_bf16_f32 %0, %1, %2" : "=v"(r) : "v"(lo), "v"(hi));
    return r;
}

// ---------------------------------------------------------------------------
// prep (fused): blocks [0,8192) cvt_flat (coalesced), [8192,12288) nhwc,
// [12288,12576) wpack, [12576,15136) lstm_pack.
// ---------------------------------------------------------------------------
__global__ __launch_bounds__(256) void prep_all_kernel(
    const float* __restrict__ f_t, const float* __restrict__ f_t_1,
    const float* __restrict__ w1, const float* __restrict__ w2,
    const float* __restrict__ whh_m, const float* __restrict__ whh_a,
    const float* __restrict__ m_wih, const float* __restrict__ m_whh,
    const float* __restrict__ a_wih, const float* __restrict__ a_whh,
    const float* __restrict__ m_bih, const float* __restrict__ m_bhh,
    const float* __restrict__ a_bih, const float* __restrict__ a_bhh,
    uint16_t* __restrict__ ftflat16, uint16_t* __restrict__ in1_nhwc,
    uint16_t* __restrict__ p1, uint16_t* __restrict__ p2,
    uint16_t* __restrict__ pw1, uint16_t* __restrict__ pw2m,
    uint16_t* __restrict__ pw2a,
    float* __restrict__ b2m_s, float* __restrict__ b2a_s)
{
    __shared__ float lds[32][258];
    const int bid = blockIdx.x;
    const int tid = threadIdx.x;

    if (bid < 8192) {
        int i = (bid * 256 + tid) * 8;
        float4 a = *(const float4*)(f_t + i);
        float4 b = *(const float4*)(f_t + i + 4);
        u16x8 o;
        o[0] = f2bf(a.x); o[1] = f2bf(a.y); o[2] = f2bf(a.z); o[3] = f2bf(a.w);
        o[4] = f2bf(b.x); o[5] = f2bf(b.y); o[6] = f2bf(b.z); o[7] = f2bf(b.w);
        *(u16x8*)(ftflat16 + i) = o;
    } else if (bid < 12288) {
        const int v   = bid - 8192;
        const int bt  = v >> 4;
        const int c0  = ((v & 15) >> 2) * 32;
        const int px0 = (v & 3) * 256;
        const int lc  = tid & 31;
        const int lpx = (tid >> 5) * 32;
        const int c   = c0 + lc;
        const float* src = (c < 64)
            ? (f_t   + ((size_t)bt * 64 + c) * 1024)
            : (f_t_1 + ((size_t)bt * 64 + (c - 64)) * 1024);
#pragma unroll
        for (int j = 0; j < 32; j += 4) {
            float4 vv = *(const float4*)(src + px0 + lpx + j);
            lds[lc][lpx + j + 0] = vv.x;
            lds[lc][lpx + j + 1] = vv.y;
            lds[lc][lpx + j + 2] = vv.z;
            lds[lc][lpx + j + 3] = vv.w;
        }
        __syncthreads();
        uint16_t* op = in1_nhwc + ((size_t)bt * 1024 + px0 + tid) * 128 + c0;
#pragma unroll
        for (int u0 = 0; u0 < 32; u0 += 8) {
            u16x8 o;
#pragma unroll
            for (int u = 0; u < 8; ++u) o[u] = f2bf(lds[u0 + u][tid]);
            *(u16x8*)(op + u0) = o;
        }
    } else if (bid < 12576) {
        int i = (bid - 12288) * 256 + tid;
        if (i < 64 * 1152) {
            int oc = i / 1152, k = i - oc * 1152;
            int s = k >> 7, c = k & 127;
            int ky = s / 3, kx = s - ky * 3;
            p1[i] = f2bf(w1[((oc * 128 + c) * 3 + ky) * 3 + kx]);
        }
        if (i < 64 * 576) {
            int oc = i / 576, k = i - oc * 576;
            int s = k >> 6, c = k & 63;
            int ky = s / 3, kx = s - ky * 3;
            p2[i] = f2bf(w2[((oc * 64 + c) * 3 + ky) * 3 + kx]);
        }
    } else {
        int id = (bid - 12576) * 256 + tid;
        if (id < 2048) {
            b2m_s[id] = m_bih[id] + m_bhh[id];
            b2a_s[id] = a_bih[id] + a_bhh[id];
        }
        if (id < 262144) {                       // pw1
            int kc = id & 63, g = (id >> 6) & 3, j = (id >> 8) & 511, pp = id >> 17;
            const float* src = (pp ? whh_a : whh_m) + ((size_t)(g * 512 + j)) * 512 + kc * 8;
            uint16_t* dst = pw1 + ((((size_t)pp * 32 + (j >> 4)) * 64 + (j & 15) * 4 + g) * 512) + kc * 8;
            float4 a = *(const float4*)src; float4 b = *(const float4*)(src + 4);
            u16x8 o;
            o[0]=f2bf(a.x); o[1]=f2bf(a.y); o[2]=f2bf(a.z); o[3]=f2bf(a.w);
            o[4]=f2bf(b.x); o[5]=f2bf(b.y); o[6]=f2bf(b.z); o[7]=f2bf(b.w);
            *(u16x8*)dst = o;
        } else if (id < 393216) {                // pw2m (sum)
            int id2 = id - 262144;
            int kc = id2 & 63, g = (id2 >> 6) & 3, j = id2 >> 8;
            size_t off = ((size_t)(g * 512 + j)) * 512 + kc * 8;
            const float* s1 = m_wih + off; const float* s2 = m_whh + off;
            uint16_t* dst = pw2m + (((size_t)(j >> 4)) * 64 + (j & 15) * 4 + g) * 512 + kc * 8;
            u16x8 o;
#pragma unroll
            for (int u = 0; u < 8; ++u) o[u] = f2bf(s1[u] + s2[u]);
            *(u16x8*)dst = o;
        } else if (id < 655360) {                // pw2a
            int id3 = id - 393216;
            int kc = id3 & 63, g = (id3 >> 6) & 3, j = (id3 >> 8) & 511, mat = id3 >> 17;
            const float* src = (mat ? a_whh : a_wih) + ((size_t)(g * 512 + j)) * 512 + kc * 8;
            uint16_t* dst = pw2a + ((((size_t)(j >> 3)) * 2 + mat) * 32 + (j & 7) * 4 + g) * 512 + kc * 8;
            float4 a = *(const float4*)src; float4 b = *(const float4*)(src + 4);
            u16x8 o;
            o[0]=f2bf(a.x); o[1]=f2bf(a.y); o[2]=f2bf(a.z); o[3]=f2bf(a.w);
            o[4]=f2bf(b.x); o[5]=f2bf(b.y); o[6]=f2bf(b.z); o[7]=f2bf(b.w);
            *(u16x8*)dst = o;
        }
    }
}

// ---------------------------------------------------------------------------
// conv3x3 + bias + relu, implicit-GEMM MFMA v5 (R20-proven): halo once;
// tap-level W staging with next-tap register prefetch after the ready-barrier.
// ---------------------------------------------------------------------------
template<int IC, bool SWAP>
__global__ __launch_bounds__(256) void conv_mfma2_kernel(
    const uint16_t* __restrict__ in_nhwc,
    const uint16_t* __restrict__ wpack,
    const float* __restrict__ bias,
    uint16_t* __restrict__ out)
{
    constexpr int ICP = IC + 8;           // halo row pad
    constexpr int BWP = IC + 8;           // Bw row pad (2-way banks, free)
    constexpr int KT  = 9 * IC;
    constexpr int CPS = IC / 32;
    constexpr int C8  = IC / 8;
    constexpr int NW  = (64 * IC / 8) / 256;   // u16x8 stage iters per thread (4 / 2)
    constexpr int MF  = SWAP ? 4 : 2;
    constexpr int NF  = SWAP ? 2 : 4;

    __shared__ __align__(16) uint16_t Ah[6 * 34 * ICP];
    __shared__ __align__(16) uint16_t Bw[64 * BWP];

    const int bt  = blockIdx.y;
    const int px0 = blockIdx.x * 128;
    const int y0  = blockIdx.x * 4;
    const int tid = threadIdx.x;
    const int w   = tid >> 6, l = tid & 63;
    const int lrow = l & 15, kg = (l >> 4) * 8;

    for (int idx = tid; idx < 204 * C8; idx += 256) {
        int cpos = idx / C8;
        int c8   = (idx - cpos * C8) * 8;
        int hy = cpos / 34, hx = cpos - hy * 34;
        int gy = y0 - 1 + hy, gx = hx - 1;
        u16x8 v = {};
        if (gy >= 0 && gy < 32 && gx >= 0 && gx < 32)
            v = *(const u16x8*)(in_nhwc + (((size_t)bt * 1024) + gy * 32 + gx) * IC + c8);
        *(u16x8*)(Ah + (hy * 34 + hx) * ICP + c8) = v;
    }

    f32x4 acc[MF][NF] = {};

    int abase[MF > NF ? MF : 2];
#pragma unroll
    for (int i = 0; i < (SWAP ? 2 : MF); ++i) {
        int m  = w * 32 + i * 16 + lrow;
        int py = m >> 5, px = m & 31;
        abase[i] = (py * 34 + px) * ICP;
    }

    const int wRow0 = tid / (IC / 8);
    const int wChk  = (tid % (IC / 8)) * 8;
    const int rowsPerIter = 256 / (IC / 8);

    // prologue: prefetch tap 0's W
    u16x8 wreg[NW];
#pragma unroll
    for (int i = 0; i < NW; ++i) {
        const int row = wRow0 + i * rowsPerIter;
        wreg[i] = *(const u16x8*)(wpack + (size_t)row * KT + 0 * IC + wChk);
    }

    for (int s = 0; s < 9; ++s) {
        const int ky = s / 3, kx = s - ky * 3;

        __syncthreads();                  // prior tap's Bw reads (and halo @s==0) done
#pragma unroll
        for (int i = 0; i < NW; ++i) {
            const int row = wRow0 + i * rowsPerIter;
            *(u16x8*)(Bw + row * BWP + wChk) = wreg[i];
        }
        __syncthreads();                  // tap W ready

        // issue NEXT tap's W loads: latency hides under the MFMA loop below
        if (s + 1 < 9) {
#pragma unroll
            for (int i = 0; i < NW; ++i) {
                const int row = wRow0 + i * rowsPerIter;
                wreg[i] = *(const u16x8*)(wpack + (size_t)row * KT + (s + 1) * IC + wChk);
            }
        }

#pragma unroll
        for (int c = 0; c < CPS; ++c) {
            const int cc = c * 32;
            const int aoff = (ky * 34 + kx) * ICP + cc + kg;

            if (!SWAP) {
                bf16x8 af[2], bf[4];
#pragma unroll
                for (int i = 0; i < 2; ++i)
                    af[i] = *(const bf16x8*)(Ah + abase[i] + aoff);
#pragma unroll
                for (int j = 0; j < 4; ++j)
                    bf[j] = *(const bf16x8*)(Bw + (j * 16 + lrow) * BWP + cc + kg);
#pragma unroll
                for (int i = 0; i < MF; ++i)
#pragma unroll
                    for (int j = 0; j < NF; ++j)
                        acc[i][j] = __builtin_amdgcn_mfma_f32_16x16x32_bf16(
                            af[i], bf[j], acc[i][j], 0, 0, 0);
            } else {
                bf16x8 af[4], bf[2];
#pragma unroll
                for (int i = 0; i < 4; ++i)
                    af[i] = *(const bf16x8*)(Bw + (i * 16 + lrow) * BWP + cc + kg);
#pragma unroll
                for (int j = 0; j < 2; ++j)
                    bf[j] = *(const bf16x8*)(Ah + abase[j] + aoff);
#pragma unroll
                for (int i = 0; i < MF; ++i)
#pragma unroll
                    for (int j = 0; j < NF; ++j)
                        acc[i][j] = __builtin_amdgcn_mfma_f32_16x16x32_bf16(
                            af[i], bf[j], acc[i][j], 0, 0, 0);
            }
        }
    }

    const int col = l & 15, rg = (l >> 4) * 4;
    if (!SWAP) {
#pragma unroll
        for (int i = 0; i < 2; ++i)
#pragma unroll
            for (int j = 0; j < 4; ++j) {
                const int ocb = j * 16 + col;
                const float bv = bias[ocb];
#pragma unroll
                for (int r = 0; r < 4; ++r) {
                    const int px = px0 + w * 32 + i * 16 + rg + r;
                    float v = acc[i][j][r] + bv; v = v > 0.f ? v : 0.f;
                    out[((size_t)bt * 1024 + px) * 64 + ocb] = f2bf(v);
                }
            }
    } else {
#pragma unroll
        for (int i = 0; i < 4; ++i)
#pragma unroll
            for (int j = 0; j < 2; ++j)
#pragma unroll
                for (int r = 0; r < 4; ++r) {
                    const int oc = i * 16 + rg + r;
                    const int px = px0 + w * 32 + j * 16 + col;
                    float v = acc[i][j][r] + bias[oc]; v = v > 0.f ? v : 0.f;
                    out[((size_t)bt * 64 + oc) * 1024 + px] = f2bf(v);
                }
    }
}

// ---------------------------------------------------------------------------
// fc1 MFMA v6: R7 geometry + coalesced slot staging + NEXT-iter register
// prefetch after the ready-barrier (conv-v5's proven schedule).
// BM=256, BN=128, BK=32, split-K=32, grid 512; 32 MFMAs per barrier pair.
// ---------------------------------------------------------------------------
__global__ __launch_bounds__(256) void fc1_mfma_kernel(
    const uint16_t* __restrict__ Am, const uint16_t* __restrict__ Af,
    const float* __restrict__ Wf, float* __restrict__ part)
{
    __shared__ __align__(16) uint16_t Aa[256 * LSTR];
    __shared__ __align__(16) uint16_t Bb[128 * LSTR];

    const int id  = blockIdx.x;
    const int vid = (id & 7) * 64 + (id >> 3);   // 512 % 8 == 0 -> bijective
    const int bx  = vid & 1;
    const int by  = (vid >> 1) & 7;
    const int ks  = vid >> 4;

    const int row0 = bx * 256;
    const int col0 = by * 128;
    const size_t kbase = (size_t)ks * 2048;
    const uint16_t* Abase = bx ? Af : Am;

    const int tid = threadIdx.x;
    const int w = tid >> 6, l = tid & 63;
    const int lrow = l & 15, kg = (l >> 4) * 8;

    const int arow = tid >> 2, achk = (tid & 3) * 8;
    const int brow = tid >> 3, bchk = (tid & 7) * 4;

    f32x4 acc[4][8] = {};

    // prologue: prefetch kk = 0
    u16x8 ra[4];
    float4 rb[4];
#pragma unroll
    for (int i = 0; i < 4; ++i)
        ra[i] = *(const u16x8*)(Abase + (size_t)(i * 64 + arow) * 65536 + kbase + achk);
#pragma unroll
    for (int i = 0; i < 4; ++i)
        rb[i] = *(const float4*)(Wf + (size_t)(col0 + i * 32 + brow) * 65536 + kbase + bchk);

    for (int kk = 0; kk < 2048; kk += 32) {
        union { u16x4 v; uint32_t u[2]; } cb[4];
#pragma unroll
        for (int i = 0; i < 4; ++i) {
            cb[i].u[0] = cvtpk(rb[i].x, rb[i].y);
            cb[i].u[1] = cvtpk(rb[i].z, rb[i].w);
        }

        __syncthreads();                  // prior iter's LDS reads done
#pragma unroll
        for (int i = 0; i < 4; ++i)
            *(u16x8*)(Aa + (i * 64 + arow) * LSTR + achk) = ra[i];
#pragma unroll
        for (int i = 0; i < 4; ++i)
            *(u16x4*)(Bb + (i * 32 + brow) * LSTR + bchk) = cb[i].v;
        __syncthreads();                  // tile ready

        // issue NEXT iter's loads: latency hides under the 32 MFMAs below
        if (kk + 32 < 2048) {
#pragma unroll
            for (int i = 0; i < 4; ++i)
                ra[i] = *(const u16x8*)(Abase + (size_t)(i * 64 + arow) * 65536 + kbase + kk + 32 + achk);
#pragma unroll
            for (int i = 0; i < 4; ++i)
                rb[i] = *(const float4*)(Wf + (size_t)(col0 + i * 32 + brow) * 65536 + kbase + kk + 32 + bchk);
        }

        bf16x8 afr[4], bfr[8];
#pragma unroll
        for (int i = 0; i < 4; ++i)
            afr[i] = *(const bf16x8*)(Aa + (w * 64 + i * 16 + lrow) * LSTR + kg);
#pragma unroll
        for (int j = 0; j < 8; ++j)
            bfr[j] = *(const bf16x8*)(Bb + (j * 16 + lrow) * LSTR + kg);
#pragma unroll
        for (int i = 0; i < 4; ++i)
#pragma unroll
            for (int j = 0; j < 8; ++j)
                acc[i][j] = __builtin_amdgcn_mfma_f32_16x16x32_bf16(
                    afr[i], bfr[j], acc[i][j], 0, 0, 0);
    }

    const int col = l & 15, rg = (l >> 4) * 4;
#pragma unroll
    for (int i = 0; i < 4; ++i)
#pragma unroll
        for (int r = 0; r < 4; ++r) {
            const int grow = row0 + w * 64 + i * 16 + rg + r;
            float* op = part + ((size_t)ks * 512 + grow) * 1024 + col0 + col;
#pragma unroll
            for (int j = 0; j < 8; ++j) op[j * 16] = acc[i][j][r];
        }
}

__global__ __launch_bounds__(256) void fc1_reduce_kernel(
    const float* __restrict__ part, const float* __restrict__ bias,
    uint16_t* __restrict__ h16)
{
    int idx = blockIdx.x * 256 + threadIdx.x;
    int j = idx & 1023;
    float s = bias[j];
#pragma unroll
    for (int ks = 0; ks < 32; ++ks) s += part[(size_t)ks * 524288 + idx];
    h16[idx] = f2bf(s > 0.f ? s : 0.f);
}

// ---------------------------------------------------------------------------
// fc2 MFMA + attention epilogue.  A = hbuf bf16; outputs inm/ina bf16.
// ---------------------------------------------------------------------------
__global__ __launch_bounds__(256) void fc2_att_mfma_kernel(
    const uint16_t* __restrict__ h16, const float* __restrict__ wf,
    const float* __restrict__ bias,
    const float* __restrict__ att1, const float* __restrict__ att2,
    float* __restrict__ alpha_out, uint16_t* __restrict__ inm, uint16_t* __restrict__ ina)
{
    __shared__ __align__(16) uint16_t Aa[128 * LSTR];
    __shared__ __align__(16) uint16_t Bb[128 * LSTR];

    const int row0 = blockIdx.x * 128;
    const int col0 = blockIdx.y * 128;

    const int t = threadIdx.x;
    const int w = t >> 6, l = t & 63;
    const int wr = (w >> 1) * 64, wc = (w & 1) * 64;

    const int srow  = t >> 1;
    const int shalf = (t & 1) * 16;
    const uint16_t* ap = h16 + (size_t)(row0 + srow) * 1024 + shalf;
    const float*    bp = wf  + (size_t)(col0 + srow) * 1024 + shalf;
    uint16_t* awr = Aa + srow * LSTR + shalf;
    uint16_t* bwr = Bb + srow * LSTR + shalf;

    f32x4 acc[4][4] = {};

    for (int kk = 0; kk < 1024; kk += 32) {
        u16x8 a0 = *(const u16x8*)(ap + kk);
        u16x8 a1 = *(const u16x8*)(ap + kk + 8);
        float4 f0 = *(const float4*)(bp + kk);
        float4 f1 = *(const float4*)(bp + kk + 4);
        float4 f2 = *(const float4*)(bp + kk + 8);
        float4 f3 = *(const float4*)(bp + kk + 12);
        union { u16x8 v; uint32_t u[4]; } b0, b1;
        b0.u[0] = cvtpk(f0.x, f0.y); b0.u[1] = cvtpk(f0.z, f0.w);
        b0.u[2] = cvtpk(f1.x, f1.y); b0.u[3] = cvtpk(f1.z, f1.w);
        b1.u[0] = cvtpk(f2.x, f2.y); b1.u[1] = cvtpk(f2.z, f2.w);
        b1.u[2] = cvtpk(f3.x, f3.y); b1.u[3] = cvtpk(f3.z, f3.w);

        __syncthreads();
        *(u16x8*)awr       = a0;
        *(u16x8*)(awr + 8) = a1;
        *(u16x8*)bwr       = b0.v;
        *(u16x8*)(bwr + 8) = b1.v;
        __syncthreads();

        const int row = l & 15, kg = (l >> 4) * 8;
        bf16x8 afr[4], bfr[4];
#pragma unroll
        for (int i = 0; i < 4; ++i)
            afr[i] = *(const bf16x8*)(Aa + (wr + i * 16 + row) * LSTR + kg);
#pragma unroll
        for (int j = 0; j < 4; ++j)
            bfr[j] = *(const bf16x8*)(Bb + (wc + j * 16 + row) * LSTR + kg);
#pragma unroll
        for (int i = 0; i < 4; ++i)
#pragma unroll
            for (int j = 0; j < 4; ++j)
                acc[i][j] = __builtin_amdgcn_mfma_f32_16x16x32_bf16(
                    afr[i], bfr[j], acc[i][j], 0, 0, 0);
    }

    const int col = l & 15, rg = (l >> 4) * 4;
#pragma unroll
    for (int i = 0; i < 4; ++i)
#pragma unroll
        for (int r = 0; r < 4; ++r) {
            const int row = row0 + wr + i * 16 + rg + r;
            const int bt  = row & 255;
            const int b = bt >> 4, tt = bt & 15;
            const size_t ibase = ((size_t)tt * 16 + b) * 1024;
#pragma unroll
            for (int j = 0; j < 4; ++j) {
                const int jj = col0 + wc + j * 16 + col;
                float v = acc[i][j][r] + bias[jj];
                if (row < 256) {
                    float al = sigm(att1[b * 512 + jj] * v);
                    alpha_out[(size_t)bt * 512 + jj] = al;
                    inm[ibase + jj]       = f2bf(al * v);
                    inm[ibase + 512 + jj] = f2bf(v);
                } else {
                    float be = sigm(att2[b * 512 + jj] * v);
                    ina[ibase + jj]       = f2bf(be * v);
                    ina[ibase + 512 + jj] = f2bf(v);
                }
            }
        }
}

// ---------------------------------------------------------------------------
// gx MFMA: gates x-projection, M=256, N=2048, K=1024, grid (2,16,2 paths).
// ---------------------------------------------------------------------------
__global__ __launch_bounds__(256) void gx_mfma_kernel(
    const uint16_t* __restrict__ inm, const uint16_t* __restrict__ ina,
    const float* __restrict__ wih_m, const float* __restrict__ bih_m, const float* __restrict__ bhh_m,
    const float* __restrict__ wih_a, const float* __restrict__ bih_a, const float* __restrict__ bhh_a,
    float* __restrict__ gxm, float* __restrict__ gxa)
{
    __shared__ __align__(16) uint16_t Aa[128 * LSTR];
    __shared__ __align__(16) uint16_t Bb[128 * LSTR];

    const int row0 = blockIdx.x * 128;
    const int col0 = blockIdx.y * 128;
    const int path = blockIdx.z;

    const uint16_t* A = path ? ina : inm;
    const float* W  = path ? wih_a : wih_m;
    const float* bi = path ? bih_a : bih_m;
    const float* bh = path ? bhh_a : bhh_m;
    float* out = path ? gxa : gxm;

    const int t = threadIdx.x;
    const int w = t >> 6, l = t & 63;
    const int wr = (w >> 1) * 64, wc = (w & 1) * 64;

    const int srow  = t >> 1;
    const int shalf = (t & 1) * 16;
    const uint16_t* ap = A + (size_t)(row0 + srow) * 1024 + shalf;
    const float*    bp = W + (size_t)(col0 + srow) * 1024 + shalf;
    uint16_t* awr = Aa + srow * LSTR + shalf;
    uint16_t* bwr = Bb + srow * LSTR + shalf;

    f32x4 acc[4][4] = {};

    for (int kk = 0; kk < 1024; kk += 32) {
        u16x8 a0 = *(const u16x8*)(ap + kk);
        u16x8 a1 = *(const u16x8*)(ap + kk + 8);
        float4 f0 = *(const float4*)(bp + kk);
        float4 f1 = *(const float4*)(bp + kk + 4);
        float4 f2 = *(const float4*)(bp + kk + 8);
        float4 f3 = *(const float4*)(bp + kk + 12);
        union { u16x8 v; uint32_t u[4]; } b0, b1;
        b0.u[0] = cvtpk(f0.x, f0.y); b0.u[1] = cvtpk(f0.z, f0.w);
        b0.u[2] = cvtpk(f1.x, f1.y); b0.u[3] = cvtpk(f1.z, f1.w);
        b1.u[0] = cvtpk(f2.x, f2.y); b1.u[1] = cvtpk(f2.z, f2.w);
        b1.u[2] = cvtpk(f3.x, f3.y); b1.u[3] = cvtpk(f3.z, f3.w);

        __syncthreads();
        *(u16x8*)awr       = a0;
        *(u16x8*)(awr + 8) = a1;
        *(u16x8*)bwr       = b0.v;
        *(u16x8*)(bwr + 8) = b1.v;
        __syncthreads();

        const int row = l & 15, kg = (l >> 4) * 8;
        bf16x8 afr[4], bfr[4];
#pragma unroll
        for (int i = 0; i < 4; ++i)
            afr[i] = *(const bf16x8*)(Aa + (wr + i * 16 + row) * LSTR + kg);
#pragma unroll
        for (int j = 0; j < 4; ++j)
            bfr[j] = *(const bf16x8*)(Bb + (wc + j * 16 + row) * LSTR + kg);
#pragma unroll
        for (int i = 0; i < 4; ++i)
#pragma unroll
            for (int j = 0; j < 4; ++j)
                acc[i][j] = __builtin_amdgcn_mfma_f32_16x16x32_bf16(
                    afr[i], bfr[j], acc[i][j], 0, 0, 0);
    }

    const int col = l & 15, rg = (l >> 4) * 4;
#pragma unroll
    for (int i = 0; i < 4; ++i)
#pragma unroll
        for (int r = 0; r < 4; ++r) {
            const int grow = row0 + wr + i * 16 + rg + r;
#pragma unroll
            for (int j = 0; j < 4; ++j) {
                const int jj = col0 + wc + j * 16 + col;
                out[(size_t)grow * 2048 + jj] = acc[i][j][r] + bi[jj] + bh[jj];
            }
        }
}

// ---------------------------------------------------------------------------
// Persistent LSTM scan v5b: fence-free point-to-point sync (IC-coherent).
// ---------------------------------------------------------------------------
__device__ __forceinline__ void wait_cnt(int* cnt, int target) {
    if (threadIdx.x == 0) {
        while (__hip_atomic_load(cnt, __ATOMIC_RELAXED, __HIP_MEMORY_SCOPE_AGENT) < target)
            __builtin_amdgcn_s_sleep(1);
    }
    __syncthreads();
}

__device__ __forceinline__ void post_cnt(int* cnt) {
    __syncthreads();   // drains vmcnt(0): all waves' sc1 stores reached the IC
    if (threadIdx.x == 0)
        __hip_atomic_fetch_add(cnt, 1, __ATOMIC_RELAXED, __HIP_MEMORY_SCOPE_AGENT);
}

__device__ __forceinline__ void stage_state(uint16_t* dst, const uint32_t* src, int tid) {
#pragma unroll
    for (int i = 0; i < 4; ++i) {
        const int idx = i * 1024 + tid * 4;
        uint4 v = *(const uint4*)(src + idx);
        const int flat = idx * 2;
        union { uint4 q; u16x8 h; } cv; cv.q = v;
        *(u16x8*)(dst + (flat >> 9) * 520 + (flat & 511)) = cv.h;
    }
}

__global__ __launch_bounds__(256, 1) void lstm_scan5_kernel(
    const float* __restrict__ gxm, const float* __restrict__ gxa,
    const uint16_t* __restrict__ pw1, const uint16_t* __restrict__ pw2m,
    const uint16_t* __restrict__ pw2a,
    const float* __restrict__ b2m_s, const float* __restrict__ b2a_s,
    uint32_t* __restrict__ s1p, uint32_t* __restrict__ s2ap,
    int* __restrict__ s1cnt, int* __restrict__ s2acnt,
    float* __restrict__ out)
{
    __shared__ __align__(16) uint16_t wlds[64 * 520];
    __shared__ __align__(16) uint16_t xs[16 * 520];
    __shared__ __align__(16) uint16_t hs[16 * 520];
    __shared__ float gbuf[2][16][68];

    const int bk  = blockIdx.x;
    const int tid = threadIdx.x;
    const int w   = tid >> 6, l = tid & 63;
    const int lrow = l & 15, kg = (l >> 4) * 8;

    const int role = (bk < 64) ? 0 : (bk < 96) ? 1 : 2;   // S1, S2M, S2A
    const int path = (role == 0) ? (bk >> 5) : (role == 1 ? 0 : 1);
    const int tile = (role == 0) ? (bk & 31) : (role == 1 ? bk - 64 : bk - 96);
    const int j0   = tile * ((role == 2) ? 8 : 16);

    const uint16_t* wsrc =
        (role == 0) ? pw1 + ((size_t)path * 32 + tile) * 64 * 512 :
        (role == 1) ? pw2m + (size_t)tile * 64 * 512
                    : pw2a + (size_t)tile * 64 * 512;
    for (int idx = tid; idx < 64 * 64; idx += 256) {
        int row = idx >> 6, c = idx & 63;
        *(u16x8*)(wlds + row * 520 + c * 8) = *(const u16x8*)(wsrc + row * 512 + c * 8);
    }

    float cv = 0.f;
    const float* gx1 = path ? gxa : gxm;

    if (role == 0) {
        const int b = tid >> 4, j = tid & 15, jg = j0 + j;
        const size_t obase = path ? 0 : 262144;
        for (int t = 0; t < 16; ++t) {
            const float* gxr = gx1 + ((size_t)(t * 16 + b)) * 2048;
            float g0 = gxr[jg], g1 = gxr[512 + jg], g2 = gxr[1024 + jg], g3 = gxr[1536 + jg];
            if (t > 0) wait_cnt(&s1cnt[path * 16 + t - 1], 32);
            stage_state(xs, s1p + ((size_t)t * 2 + path) * 4096, tid);
            __syncthreads();
            f32x4 acc = {};
#pragma unroll
            for (int kk = 0; kk < 512; kk += 32) {
                bf16x8 a  = *(const bf16x8*)(xs + lrow * 520 + kk + kg);
                bf16x8 bw = *(const bf16x8*)(wlds + (w * 16 + lrow) * 520 + kk + kg);
                acc = __builtin_amdgcn_mfma_f32_16x16x32_bf16(a, bw, acc, 0, 0, 0);
            }
#pragma unroll
            for (int r = 0; r < 4; ++r)
                gbuf[0][(l >> 4) * 4 + r][w * 16 + lrow] = acc[r];
            __syncthreads();

            float G0 = gbuf[0][b][j * 4 + 0] + g0;
            float G1 = gbuf[0][b][j * 4 + 1] + g1;
            float G2 = gbuf[0][b][j * 4 + 2] + g2;
            float G3 = gbuf[0][b][j * 4 + 3] + g3;
            cv = sigm(G1) * cv + sigm(G0) * tanhf(G2);
            float h = sigm(G3) * tanhf(cv);
            out[obase + ((size_t)b * 16 + t) * 1024 + jg] = h;
            float hn = __shfl_xor(h, 1);
            if ((j & 1) == 0) {
                uint32_t pk = (uint32_t)f2bf(h) | ((uint32_t)f2bf(hn) << 16);
                __hip_atomic_store(s1p + ((size_t)(t + 1) * 2 + path) * 4096 + b * 256 + (jg >> 1),
                                   pk, __ATOMIC_RELAXED, __HIP_MEMORY_SCOPE_AGENT);
            }
            post_cnt(&s1cnt[path * 16 + t]);
        }
    } else if (role == 1) {
        const int b = tid >> 4, j = tid & 15, jg = j0 + j;
        const float B0 = b2m_s[jg], B1 = b2m_s[512 + jg], B2 = b2m_s[1024 + jg], B3 = b2m_s[1536 + jg];
        for (int t = 0; t < 16; ++t) {
            wait_cnt(&s1cnt[t], 32);
            stage_state(xs, s1p + ((size_t)(t + 1) * 2 + 0) * 4096, tid);
            __syncthreads();
            f32x4 acc = {};
#pragma unroll
            for (int kk = 0; kk < 512; kk += 32) {
                bf16x8 a  = *(const bf16x8*)(xs + lrow * 520 + kk + kg);
                bf16x8 bw = *(const bf16x8*)(wlds + (w * 16 + lrow) * 520 + kk + kg);
                acc = __builtin_amdgcn_mfma_f32_16x16x32_bf16(a, bw, acc, 0, 0, 0);
            }
#pragma unroll
            for (int r = 0; r < 4; ++r)
                gbuf[0][(l >> 4) * 4 + r][w * 16 + lrow] = acc[r];
            __syncthreads();

            float G0 = gbuf[0][b][j * 4 + 0] + B0;
            float G1 = gbuf[0][b][j * 4 + 1] + B1;
            float G2 = gbuf[0][b][j * 4 + 2] + B2;
            float G3 = gbuf[0][b][j * 4 + 3] + B3;
            cv = sigm(G1) * cv + sigm(G0) * tanhf(G2);
            float h = sigm(G3) * tanhf(cv);
            out[262144 + ((size_t)b * 16 + t) * 1024 + 512 + jg] = h;
        }
    } else {
        const int b = tid >> 3, j = tid & 7, jg = j0 + j;
        float B0 = 0, B1 = 0, B2 = 0, B3 = 0;
        if (tid < 128) {
            B0 = b2a_s[jg]; B1 = b2a_s[512 + jg]; B2 = b2a_s[1024 + jg]; B3 = b2a_s[1536 + jg];
        }
        for (int t = 0; t < 16; ++t) {
            wait_cnt(&s1cnt[16 + t], 32);
            if (t > 0) wait_cnt(&s2acnt[t - 1], 64);
            stage_state(xs, s1p + ((size_t)(t + 1) * 2 + 1) * 4096, tid);
            stage_state(hs, s2ap + (size_t)t * 4096, tid);
            __syncthreads();
            const uint16_t* src = (w < 2) ? xs : hs;
            const int wt = (w < 2) ? w : w - 2;
            const int wb = (w < 2) ? 0 : 32 * 520;
            f32x4 acc = {};
#pragma unroll
            for (int kk = 0; kk < 512; kk += 32) {
                bf16x8 a  = *(const bf16x8*)(src + lrow * 520 + kk + kg);
                bf16x8 bw = *(const bf16x8*)(wlds + wb + (wt * 16 + lrow) * 520 + kk + kg);
                acc = __builtin_amdgcn_mfma_f32_16x16x32_bf16(a, bw, acc, 0, 0, 0);
            }
#pragma unroll
            for (int r = 0; r < 4; ++r)
                gbuf[w >> 1][(l >> 4) * 4 + r][wt * 16 + lrow] = acc[r];
            __syncthreads();

            if (tid < 128) {
                float G0 = gbuf[0][b][j * 4 + 0] + gbuf[1][b][j * 4 + 0] + B0;
                float G1 = gbuf[0][b][j * 4 + 1] + gbuf[1][b][j * 4 + 1] + B1;
                float G2 = gbuf[0][b][j * 4 + 2] + gbuf[1][b][j * 4 + 2] + B2;
                float G3 = gbuf[0][b][j * 4 + 3] + gbuf[1][b][j * 4 + 3] + B3;
                cv = sigm(G1) * cv + sigm(G0) * tanhf(G2);
                float h = sigm(G3) * tanhf(cv);
                out[((size_t)b * 16 + t) * 1024 + 512 + jg] = h;
                float hn = __shfl_xor(h, 1);
                if ((j & 1) == 0) {
                    uint32_t pk = (uint32_t)f2bf(h) | ((uint32_t)f2bf(hn) << 16);
                    __hip_atomic_store(s2ap + (size_t)(t + 1) * 4096 + b * 256 + (jg >> 1),
                                       pk, __ATOMIC_RELAXED, __HIP_MEMORY_SCOPE_AGENT);
                }
            }
            post_cnt(&s2acnt[t]);
        }
    }
}

// ---------------------------------------------------------------------------
extern "C" void kernel_launch(void* const* d_in, const int* in_sizes, int n_in,
                              void* d_out, int out_size, void* d_ws, size_t ws_size,
                              hipStream_t stream)
{
    (void)in_sizes; (void)n_in; (void)out_size; (void)ws_size;
    const float* f_t     = (const float*)d_in[0];
    const float* f_t_1   = (const float*)d_in[1];
    const float* att1    = (const float*)d_in[2];
    const float* att2    = (const float*)d_in[3];
    const float* conv1_w = (const float*)d_in[4];
    const float* conv1_b = (const float*)d_in[5];
    const float* conv2_w = (const float*)d_in[6];
    const float* conv2_b = (const float*)d_in[7];
    const float* l1a_wih = (const float*)d_in[8];
    const float* l1a_whh = (const float*)d_in[9];
    const float* l1a_bih = (const float*)d_in[10];
    const float* l1a_bhh = (const float*)d_in[11];
    const float* l2a_wih = (const float*)d_in[12];
    const float* l2a_whh = (const float*)d_in[13];
    const float* l2a_bih = (const float*)d_in[14];
    const float* l2a_bhh = (const float*)d_in[15];
    const float* l1m_wih = (const float*)d_in[16];
    const float* l1m_whh = (const float*)d_in[17];
    const float* l1m_bih = (const float*)d_in[18];
    const float* l1m_bhh = (const float*)d_in[19];
    const float* l2m_wih = (const float*)d_in[20];
    const float* l2m_whh = (const float*)d_in[21];
    const float* l2m_bih = (const float*)d_in[22];
    const float* l2m_bhh = (const float*)d_in[23];
    const float* fc1_w   = (const float*)d_in[24];
    const float* fc1_b   = (const float*)d_in[25];
    const float* fc2_w   = (const float*)d_in[26];
    const float* fc2_b   = (const float*)d_in[27];

    char* p = (char*)d_ws;
    // part (64MB, fc1 split-K=32 partials) aliases in1_nhwc (dead after conv1)
    float*    part     = (float*)p;
    uint16_t* in1_nhwc = (uint16_t*)p;             // [256][1024][128] bf16
    p += (size_t)64 << 20;
    uint16_t* c1out    = (uint16_t*)p; p += (size_t)32 << 20;  // [256][1024][64] NHWC
    uint16_t* mbuf16   = (uint16_t*)p; p += (size_t)32 << 20;  // [256][64][1024] NCHW
    uint16_t* ftflat16 = (uint16_t*)p; p += (size_t)32 << 20;  // [256][65536]
    uint16_t* wpack1   = (uint16_t*)p; p += 256 * 1024;
    uint16_t* wpack2   = (uint16_t*)p; p += 128 * 1024;
    uint16_t* hbuf16 = (uint16_t*)p; p += (size_t)2 << 20;
    uint16_t* inm  = (uint16_t*)p; p += (size_t)1 << 20;
    uint16_t* ina  = (uint16_t*)p; p += (size_t)1 << 20;
    float* gxm  = (float*)p; p += (size_t)2 << 20;
    float* gxa  = (float*)p; p += (size_t)2 << 20;
    uint16_t* pw1  = (uint16_t*)p; p += (size_t)2097152 * 2;
    uint16_t* pw2m = (uint16_t*)p; p += (size_t)1048576 * 2;
    uint16_t* pw2a = (uint16_t*)p; p += (size_t)2097152 * 2;
    float* b2m_s = (float*)p; p += 2048 * 4;
    float* b2a_s = (float*)p; p += 2048 * 4;
    uint32_t* s1p  = (uint32_t*)p; p += (size_t)17 * 2 * 4096 * 4;
    uint32_t* s2ap = (uint32_t*)p; p += (size_t)17 * 4096 * 4;
    int* s1cnt  = (int*)p; p += 32 * 4;
    int* s2acnt = (int*)p; p += 16 * 4;

    float* outp = (float*)d_out;
    float* alpha_out = outp + 524288;

    hipMemsetAsync(s1p, 0, 2 * 4096 * 4, stream);
    hipMemsetAsync(s2ap, 0, 4096 * 4, stream);
    hipMemsetAsync(s1cnt, 0, 48 * 4, stream);

    prep_all_kernel<<<15136, 256, 0, stream>>>(
        f_t, f_t_1, conv1_w, conv2_w,
        l1m_whh, l1a_whh, l2m_wih, l2m_whh, l2a_wih, l2a_whh,
        l2m_bih, l2m_bhh, l2a_bih, l2a_bhh,
        ftflat16, in1_nhwc, wpack1, wpack2,
        pw1, pw2m, pw2a, b2m_s, b2a_s);

    conv_mfma2_kernel<128, false><<<dim3(8, 256), 256, 0, stream>>>(
        in1_nhwc, wpack1, conv1_b, c1out);
    conv_mfma2_kernel<64, true><<<dim3(8, 256), 256, 0, stream>>>(
        c1out, wpack2, conv2_b, mbuf16);

    fc1_mfma_kernel<<<512, 256, 0, stream>>>(mbuf16, ftflat16, fc1_w, part);
    fc1_reduce_kernel<<<2048, 256, 0, stream>>>(part, fc1_b, hbuf16);

    fc2_att_mfma_kernel<<<dim3(4, 4), 256, 0, stream>>>(hbuf16, fc2_w, fc2_b, att1, att2,
                                                        alpha_out, inm, ina);

    gx_mfma_kernel<<<dim3(2, 16, 2), 256, 0, stream>>>(inm, ina,
                                                       l1m_wih, l1m_bih, l1m_bhh,
                                                       l1a_wih, l1a_bih, l1a_bhh,
                                                       gxm, gxa);

    lstm_scan5_kernel<<<NBLK, 256, 0, stream>>>(
        gxm, gxa, pw1, pw2m, pw2a, b2m_s, b2a_s,
        s1p, s2ap, s1cnt, s2acnt, outp);
}